// Round 1
// baseline (16951.965 us; speedup 1.0000x reference)
//
#include <hip/hip_runtime.h>
#include <math.h>

#define B_N 512

// ---------------- conv k4 s2 p1 ----------------
template<int Ci, int Co, int Hin>
__global__ __launch_bounds__(256) void conv4s2(const float* __restrict__ in,
    const float* __restrict__ wt, const float* __restrict__ bias, float* __restrict__ out) {
  constexpr int Ho = Hin / 2;
  constexpr long total = (long)B_N * Co * Ho * Ho;
  long idx = (long)blockIdx.x * 256 + threadIdx.x;
  if (idx >= total) return;
  int wo = (int)(idx % Ho); long t = idx / Ho;
  int ho = (int)(t % Ho); t /= Ho;
  int co = (int)(t % Co); int n = (int)(t / Co);
  float acc = bias[co];
  const float* wp = wt + (long)co * Ci * 16;
  const float* ip = in + (long)n * Ci * Hin * Hin;
  for (int ci = 0; ci < Ci; ++ci) {
    const float* iprow = ip + (long)ci * Hin * Hin;
    const float* wrow = wp + ci * 16;
#pragma unroll
    for (int kh = 0; kh < 4; ++kh) {
      int ih = ho * 2 - 1 + kh;
      if ((unsigned)ih >= (unsigned)Hin) continue;
#pragma unroll
      for (int kw = 0; kw < 4; ++kw) {
        int iw = wo * 2 - 1 + kw;
        if ((unsigned)iw >= (unsigned)Hin) continue;
        acc = fmaf(iprow[ih * Hin + iw], wrow[kh * 4 + kw], acc);
      }
    }
  }
  out[idx] = acc;
}

// ---------------- conv 1x1 (HW = 16) ----------------
template<int Ci, int Co>
__global__ __launch_bounds__(256) void conv1x1(const float* __restrict__ in,
    const float* __restrict__ wt, const float* __restrict__ bias, float* __restrict__ out) {
  constexpr int HW = 16;
  constexpr long total = (long)B_N * Co * HW;
  long idx = (long)blockIdx.x * 256 + threadIdx.x;
  if (idx >= total) return;
  int p = (int)(idx & 15); long t = idx >> 4;
  int co = (int)(t % Co); int n = (int)(t / Co);
  float acc = bias[co];
  const float* ip = in + ((long)n * Ci) * HW + p;
  const float* wp = wt + (long)co * Ci;
#pragma unroll 8
  for (int ci = 0; ci < Ci; ++ci) acc = fmaf(ip[ci * HW], wp[ci], acc);
  out[idx] = acc;
}

// ---------------- nearest-up2 + conv 3x3 s1 p1 ----------------
// Ho = output spatial = 2 * original input spatial
template<int Ci, int Co, int Ho, bool SIG>
__global__ __launch_bounds__(256) void conv3x3up(const float* __restrict__ in,
    const float* __restrict__ wt, const float* __restrict__ bias, float* __restrict__ out) {
  constexpr int Hin = Ho / 2;
  constexpr long total = (long)B_N * Co * Ho * Ho;
  long idx = (long)blockIdx.x * 256 + threadIdx.x;
  if (idx >= total) return;
  int wo = (int)(idx % Ho); long t = idx / Ho;
  int ho = (int)(t % Ho); t /= Ho;
  int co = (int)(t % Co); int n = (int)(t / Co);
  float acc = bias[co];
  const float* wp = wt + (long)co * Ci * 9;
  const float* ip = in + (long)n * Ci * Hin * Hin;
  int rr[3], cc[3]; bool rv[3], cv[3];
#pragma unroll
  for (int k = 0; k < 3; ++k) {
    int ih = ho - 1 + k;
    rv[k] = (unsigned)ih < (unsigned)Ho;
    rr[k] = ih >> 1;           // upsampled -> original row
    int iw = wo - 1 + k;
    cv[k] = (unsigned)iw < (unsigned)Ho;
    cc[k] = iw >> 1;           // upsampled -> original col
  }
  for (int ci = 0; ci < Ci; ++ci) {
    const float* iprow = ip + (long)ci * Hin * Hin;
    const float* ww = wp + ci * 9;
#pragma unroll
    for (int kh = 0; kh < 3; ++kh) {
      if (!rv[kh]) continue;
      const float* row = iprow + rr[kh] * Hin;
#pragma unroll
      for (int kw = 0; kw < 3; ++kw) {
        if (!cv[kw]) continue;
        acc = fmaf(row[cc[kw]], ww[kh * 3 + kw], acc);
      }
    }
  }
  if (SIG) acc = 1.0f / (1.0f + expf(-acc));
  out[idx] = acc;
}

// ---------------- BN batch statistics ----------------
// stats layout: [0,C) sum, [C,2C) sumsq, [2C,3C) scale, [3C,4C) shift
__global__ __launch_bounds__(256) void bn_stats(const float* __restrict__ x,
    float* __restrict__ stats, int C, int hwShift) {
  int c = blockIdx.x;
  long per = ((long)B_N) << hwShift;
  int HWm = (1 << hwShift) - 1;
  float s = 0.f, s2 = 0.f;
  for (long i = (long)blockIdx.y * 256 + threadIdx.x; i < per; i += (long)gridDim.y * 256) {
    long n = i >> hwShift; int p = (int)(i & HWm);
    float v = x[((n * C + c) << hwShift) + p];
    s += v; s2 = fmaf(v, v, s2);
  }
#pragma unroll
  for (int o = 32; o > 0; o >>= 1) { s += __shfl_down(s, o); s2 += __shfl_down(s2, o); }
  __shared__ float sh[8];
  int wid = threadIdx.x >> 6;
  if ((threadIdx.x & 63) == 0) { sh[wid] = s; sh[4 + wid] = s2; }
  __syncthreads();
  if (threadIdx.x == 0) {
    s = sh[0] + sh[1] + sh[2] + sh[3];
    s2 = sh[4] + sh[5] + sh[6] + sh[7];
    atomicAdd(&stats[c], s);
    atomicAdd(&stats[C + c], s2);
  }
}

__global__ void bn_finalize(float* __restrict__ stats, const float* __restrict__ g,
                            const float* __restrict__ b, int C, float inv_cnt) {
  int c = threadIdx.x;
  if (c >= C) return;
  float mean = stats[c] * inv_cnt;
  float var  = stats[C + c] * inv_cnt - mean * mean;
  float sc = g[c] / sqrtf(var + 1e-5f);
  stats[2 * C + c] = sc;
  stats[3 * C + c] = b[c] - mean * sc;
}

__global__ __launch_bounds__(256) void bn_apply(float* __restrict__ x,
    const float* __restrict__ stats, int cMask, int hwShift, long total) {
  long idx = (long)blockIdx.x * 256 + threadIdx.x;
  if (idx >= total) return;
  int C = cMask + 1;
  int c = (int)(idx >> hwShift) & cMask;
  float v = fmaf(x[idx], stats[2 * C + c], stats[3 * C + c]);
  x[idx] = v > 0.f ? v : 0.01f * v;
}

// ---------------- VQ ----------------
// Z[b, (h*4+w)*64 + c] = Ze[b, c, h, w]
__global__ __launch_bounds__(256) void make_Z(const float* __restrict__ ze, float* __restrict__ Z) {
  int idx = blockIdx.x * 256 + threadIdx.x;  // 524288 total
  int d = idx & 1023; int b = idx >> 10;
  int c = d & 63; int hw = d >> 6;
  Z[idx] = ze[(b << 10) + (c << 4) + hw];
}

__global__ __launch_bounds__(256) void vq_argmin(const float* __restrict__ Z,
    const float* __restrict__ cb, int* __restrict__ jout) {
  __shared__ float zsh[1024];
  int b = blockIdx.x;
  const float* zp = Z + ((long)b << 10);
  for (int i = threadIdx.x; i < 1024; i += 256) zsh[i] = zp[i];
  __syncthreads();
  float best = 3.4e38f; int bestk = 0;
  for (int k = threadIdx.x; k < 512; k += 256) {
    const float* w = cb + ((long)k << 10);
    float dot = 0.f, ccs = 0.f;
#pragma unroll 4
    for (int i = 0; i < 1024; ++i) {
      float wv = w[i];
      dot = fmaf(zsh[i], wv, dot);
      ccs = fmaf(wv, wv, ccs);
    }
    float dist = ccs - 2.0f * dot;   // zz term is constant per row -> same argmin
    if (dist < best) { best = dist; bestk = k; }   // strict < keeps first index
  }
  __shared__ float vsh[256]; __shared__ int ish[256];
  vsh[threadIdx.x] = best; ish[threadIdx.x] = bestk;
  __syncthreads();
  for (int srd = 128; srd > 0; srd >>= 1) {
    if (threadIdx.x < srd) {
      float ov = vsh[threadIdx.x + srd]; int oi = ish[threadIdx.x + srd];
      if (ov < vsh[threadIdx.x] || (ov == vsh[threadIdx.x] && oi < ish[threadIdx.x])) {
        vsh[threadIdx.x] = ov; ish[threadIdx.x] = oi;
      }
    }
    __syncthreads();
  }
  if (threadIdx.x == 0) jout[b] = ish[0];
}

// gather Zq (NCHW) + exact (Z - W_j)^2 sum -> atomic accumulate
__global__ __launch_bounds__(256) void vq_gather_loss(const float* __restrict__ Z,
    const float* __restrict__ cb, const int* __restrict__ jidx,
    float* __restrict__ Zq, float* __restrict__ lossAcc) {
  int b = blockIdx.x;
  int k = jidx[b];
  const float* w = cb + ((long)k << 10);
  const float* zp = Z + ((long)b << 10);
  float part = 0.f;
  for (int d = threadIdx.x; d < 1024; d += 256) {
    float wv = w[d];
    float diff = zp[d] - wv;
    part = fmaf(diff, diff, part);
    int c = d & 63; int hw = d >> 6;
    Zq[(b << 10) + (c << 4) + hw] = wv;
  }
#pragma unroll
  for (int o = 32; o > 0; o >>= 1) part += __shfl_down(part, o);
  __shared__ float sh[4];
  if ((threadIdx.x & 63) == 0) sh[threadIdx.x >> 6] = part;
  __syncthreads();
  if (threadIdx.x == 0) atomicAdd(lossAcc, sh[0] + sh[1] + sh[2] + sh[3]);
}

__global__ void write_losses(const float* __restrict__ lossAcc, float* __restrict__ out2) {
  float v = lossAcc[0] * (1.0f / 512.0f);
  out2[0] = v;   // vq_loss
  out2[1] = v;   // commit_loss (identical forward value)
}

// ---------------- launch ----------------
extern "C" void kernel_launch(void* const* d_in, const int* in_sizes, int n_in,
                              void* d_out, int out_size, void* d_ws, size_t ws_size,
                              hipStream_t stream) {
  const float* x      = (const float*)d_in[0];
  const float* ce1_w  = (const float*)d_in[1];  const float* ce1_b = (const float*)d_in[2];
  const float* ce2_w  = (const float*)d_in[3];  const float* ce2_b = (const float*)d_in[4];
  const float* ce3_w  = (const float*)d_in[5];  const float* ce3_b = (const float*)d_in[6];
  const float* ce4_w  = (const float*)d_in[7];  const float* ce4_b = (const float*)d_in[8];
  const float* ce5_w  = (const float*)d_in[9];  const float* ce5_b = (const float*)d_in[10];
  const float* cd0_w  = (const float*)d_in[11]; const float* cd0_b = (const float*)d_in[12];
  const float* cd1_w  = (const float*)d_in[13]; const float* cd1_b = (const float*)d_in[14];
  const float* cd2_w  = (const float*)d_in[15]; const float* cd2_b = (const float*)d_in[16];
  const float* cd3_w  = (const float*)d_in[17]; const float* cd3_b = (const float*)d_in[18];
  const float* cd4_w  = (const float*)d_in[19]; const float* cd4_b = (const float*)d_in[20];
  const float* bn_e1_g = (const float*)d_in[21]; const float* bn_e1_b = (const float*)d_in[22];
  const float* bn_e2_g = (const float*)d_in[23]; const float* bn_e2_b = (const float*)d_in[24];
  const float* bn_e3_g = (const float*)d_in[25]; const float* bn_e3_b = (const float*)d_in[26];
  const float* bn_e4_g = (const float*)d_in[27]; const float* bn_e4_b = (const float*)d_in[28];
  const float* bn_e5_g = (const float*)d_in[29]; const float* bn_e5_b = (const float*)d_in[30];
  const float* bn_d0_g = (const float*)d_in[31]; const float* bn_d0_b = (const float*)d_in[32];
  const float* bn_d1_g = (const float*)d_in[33]; const float* bn_d1_b = (const float*)d_in[34];
  const float* bn_d2_g = (const float*)d_in[35]; const float* bn_d2_b = (const float*)d_in[36];
  const float* bn_d3_g = (const float*)d_in[37]; const float* bn_d3_b = (const float*)d_in[38];
  const float* codebook = (const float*)d_in[39];

  float* out = (float*)d_out;

  float* bufA   = (float*)d_ws;              // 16,777,216 floats
  float* bufB   = bufA + 16777216;           // 16,777,216 floats
  float* Z      = bufB + 16777216;           // 524,288
  float* Zq     = Z + 524288;                // 524,288
  float* stats  = Zq + 524288;               // 1024
  float* lossAcc = stats + 1024;             // 4
  int*   jbuf   = (int*)(lossAcc + 4);       // 512

  auto bnstage = [&](float* buf, int C, int hwShift, const float* g, const float* b) {
    hipMemsetAsync(stats, 0, 2 * C * sizeof(float), stream);
    int chunks = 2048 / C; if (chunks < 1) chunks = 1;
    hipLaunchKernelGGL(bn_stats, dim3(C, chunks), dim3(256), 0, stream, buf, stats, C, hwShift);
    float inv_cnt = 1.0f / (float)((long)B_N << hwShift);
    hipLaunchKernelGGL(bn_finalize, dim3(1), dim3(C), 0, stream, stats, g, b, C, inv_cnt);
    long total = ((long)B_N * C) << hwShift;
    int grid = (int)((total + 255) / 256);
    hipLaunchKernelGGL(bn_apply, dim3(grid), dim3(256), 0, stream, buf, stats, C - 1, hwShift, total);
  };

  // ---- encoder ----
  conv4s2<3, 32, 64><<<65536, 256, 0, stream>>>(x, ce1_w, ce1_b, bufA);
  bnstage(bufA, 32, 10, bn_e1_g, bn_e1_b);

  conv4s2<32, 64, 32><<<32768, 256, 0, stream>>>(bufA, ce2_w, ce2_b, bufB);
  bnstage(bufB, 64, 8, bn_e2_g, bn_e2_b);

  conv4s2<64, 128, 16><<<16384, 256, 0, stream>>>(bufB, ce3_w, ce3_b, bufA);
  bnstage(bufA, 128, 6, bn_e3_g, bn_e3_b);

  conv4s2<128, 256, 8><<<8192, 256, 0, stream>>>(bufA, ce4_w, ce4_b, bufB);
  bnstage(bufB, 256, 4, bn_e4_g, bn_e4_b);

  conv1x1<256, 64><<<2048, 256, 0, stream>>>(bufB, ce5_w, ce5_b, bufA);
  bnstage(bufA, 64, 4, bn_e5_g, bn_e5_b);

  // ---- VQ ----
  make_Z<<<2048, 256, 0, stream>>>(bufA, Z);
  vq_argmin<<<512, 256, 0, stream>>>(Z, codebook, jbuf);
  hipMemsetAsync(lossAcc, 0, sizeof(float), stream);
  vq_gather_loss<<<512, 256, 0, stream>>>(Z, codebook, jbuf, Zq, lossAcc);
  write_losses<<<1, 1, 0, stream>>>(lossAcc, out + 6291456);

  // ---- decoder ----
  conv1x1<64, 256><<<8192, 256, 0, stream>>>(Zq, cd0_w, cd0_b, bufA);
  bnstage(bufA, 256, 4, bn_d0_g, bn_d0_b);

  conv3x3up<256, 128, 8, false><<<16384, 256, 0, stream>>>(bufA, cd1_w, cd1_b, bufB);
  bnstage(bufB, 128, 6, bn_d1_g, bn_d1_b);

  conv3x3up<128, 64, 16, false><<<32768, 256, 0, stream>>>(bufB, cd2_w, cd2_b, bufA);
  bnstage(bufA, 64, 8, bn_d2_g, bn_d2_b);

  conv3x3up<64, 32, 32, false><<<65536, 256, 0, stream>>>(bufA, cd3_w, cd3_b, bufB);
  bnstage(bufB, 32, 10, bn_d3_g, bn_d3_b);

  conv3x3up<32, 3, 64, true><<<24576, 256, 0, stream>>>(bufB, cd4_w, cd4_b, out);
}

// Round 2
// 2632.191 us; speedup vs baseline: 6.4402x; 6.4402x over previous
//
#include <hip/hip_runtime.h>
#include <math.h>

#define B_N 512

// ================= encoder conv k4 s2 p1, register-tiled over co =================
template<int Ci, int Co, int Hin, int Tco>
__global__ __launch_bounds__(256) void conv4s2_rt(const float* __restrict__ in,
    const float* __restrict__ wt, const float* __restrict__ bias, float* __restrict__ out) {
  constexpr int Ho = Hin / 2;
  int idx = blockIdx.x * 256 + threadIdx.x;        // over B*Ho*Ho (exact multiple of 256)
  int wo = idx % Ho; int t1 = idx / Ho; int ho = t1 % Ho; int n = t1 / Ho;
  int co0 = blockIdx.y * Tco;                      // wave-uniform -> scalar weight loads
  float acc[Tco];
#pragma unroll
  for (int t = 0; t < Tco; ++t) acc[t] = bias[co0 + t];
  const float* ip = in + (long)n * Ci * Hin * Hin;
  for (int ci = 0; ci < Ci; ++ci) {
    float pin[16];
    const float* pl = ip + (long)ci * Hin * Hin;
#pragma unroll
    for (int kh = 0; kh < 4; ++kh) {
      int ih = 2 * ho - 1 + kh;
#pragma unroll
      for (int kw = 0; kw < 4; ++kw) {
        int iw = 2 * wo - 1 + kw;
        bool v = ((unsigned)ih < (unsigned)Hin) && ((unsigned)iw < (unsigned)Hin);
        pin[kh * 4 + kw] = v ? pl[ih * Hin + iw] : 0.f;
      }
    }
#pragma unroll
    for (int t = 0; t < Tco; ++t) {
      const float* wr = wt + ((long)(co0 + t) * Ci + ci) * 16;
#pragma unroll
      for (int k = 0; k < 16; ++k) acc[t] = fmaf(pin[k], wr[k], acc[t]);
    }
  }
#pragma unroll
  for (int t = 0; t < Tco; ++t)
    out[((long)(n * Co + co0 + t) * Ho + ho) * Ho + wo] = acc[t];
}

// ================= conv 1x1 (HW=16), register-tiled over co =================
template<int Ci, int Co, int Tco>
__global__ __launch_bounds__(256) void conv1x1_rt(const float* __restrict__ in,
    const float* __restrict__ wt, const float* __restrict__ bias, float* __restrict__ out) {
  int idx = blockIdx.x * 256 + threadIdx.x;        // over B*16 (exact)
  int p = idx & 15; int n = idx >> 4;
  int co0 = blockIdx.y * Tco;
  float acc[Tco];
#pragma unroll
  for (int t = 0; t < Tco; ++t) acc[t] = bias[co0 + t];
  const float* ip = in + ((long)n * Ci) * 16 + p;
  for (int ci = 0; ci < Ci; ++ci) {
    float v = ip[ci * 16];
#pragma unroll
    for (int t = 0; t < Tco; ++t)
      acc[t] = fmaf(v, wt[(long)(co0 + t) * Ci + ci], acc[t]);
  }
#pragma unroll
  for (int t = 0; t < Tco; ++t)
    out[(((long)n * Co + co0 + t) << 4) + p] = acc[t];
}

// ================= weight transform OIHW -> [ci][9][co] =================
__global__ __launch_bounds__(256) void wtrans(const float* __restrict__ w, float* __restrict__ o,
                                              int Co, int Ci) {
  int idx = blockIdx.x * 256 + threadIdx.x;
  int tot = Co * Ci * 9;
  if (idx >= tot) return;
  int k = idx % 9; int t = idx / 9; int ci = t % Ci; int co = t / Ci;
  o[(ci * 9 + k) * Co + co] = w[idx];
}

// ================= decoder: nearest-up2 + 3x3 s1 p1, LDS-tiled =================
// wtk layout: [Ci][9][Co] (from wtrans). Output Ho=2*Hin.
template<int Ci, int Co, int Hin, int Rco, int CK, int NB, bool SIG>
__global__ __launch_bounds__(256) void dconv(const float* __restrict__ in,
    const float* __restrict__ wtk, const float* __restrict__ bias, float* __restrict__ out) {
  constexpr int Ho = 2 * Hin, Wo = Ho, Win = Hin;
  constexpr int WG  = Wo / 8;                 // wo-groups of 8
  constexpr int COG = Co / Rco;               // co groups
  constexpr int ROWS = 256 / (WG * COG * NB); // output rows per (block,image)
  constexpr int IN_ROWS = ROWS / 2 + 2;
  constexpr int WTC = Win + 2;                // padded LDS row width
  constexpr int RB = Ho / ROWS;               // row-blocks per image
  static_assert(WG * COG * ROWS * NB == 256, "thread map");
  static_assert(Ci % CK == 0, "chunks");
  static_assert((CK * 9 * Co) % 4 == 0, "w stage vec");

  __shared__ __align__(16) float li[CK * NB * IN_ROWS * WTC];
  __shared__ __align__(16) float lw[CK * 9 * Co];

  int tid = threadIdx.x;
  int rb = blockIdx.x % RB;
  int nbase = (blockIdx.x / RB) * NB;
  int wg  = tid % WG;
  int cog = (tid / WG) % COG;
  int r   = (tid / (WG * COG)) % ROWS;
  int nb  = tid / (WG * COG * ROWS);
  int row0 = rb * ROWS;
  int ihbase = row0 / 2 - 1;
  int co0 = cog * Rco;

  float acc[Rco][8];
#pragma unroll
  for (int t = 0; t < Rco; ++t) {
    float b = bias[co0 + t];
#pragma unroll
    for (int j = 0; j < 8; ++j) acc[t][j] = b;
  }

  for (int c0 = 0; c0 < Ci; c0 += CK) {
    __syncthreads();
    // ---- stage input tile (zero-padded) ----
    constexpr int IN_N = CK * NB * IN_ROWS * WTC;
    for (int i = tid; i < IN_N; i += 256) {
      int c = i % WTC; int t2 = i / WTC;
      int rr = t2 % IN_ROWS; int t3 = t2 / IN_ROWS;
      int nbs = t3 % NB; int ck = t3 / NB;
      int ih = ihbase + rr; int ic = c - 1;
      float v = 0.f;
      if ((unsigned)ih < (unsigned)Hin && (unsigned)ic < (unsigned)Win)
        v = in[(((long)(nbase + nbs) * Ci + c0 + ck) * Hin + ih) * Win + ic];
      li[(((long)ck * NB + nbs) * IN_ROWS + rr) * WTC + c] = v;
    }
    // ---- stage weights (contiguous, vectorized) ----
    constexpr int WN = CK * 9 * Co;
    const float* wsrc = wtk + (long)c0 * 9 * Co;
    for (int i4 = tid * 4; i4 < WN; i4 += 1024)
      *(float4*)&lw[i4] = *(const float4*)&wsrc[i4];
    __syncthreads();

#pragma unroll 1
    for (int ck = 0; ck < CK; ++ck) {
#pragma unroll
      for (int kh = 0; kh < 3; ++kh) {
        int irow = ((r - 1 + kh) >> 1) + 1;
        const float* ib = &li[((ck * NB + nb) * IN_ROWS + irow) * WTC + wg * 4];
        float iv[6];
#pragma unroll
        for (int p = 0; p < 6; ++p) iv[p] = ib[p];
#pragma unroll
        for (int kw = 0; kw < 3; ++kw) {
          const float* wb = &lw[(ck * 9 + kh * 3 + kw) * Co + co0];
          float wv[Rco];
          if constexpr (Rco % 4 == 0) {
#pragma unroll
            for (int q = 0; q < Rco / 4; ++q) {
              float4 w4 = *(const float4*)(wb + 4 * q);
              wv[4 * q] = w4.x; wv[4 * q + 1] = w4.y; wv[4 * q + 2] = w4.z; wv[4 * q + 3] = w4.w;
            }
          } else {
#pragma unroll
            for (int t = 0; t < Rco; ++t) wv[t] = wb[t];
          }
#pragma unroll
          for (int t = 0; t < Rco; ++t)
#pragma unroll
            for (int j = 0; j < 8; ++j)
              acc[t][j] = fmaf(iv[((j - 1 + kw) >> 1) + 1], wv[t], acc[t][j]);
        }
      }
    }
  }

  // ---- epilogue ----
  int ho = row0 + r; int wo0 = wg * 8; int n = nbase + nb;
#pragma unroll
  for (int t = 0; t < Rco; ++t) {
    float v[8];
#pragma unroll
    for (int j = 0; j < 8; ++j) {
      float a = acc[t][j];
      v[j] = SIG ? 1.f / (1.f + expf(-a)) : a;
    }
    float* op = out + (((long)n * Co + co0 + t) * Ho + ho) * Wo + wo0;
    *(float4*)op = make_float4(v[0], v[1], v[2], v[3]);
    *(float4*)(op + 4) = make_float4(v[4], v[5], v[6], v[7]);
  }
}

// ================= BatchNorm (training-mode batch stats) =================
// stats layout: [0,C) sum, [C,2C) sumsq, [2C,3C) scale, [3C,4C) shift
__global__ __launch_bounds__(256) void bn_stats(const float* __restrict__ x,
    float* __restrict__ stats, int C, int hwShift) {
  int c = blockIdx.x;
  long per = ((long)B_N) << hwShift;
  int HWm = (1 << hwShift) - 1;
  float s = 0.f, s2 = 0.f;
  for (long i = (long)blockIdx.y * 256 + threadIdx.x; i < per; i += (long)gridDim.y * 256) {
    long n = i >> hwShift; int p = (int)(i & HWm);
    float v = x[((n * C + c) << hwShift) + p];
    s += v; s2 = fmaf(v, v, s2);
  }
#pragma unroll
  for (int o = 32; o > 0; o >>= 1) { s += __shfl_down(s, o); s2 += __shfl_down(s2, o); }
  __shared__ float sh[8];
  int wid = threadIdx.x >> 6;
  if ((threadIdx.x & 63) == 0) { sh[wid] = s; sh[4 + wid] = s2; }
  __syncthreads();
  if (threadIdx.x == 0) {
    s = sh[0] + sh[1] + sh[2] + sh[3];
    s2 = sh[4] + sh[5] + sh[6] + sh[7];
    atomicAdd(&stats[c], s);
    atomicAdd(&stats[C + c], s2);
  }
}

__global__ void bn_finalize(float* __restrict__ stats, const float* __restrict__ g,
                            const float* __restrict__ b, int C, float inv_cnt) {
  int c = threadIdx.x;
  if (c >= C) return;
  float mean = stats[c] * inv_cnt;
  float var  = stats[C + c] * inv_cnt - mean * mean;
  float sc = g[c] / sqrtf(var + 1e-5f);
  stats[2 * C + c] = sc;
  stats[3 * C + c] = b[c] - mean * sc;
}

__global__ __launch_bounds__(256) void bn_apply(float* __restrict__ x,
    const float* __restrict__ stats, int cMask, int hwShift, long total) {
  long idx = (long)blockIdx.x * 256 + threadIdx.x;
  if (idx >= total) return;
  int C = cMask + 1;
  int c = (int)(idx >> hwShift) & cMask;
  float v = fmaf(x[idx], stats[2 * C + c], stats[3 * C + c]);
  x[idx] = v > 0.f ? v : 0.01f * v;
}

// ================= VQ =================
__global__ __launch_bounds__(256) void make_Z(const float* __restrict__ ze, float* __restrict__ Z) {
  int idx = blockIdx.x * 256 + threadIdx.x;  // 524288 total
  int d = idx & 1023; int b = idx >> 10;
  int c = d & 63; int hw = d >> 6;
  Z[idx] = ze[(b << 10) + (c << 4) + hw];
}

__global__ __launch_bounds__(256) void vq_argmin(const float* __restrict__ Z,
    const float* __restrict__ cb, int* __restrict__ jout) {
  __shared__ float zsh[1024];
  int b = blockIdx.x;
  const float* zp = Z + ((long)b << 10);
  for (int i = threadIdx.x; i < 1024; i += 256) zsh[i] = zp[i];
  __syncthreads();
  float best = 3.4e38f; int bestk = 0;
  for (int k = threadIdx.x; k < 512; k += 256) {
    const float* w = cb + ((long)k << 10);
    float dot = 0.f, ccs = 0.f;
#pragma unroll 4
    for (int i = 0; i < 1024; ++i) {
      float wv = w[i];
      dot = fmaf(zsh[i], wv, dot);
      ccs = fmaf(wv, wv, ccs);
    }
    float dist = ccs - 2.0f * dot;
    if (dist < best) { best = dist; bestk = k; }
  }
  __shared__ float vsh[256]; __shared__ int ish[256];
  vsh[threadIdx.x] = best; ish[threadIdx.x] = bestk;
  __syncthreads();
  for (int srd = 128; srd > 0; srd >>= 1) {
    if (threadIdx.x < srd) {
      float ov = vsh[threadIdx.x + srd]; int oi = ish[threadIdx.x + srd];
      if (ov < vsh[threadIdx.x] || (ov == vsh[threadIdx.x] && oi < ish[threadIdx.x])) {
        vsh[threadIdx.x] = ov; ish[threadIdx.x] = oi;
      }
    }
    __syncthreads();
  }
  if (threadIdx.x == 0) jout[b] = ish[0];
}

__global__ __launch_bounds__(256) void vq_gather_loss(const float* __restrict__ Z,
    const float* __restrict__ cb, const int* __restrict__ jidx,
    float* __restrict__ Zq, float* __restrict__ lossAcc) {
  int b = blockIdx.x;
  int k = jidx[b];
  const float* w = cb + ((long)k << 10);
  const float* zp = Z + ((long)b << 10);
  float part = 0.f;
  for (int d = threadIdx.x; d < 1024; d += 256) {
    float wv = w[d];
    float diff = zp[d] - wv;
    part = fmaf(diff, diff, part);
    int c = d & 63; int hw = d >> 6;
    Zq[(b << 10) + (c << 4) + hw] = wv;
  }
#pragma unroll
  for (int o = 32; o > 0; o >>= 1) part += __shfl_down(part, o);
  __shared__ float sh[4];
  if ((threadIdx.x & 63) == 0) sh[threadIdx.x >> 6] = part;
  __syncthreads();
  if (threadIdx.x == 0) atomicAdd(lossAcc, sh[0] + sh[1] + sh[2] + sh[3]);
}

__global__ void write_losses(const float* __restrict__ lossAcc, float* __restrict__ out2) {
  float v = lossAcc[0] * (1.0f / 512.0f);
  out2[0] = v;
  out2[1] = v;
}

// ================= launch =================
extern "C" void kernel_launch(void* const* d_in, const int* in_sizes, int n_in,
                              void* d_out, int out_size, void* d_ws, size_t ws_size,
                              hipStream_t stream) {
  const float* x      = (const float*)d_in[0];
  const float* ce1_w  = (const float*)d_in[1];  const float* ce1_b = (const float*)d_in[2];
  const float* ce2_w  = (const float*)d_in[3];  const float* ce2_b = (const float*)d_in[4];
  const float* ce3_w  = (const float*)d_in[5];  const float* ce3_b = (const float*)d_in[6];
  const float* ce4_w  = (const float*)d_in[7];  const float* ce4_b = (const float*)d_in[8];
  const float* ce5_w  = (const float*)d_in[9];  const float* ce5_b = (const float*)d_in[10];
  const float* cd0_w  = (const float*)d_in[11]; const float* cd0_b = (const float*)d_in[12];
  const float* cd1_w  = (const float*)d_in[13]; const float* cd1_b = (const float*)d_in[14];
  const float* cd2_w  = (const float*)d_in[15]; const float* cd2_b = (const float*)d_in[16];
  const float* cd3_w  = (const float*)d_in[17]; const float* cd3_b = (const float*)d_in[18];
  const float* cd4_w  = (const float*)d_in[19]; const float* cd4_b = (const float*)d_in[20];
  const float* bn_e1_g = (const float*)d_in[21]; const float* bn_e1_b = (const float*)d_in[22];
  const float* bn_e2_g = (const float*)d_in[23]; const float* bn_e2_b = (const float*)d_in[24];
  const float* bn_e3_g = (const float*)d_in[25]; const float* bn_e3_b = (const float*)d_in[26];
  const float* bn_e4_g = (const float*)d_in[27]; const float* bn_e4_b = (const float*)d_in[28];
  const float* bn_e5_g = (const float*)d_in[29]; const float* bn_e5_b = (const float*)d_in[30];
  const float* bn_d0_g = (const float*)d_in[31]; const float* bn_d0_b = (const float*)d_in[32];
  const float* bn_d1_g = (const float*)d_in[33]; const float* bn_d1_b = (const float*)d_in[34];
  const float* bn_d2_g = (const float*)d_in[35]; const float* bn_d2_b = (const float*)d_in[36];
  const float* bn_d3_g = (const float*)d_in[37]; const float* bn_d3_b = (const float*)d_in[38];
  const float* codebook = (const float*)d_in[39];

  float* out = (float*)d_out;

  float* bufA    = (float*)d_ws;             // 16,777,216 floats
  float* bufB    = bufA + 16777216;          // 16,777,216 floats
  float* Z       = bufB + 16777216;          // 524,288 (reused for transformed weights post-VQ)
  float* Zq      = Z + 524288;               // 524,288
  float* stats   = Zq + 524288;              // 1024
  float* lossAcc = stats + 1024;             // 4
  int*   jbuf    = (int*)(lossAcc + 4);      // 512
  // transformed decoder weights overlay the Z region (Z dead after vq_gather_loss)
  float* cd1t = Z;                           // 294912
  float* cd2t = cd1t + 294912;               // 73728
  float* cd3t = cd2t + 73728;                // 18432
  float* cd4t = cd3t + 18432;                // 864

  auto bnstage = [&](float* buf, int C, int hwShift, const float* g, const float* b) {
    hipMemsetAsync(stats, 0, 2 * C * sizeof(float), stream);
    int chunks = 2048 / C; if (chunks < 1) chunks = 1;
    hipLaunchKernelGGL(bn_stats, dim3(C, chunks), dim3(256), 0, stream, buf, stats, C, hwShift);
    float inv_cnt = 1.0f / (float)((long)B_N << hwShift);
    hipLaunchKernelGGL(bn_finalize, dim3(1), dim3(C), 0, stream, stats, g, b, C, inv_cnt);
    long total = ((long)B_N * C) << hwShift;
    int grid = (int)((total + 255) / 256);
    hipLaunchKernelGGL(bn_apply, dim3(grid), dim3(256), 0, stream, buf, stats, C - 1, hwShift, total);
  };

  // ---- encoder ----
  conv4s2_rt<3, 32, 64, 8><<<dim3(2048, 4), 256, 0, stream>>>(x, ce1_w, ce1_b, bufA);
  bnstage(bufA, 32, 10, bn_e1_g, bn_e1_b);

  conv4s2_rt<32, 64, 32, 8><<<dim3(512, 8), 256, 0, stream>>>(bufA, ce2_w, ce2_b, bufB);
  bnstage(bufB, 64, 8, bn_e2_g, bn_e2_b);

  conv4s2_rt<64, 128, 16, 8><<<dim3(128, 16), 256, 0, stream>>>(bufB, ce3_w, ce3_b, bufA);
  bnstage(bufA, 128, 6, bn_e3_g, bn_e3_b);

  conv4s2_rt<128, 256, 8, 8><<<dim3(32, 32), 256, 0, stream>>>(bufA, ce4_w, ce4_b, bufB);
  bnstage(bufB, 256, 4, bn_e4_g, bn_e4_b);

  conv1x1_rt<256, 64, 8><<<dim3(32, 8), 256, 0, stream>>>(bufB, ce5_w, ce5_b, bufA);
  bnstage(bufA, 64, 4, bn_e5_g, bn_e5_b);

  // ---- VQ ----
  make_Z<<<2048, 256, 0, stream>>>(bufA, Z);
  vq_argmin<<<512, 256, 0, stream>>>(Z, codebook, jbuf);
  hipMemsetAsync(lossAcc, 0, sizeof(float), stream);
  vq_gather_loss<<<512, 256, 0, stream>>>(Z, codebook, jbuf, Zq, lossAcc);
  write_losses<<<1, 1, 0, stream>>>(lossAcc, out + 6291456);

  // ---- decoder weight transforms (Z region is dead now) ----
  wtrans<<<1152, 256, 0, stream>>>(cd1_w, cd1t, 128, 256);
  wtrans<<<288, 256, 0, stream>>>(cd2_w, cd2t, 64, 128);
  wtrans<<<72, 256, 0, stream>>>(cd3_w, cd3t, 32, 64);
  wtrans<<<4, 256, 0, stream>>>(cd4_w, cd4t, 3, 32);

  // ---- decoder ----
  conv1x1_rt<64, 256, 8><<<dim3(32, 32), 256, 0, stream>>>(Zq, cd0_w, cd0_b, bufA);
  bnstage(bufA, 256, 4, bn_d0_g, bn_d0_b);

  // cd1: Ci=256,Co=128,Hin=4 -> 8x8 out. Rco=4, CK=8, NB=1 -> 512 blocks
  dconv<256, 128, 4, 4, 8, 1, false><<<512, 256, 0, stream>>>(bufA, cd1t, cd1_b, bufB);
  bnstage(bufB, 128, 6, bn_d1_g, bn_d1_b);

  // cd2: Ci=128,Co=64,Hin=8 -> 16x16. Rco=8, CK=16, NB=2 -> 512 blocks
  dconv<128, 64, 8, 8, 16, 2, false><<<512, 256, 0, stream>>>(bufB, cd2t, cd2_b, bufA);
  bnstage(bufA, 64, 8, bn_d2_g, bn_d2_b);

  // cd3: Ci=64,Co=32,Hin=16 -> 32x32. Rco=8, CK=16, NB=2 -> 1024 blocks
  dconv<64, 32, 16, 8, 16, 2, false><<<1024, 256, 0, stream>>>(bufA, cd3t, cd3_b, bufB);
  bnstage(bufB, 32, 10, bn_d3_g, bn_d3_b);

  // cd4: Ci=32,Co=3,Hin=32 -> 64x64 + sigmoid. Rco=3, CK=8, NB=1 -> 1024 blocks
  dconv<32, 3, 32, 3, 8, 1, true><<<1024, 256, 0, stream>>>(bufB, cd4t, cd4_b, out);
}

// Round 3
// 1217.162 us; speedup vs baseline: 13.9274x; 2.1626x over previous
//
#include <hip/hip_runtime.h>
#include <hip/hip_bf16.h>
#include <math.h>

#define B_N 512

typedef __attribute__((ext_vector_type(8))) short bf16x8;
typedef __attribute__((ext_vector_type(4))) float f32x4;

__device__ __forceinline__ float bf2f(ushort u) {
  union { uint i; float f; } t; t.i = ((uint)u) << 16; return t.f;
}
__device__ __forceinline__ ushort f2bf(float f) {
  __hip_bfloat16 h = __float2bfloat16(f);
  return *reinterpret_cast<ushort*>(&h);
}
constexpr int ilog2c(int v) { int r = 0; while (v > 1) { v >>= 1; ++r; } return r; }

// =====================================================================
// Generic MFMA conv.  MODE: 0 = 1x1, 1 = enc k4s2p1, 2 = dec up2+3x3 (parity 2x2)
// Layout: activations NHWC.  SPLIT: values stored as uint (lo16=hi-bf16, hi16=lo-bf16),
// GEMM done with 3 MFMAs (hi*hi + hi*lo + lo*hi) for ~fp32 precision.
// Weights pre-transformed to [tap][Co][Ci] (bf16, or packed hi|lo uint when SPLIT).
// BN: scale/shift (+LReLU) applied to the INPUT during staging, coef = [scale[Ci], shift[Ci]].
// =====================================================================
template<int MODE, int Ci, int Co, int HIN, int COT, int PIXT, bool BN, bool SPLIT>
__global__ __launch_bounds__(256) void conv_mfma(
    const void* __restrict__ in_, const void* __restrict__ wt_,
    const float* __restrict__ bias, const float* __restrict__ coef,
    void* __restrict__ out_) {
  constexpr int T   = MODE == 1 ? 16 : (MODE == 2 ? 4 : 1);
  constexpr int HO  = MODE == 1 ? HIN / 2 : HIN;   // spatial of the pix index space
  constexpr int LHO = ilog2c(HO);
  constexpr int LHI = ilog2c(HIN);
  constexpr int CG  = COT / 16;
  constexpr int PG  = (PIXT / 4) / 16;
  constexpr int PLANES = SPLIT ? 2 : 1;
  constexpr int WK = (COT * 16) / 256;   // W stage iters
  constexpr int PK = (PIXT * 16) / 256;  // P stage iters
  static_assert((COT * 16) % 256 == 0 && (PIXT * 16) % 256 == 0, "stage");

  __shared__ __align__(16) ushort lA[PLANES][COT * 40];
  __shared__ __align__(16) ushort lB[PLANES][PIXT * 40];

  const int tid  = threadIdx.x;
  const int wave = tid >> 6;
  const int ln15 = tid & 15;
  const int quad = (tid & 63) >> 4;
  const int pixBase = blockIdx.x * PIXT;
  const int co0 = blockIdx.y * COT;
  const int par = (MODE == 2) ? blockIdx.z : 0;
  const int ph = par >> 1, pw = par & 1;
  const int cip = tid & 15;

  f32x4 acc[CG][PG];
#pragma unroll
  for (int cg = 0; cg < CG; ++cg) {
    const float* bp = &bias[co0 + cg * 16 + quad * 4];
    f32x4 bz; bz[0] = bp[0]; bz[1] = bp[1]; bz[2] = bp[2]; bz[3] = bp[3];
#pragma unroll
    for (int pg = 0; pg < PG; ++pg) acc[cg][pg] = bz;
  }

  for (int t = 0; t < T; ++t) {
    int kh, kw;
    if (MODE == 1) { kh = t >> 2; kw = t & 3; } else { kh = t >> 1; kw = t & 1; }
    const size_t wtap = (size_t)(par * T + t) * Co * Ci;

    for (int c0 = 0; c0 < Ci; c0 += 32) {
      __syncthreads();
      // ---- stage weights ----
      if (SPLIT) {
        const uint* ws = (const uint*)wt_ + wtap;
#pragma unroll
        for (int k = 0; k < WK; ++k) {
          int co = (tid + k * 256) >> 4;
          uint2 ab = *(const uint2*)&ws[(size_t)(co0 + co) * Ci + c0 + 2 * cip];
          ((uint*)&lA[0][0])[co * 20 + cip] = (ab.x & 0xffffu) | (ab.y << 16);
          ((uint*)&lA[1][0])[co * 20 + cip] = (ab.x >> 16) | (ab.y & 0xffff0000u);
        }
      } else {
        const uint* ws = (const uint*)((const ushort*)wt_ + wtap);
#pragma unroll
        for (int k = 0; k < WK; ++k) {
          int co = (tid + k * 256) >> 4;
          ((uint*)&lA[0][0])[co * 20 + cip] = ws[(((size_t)(co0 + co) * Ci + c0) >> 1) + cip];
        }
      }
      // ---- stage input patches (+BN +LReLU) ----
      {
        float sc0 = 0.f, sh0 = 0.f, sc1 = 0.f, sh1 = 0.f;
        if (BN) {
          int ci = c0 + 2 * cip;
          sc0 = coef[ci]; sh0 = coef[Ci + ci];
          sc1 = coef[ci + 1]; sh1 = coef[Ci + ci + 1];
        }
#pragma unroll
        for (int k = 0; k < PK; ++k) {
          int pl = (tid + k * 256) >> 4;
          int pix = pixBase + pl;
          size_t vbase = 0; bool ok = true;
          if (MODE == 0) {
            vbase = (size_t)pix * Ci + c0 + 2 * cip;
          } else {
            int w_ = pix & (HO - 1);
            int h_ = (pix >> LHO) & (HO - 1);
            int n_ = pix >> (2 * LHO);
            int ih, iw;
            if (MODE == 1) { ih = 2 * h_ - 1 + kh; iw = 2 * w_ - 1 + kw; }
            else           { ih = h_ + kh - 1 + ph; iw = w_ + kw - 1 + pw; }
            ok = ((unsigned)ih < (unsigned)HIN) && ((unsigned)iw < (unsigned)HIN);
            int sp = (((n_ << LHI) | (ih & (HIN - 1))) << LHI) | (iw & (HIN - 1));
            vbase = (size_t)sp * Ci + c0 + 2 * cip;
          }
          if (SPLIT) {
            uint2 ab = make_uint2(0u, 0u);
            if (ok) ab = *(const uint2*)&((const uint*)in_)[vbase];
            uint p0, p1;
            if (BN) {
              float f0 = bf2f((ushort)(ab.x & 0xffffu)) + bf2f((ushort)(ab.x >> 16));
              float f1 = bf2f((ushort)(ab.y & 0xffffu)) + bf2f((ushort)(ab.y >> 16));
              f0 = fmaf(f0, sc0, sh0); f1 = fmaf(f1, sc1, sh1);
              f0 = f0 > 0.f ? f0 : 0.01f * f0;
              f1 = f1 > 0.f ? f1 : 0.01f * f1;
              ushort h0 = f2bf(f0); ushort l0 = f2bf(f0 - bf2f(h0));
              ushort h1 = f2bf(f1); ushort l1 = f2bf(f1 - bf2f(h1));
              p0 = (uint)h0 | ((uint)h1 << 16);
              p1 = (uint)l0 | ((uint)l1 << 16);
            } else {
              p0 = (ab.x & 0xffffu) | (ab.y << 16);
              p1 = (ab.x >> 16) | (ab.y & 0xffff0000u);
            }
            ((uint*)&lB[0][0])[pl * 20 + cip] = p0;
            ((uint*)&lB[1][0])[pl * 20 + cip] = p1;
          } else {
            uint v = 0;
            if (ok) v = ((const uint*)in_)[vbase >> 1];
            if (BN) {
              float f0 = bf2f((ushort)(v & 0xffffu));
              float f1 = bf2f((ushort)(v >> 16));
              f0 = fmaf(f0, sc0, sh0); f1 = fmaf(f1, sc1, sh1);
              f0 = f0 > 0.f ? f0 : 0.01f * f0;
              f1 = f1 > 0.f ? f1 : 0.01f * f1;
              v = (uint)f2bf(f0) | ((uint)f2bf(f1) << 16);
            }
            ((uint*)&lB[0][0])[pl * 20 + cip] = v;
          }
        }
      }
      __syncthreads();
      // ---- MFMA ----
      bf16x8 ah[CG], bh[PG];
#pragma unroll
      for (int cg = 0; cg < CG; ++cg)
        ah[cg] = *(const bf16x8*)&lA[0][(cg * 16 + ln15) * 40 + quad * 8];
#pragma unroll
      for (int pg = 0; pg < PG; ++pg)
        bh[pg] = *(const bf16x8*)&lB[0][(wave * (PIXT / 4) + pg * 16 + ln15) * 40 + quad * 8];
      if (SPLIT) {
        bf16x8 al[CG], bl[PG];
#pragma unroll
        for (int cg = 0; cg < CG; ++cg)
          al[cg] = *(const bf16x8*)&lA[1][(cg * 16 + ln15) * 40 + quad * 8];
#pragma unroll
        for (int pg = 0; pg < PG; ++pg)
          bl[pg] = *(const bf16x8*)&lB[1][(wave * (PIXT / 4) + pg * 16 + ln15) * 40 + quad * 8];
#pragma unroll
        for (int cg = 0; cg < CG; ++cg)
#pragma unroll
          for (int pg = 0; pg < PG; ++pg) {
            acc[cg][pg] = __builtin_amdgcn_mfma_f32_16x16x32_bf16(ah[cg], bh[pg], acc[cg][pg], 0, 0, 0);
            acc[cg][pg] = __builtin_amdgcn_mfma_f32_16x16x32_bf16(ah[cg], bl[pg], acc[cg][pg], 0, 0, 0);
            acc[cg][pg] = __builtin_amdgcn_mfma_f32_16x16x32_bf16(al[cg], bh[pg], acc[cg][pg], 0, 0, 0);
          }
      } else {
#pragma unroll
        for (int cg = 0; cg < CG; ++cg)
#pragma unroll
          for (int pg = 0; pg < PG; ++pg)
            acc[cg][pg] = __builtin_amdgcn_mfma_f32_16x16x32_bf16(ah[cg], bh[pg], acc[cg][pg], 0, 0, 0);
      }
    }
  }

  // ---- epilogue: write NHWC (split-pair uints or bf16 pairs) ----
#pragma unroll
  for (int pg = 0; pg < PG; ++pg) {
    int pixl = wave * (PIXT / 4) + pg * 16 + ln15;
    int pix = pixBase + pixl;
    size_t rowAddr;
    if (MODE == 2) {
      int w_ = pix & (HO - 1);
      int h_ = (pix >> LHO) & (HO - 1);
      int n_ = pix >> (2 * LHO);
      int oh = 2 * h_ + ph, ow = 2 * w_ + pw;
      int sp = (((n_ << (LHI + 1)) | oh) << (LHI + 1)) | ow;
      rowAddr = (size_t)sp * Co;
    } else {
      rowAddr = (size_t)pix * Co;
    }
#pragma unroll
    for (int cg = 0; cg < CG; ++cg) {
      f32x4 a = acc[cg][pg];
      size_t addr = rowAddr + co0 + cg * 16 + quad * 4;
      if (SPLIT) {
        uint4 st;
        float v0 = a[0], v1 = a[1], v2 = a[2], v3 = a[3];
        ushort h0 = f2bf(v0), h1 = f2bf(v1), h2 = f2bf(v2), h3 = f2bf(v3);
        st.x = (uint)h0 | ((uint)f2bf(v0 - bf2f(h0)) << 16);
        st.y = (uint)h1 | ((uint)f2bf(v1 - bf2f(h1)) << 16);
        st.z = (uint)h2 | ((uint)f2bf(v2 - bf2f(h2)) << 16);
        st.w = (uint)h3 | ((uint)f2bf(v3 - bf2f(h3)) << 16);
        *(uint4*)&((uint*)out_)[addr] = st;
      } else {
        uint2 st;
        st.x = (uint)f2bf(a[0]) | ((uint)f2bf(a[1]) << 16);
        st.y = (uint)f2bf(a[2]) | ((uint)f2bf(a[3]) << 16);
        *(uint2*)&((ushort*)out_)[addr] = st;
      }
    }
  }
}

// ===================== ce1: k4s2p1, Ci=3, fp32 in (NCHW), split-pair out (NHWC) ==========
__global__ __launch_bounds__(256) void ce1_conv(const float* __restrict__ x,
    const float* __restrict__ w, const float* __restrict__ bias, uint* __restrict__ out) {
  __shared__ float lw[1536];
  __shared__ float lb[32];
  int tid = threadIdx.x;
#pragma unroll
  for (int k = 0; k < 6; ++k) lw[tid + k * 256] = w[tid + k * 256];
  if (tid < 32) lb[tid] = bias[tid];
  __syncthreads();
  int pix = blockIdx.x * 256 + tid;     // 512*32*32
  int w_ = pix & 31, h_ = (pix >> 5) & 31, n = pix >> 10;
  float v[48];
#pragma unroll
  for (int ci = 0; ci < 3; ++ci) {
    const float* xp = x + (((size_t)n * 3 + ci) << 12);
#pragma unroll
    for (int kh = 0; kh < 4; ++kh) {
      int ih = 2 * h_ - 1 + kh;
#pragma unroll
      for (int kw = 0; kw < 4; ++kw) {
        int iw = 2 * w_ - 1 + kw;
        bool okk = ((unsigned)ih < 64u) && ((unsigned)iw < 64u);
        v[ci * 16 + kh * 4 + kw] = okk ? xp[(ih << 6) + iw] : 0.f;
      }
    }
  }
  uint ub[32];
#pragma unroll
  for (int co = 0; co < 32; ++co) {
    float a = lb[co];
#pragma unroll
    for (int q = 0; q < 12; ++q) {
      float4 wv = *(const float4*)&lw[co * 48 + q * 4];
      a = fmaf(v[q * 4 + 0], wv.x, a);
      a = fmaf(v[q * 4 + 1], wv.y, a);
      a = fmaf(v[q * 4 + 2], wv.z, a);
      a = fmaf(v[q * 4 + 3], wv.w, a);
    }
    ushort h = f2bf(a);
    ub[co] = (uint)h | ((uint)f2bf(a - bf2f(h)) << 16);
  }
  uint4* op = (uint4*)&out[(size_t)pix * 32];
#pragma unroll
  for (int q = 0; q < 8; ++q)
    op[q] = make_uint4(ub[4 * q], ub[4 * q + 1], ub[4 * q + 2], ub[4 * q + 3]);
}

// ===================== cd4: parity 2x2 + sigmoid, bf16 NHWC in, fp32 NCHW out ==========
__global__ __launch_bounds__(256) void cd4_conv(const ushort* __restrict__ in,
    const ushort* __restrict__ wt, const float* __restrict__ bias,
    const float* __restrict__ coef, float* __restrict__ out) {
  __shared__ ushort lw[1536];
  __shared__ float lsc[32], lsh[32], lb[3];
  int tid = threadIdx.x;
#pragma unroll
  for (int k = 0; k < 6; ++k) lw[tid + k * 256] = wt[tid + k * 256];
  if (tid < 32) { lsc[tid] = coef[tid]; lsh[tid] = coef[32 + tid]; }
  if (tid < 3) lb[tid] = bias[tid];
  __syncthreads();
  int pix = blockIdx.x * 256 + tid;    // 512*64*64
  int ow = pix & 63, oh = (pix >> 6) & 63, n = pix >> 12;
  int pw_ = ow & 1, ph_ = oh & 1, w_ = ow >> 1, h_ = oh >> 1;
  int p = ph_ * 2 + pw_;
  float a0 = lb[0], a1 = lb[1], a2 = lb[2];
#pragma unroll
  for (int t = 0; t < 4; ++t) {
    int r = t >> 1, c = t & 1;
    int ih = h_ + r - 1 + ph_;
    int iw = w_ + c - 1 + pw_;
    if ((unsigned)ih < 32u && (unsigned)iw < 32u) {
      const uint* ip = (const uint*)&in[(size_t)((n * 32 + ih) * 32 + iw) * 32];
      const uint* w0 = (const uint*)&lw[((p * 4 + t) * 3 + 0) * 32];
      const uint* w1 = (const uint*)&lw[((p * 4 + t) * 3 + 1) * 32];
      const uint* w2 = (const uint*)&lw[((p * 4 + t) * 3 + 2) * 32];
#pragma unroll
      for (int cp2 = 0; cp2 < 16; ++cp2) {
        uint v = ip[cp2];
        float f0 = bf2f((ushort)(v & 0xffffu));
        float f1 = bf2f((ushort)(v >> 16));
        f0 = fmaf(f0, lsc[2 * cp2], lsh[2 * cp2]);
        f1 = fmaf(f1, lsc[2 * cp2 + 1], lsh[2 * cp2 + 1]);
        f0 = f0 > 0.f ? f0 : 0.01f * f0;
        f1 = f1 > 0.f ? f1 : 0.01f * f1;
        uint u0 = w0[cp2], u1 = w1[cp2], u2 = w2[cp2];
        a0 = fmaf(f0, bf2f((ushort)(u0 & 0xffffu)), a0);
        a0 = fmaf(f1, bf2f((ushort)(u0 >> 16)), a0);
        a1 = fmaf(f0, bf2f((ushort)(u1 & 0xffffu)), a1);
        a1 = fmaf(f1, bf2f((ushort)(u1 >> 16)), a1);
        a2 = fmaf(f0, bf2f((ushort)(u2 & 0xffffu)), a2);
        a2 = fmaf(f1, bf2f((ushort)(u2 >> 16)), a2);
      }
    }
  }
  a0 = 1.f / (1.f + __expf(-a0));
  a1 = 1.f / (1.f + __expf(-a1));
  a2 = 1.f / (1.f + __expf(-a2));
  size_t ob = ((size_t)n * 3) << 12;
  int sp = (oh << 6) | ow;
  out[ob + sp] = a0;
  out[ob + 4096 + sp] = a1;
  out[ob + 8192 + sp] = a2;
}

// ===================== weight transforms ==========
__global__ void enc_wt_sp(const float* __restrict__ w, uint* __restrict__ o,
                          int Co, int Ci, int T) {
  int idx = blockIdx.x * 256 + threadIdx.x;
  if (idx >= T * Co * Ci) return;
  int ci = idx % Ci; int r = idx / Ci; int co = r % Co; int t = r / Co;
  float f = w[(co * Ci + ci) * T + t];
  ushort h = f2bf(f);
  o[idx] = (uint)h | ((uint)f2bf(f - bf2f(h)) << 16);
}

__global__ void dec_wt(const float* __restrict__ w, ushort* __restrict__ o,
                       int Co, int Ci) {
  int idx = blockIdx.x * 256 + threadIdx.x;
  if (idx >= 16 * Co * Ci) return;
  int ci = idx % Ci; int r = idx / Ci; int co = r % Co; int pt = r / Co;
  int p = pt >> 2, t = pt & 3;
  int ph = p >> 1, pw = p & 1, rr = t >> 1, cc = t & 1;
  int rs = (rr == 0) ? 0 : (ph == 0 ? 1 : 2);
  int re = (rr == 0) ? (ph == 0 ? 1 : 2) : 3;
  int cs = (cc == 0) ? 0 : (pw == 0 ? 1 : 2);
  int ce = (cc == 0) ? (pw == 0 ? 1 : 2) : 3;
  float s = 0.f;
  for (int kh = rs; kh < re; ++kh)
    for (int kw = cs; kw < ce; ++kw)
      s += w[((co * Ci + ci) * 3 + kh) * 3 + kw];
  o[idx] = f2bf(s);
}

// ===================== BN stats ==========
// st layout: [8 slices][2][C]
__global__ __launch_bounds__(256) void bn_stats(const ushort* __restrict__ x,
    float* __restrict__ st, int C, long npairs) {
  int tid = threadIdx.x;
  int cpw = C >> 1;
  float s0 = 0.f, s1 = 0.f, q0 = 0.f, q1 = 0.f;
  const uint* xp = (const uint*)x;
  for (long i = (long)blockIdx.x * 256 + tid; i < npairs; i += (long)gridDim.x * 256) {
    uint v = xp[i];
    float f0 = bf2f((ushort)(v & 0xffffu));
    float f1 = bf2f((ushort)(v >> 16));
    s0 += f0; q0 = fmaf(f0, f0, q0);
    s1 += f1; q1 = fmaf(f1, f1, q1);
  }
  __shared__ float A0[256], A1[256], Q0[256], Q1[256];
  A0[tid] = s0; A1[tid] = s1; Q0[tid] = q0; Q1[tid] = q1;
  __syncthreads();
  for (int off = 128; off >= cpw; off >>= 1) {
    if (tid < off) {
      A0[tid] += A0[tid + off]; A1[tid] += A1[tid + off];
      Q0[tid] += Q0[tid + off]; Q1[tid] += Q1[tid + off];
    }
    __syncthreads();
  }
  if (tid < cpw) {
    float* d = st + (size_t)(blockIdx.x & 7) * 2 * C;
    atomicAdd(&d[2 * tid], A0[tid]);
    atomicAdd(&d[2 * tid + 1], A1[tid]);
    atomicAdd(&d[C + 2 * tid], Q0[tid]);
    atomicAdd(&d[C + 2 * tid + 1], Q1[tid]);
  }
}

__global__ __launch_bounds__(256) void bn_stats_sp(const uint* __restrict__ x,
    float* __restrict__ st, int C, long n) {
  int tid = threadIdx.x;
  float s = 0.f, q = 0.f;
  for (long i = (long)blockIdx.x * 256 + tid; i < n; i += (long)gridDim.x * 256) {
    uint v = x[i];
    float f = bf2f((ushort)(v & 0xffffu)) + bf2f((ushort)(v >> 16));
    s += f; q = fmaf(f, f, q);
  }
  __shared__ float S[256], Q[256];
  S[tid] = s; Q[tid] = q;
  __syncthreads();
  for (int off = 128; off >= C; off >>= 1) {
    if (tid < off) { S[tid] += S[tid + off]; Q[tid] += Q[tid + off]; }
    __syncthreads();
  }
  if (tid < C) {
    float* d = st + (size_t)(blockIdx.x & 7) * 2 * C;
    atomicAdd(&d[tid], S[tid]);
    atomicAdd(&d[C + tid], Q[tid]);
  }
}

__global__ void bn_finalize(const float* __restrict__ st, const float* __restrict__ g,
    const float* __restrict__ b, float* __restrict__ coef, int C, float inv_cnt) {
  int c = threadIdx.x;
  if (c >= C) return;
  float s = 0.f, q = 0.f;
  for (int sl = 0; sl < 8; ++sl) {
    s += st[(size_t)sl * 2 * C + c];
    q += st[(size_t)sl * 2 * C + C + c];
  }
  float m = s * inv_cnt;
  float var = fmaf(q, inv_cnt, -m * m);
  float sc = g[c] * rsqrtf(var + 1e-5f);
  coef[c] = sc;
  coef[C + c] = fmaf(-m, sc, b[c]);
}

// ===================== VQ ==========
__global__ __launch_bounds__(256) void make_Z(const uint* __restrict__ r5,
    const float* __restrict__ coef, float* __restrict__ Z) {
  int idx = blockIdx.x * 256 + threadIdx.x;   // 524288
  int c = idx & 63;
  uint v = r5[idx];
  float f = bf2f((ushort)(v & 0xffffu)) + bf2f((ushort)(v >> 16));
  f = fmaf(f, coef[c], coef[64 + c]);
  Z[idx] = f > 0.f ? f : 0.01f * f;
}

__global__ __launch_bounds__(256) void vq_argmin(const float* __restrict__ Z,
    const float* __restrict__ cb, int* __restrict__ jout) {
  __shared__ float zsh[1024];
  int b = blockIdx.x;
  const float* zp = Z + ((long)b << 10);
  for (int i = threadIdx.x; i < 1024; i += 256) zsh[i] = zp[i];
  __syncthreads();
  float best = 3.4e38f; int bestk = 0;
  for (int k = threadIdx.x; k < 512; k += 256) {
    const float* w = cb + ((long)k << 10);
    float dot = 0.f, ccs = 0.f;
#pragma unroll 4
    for (int i = 0; i < 1024; ++i) {
      float wv = w[i];
      dot = fmaf(zsh[i], wv, dot);
      ccs = fmaf(wv, wv, ccs);
    }
    float dist = ccs - 2.0f * dot;
    if (dist < best) { best = dist; bestk = k; }
  }
  __shared__ float vsh[256]; __shared__ int ish[256];
  vsh[threadIdx.x] = best; ish[threadIdx.x] = bestk;
  __syncthreads();
  for (int srd = 128; srd > 0; srd >>= 1) {
    if (threadIdx.x < srd) {
      float ov = vsh[threadIdx.x + srd]; int oi = ish[threadIdx.x + srd];
      if (ov < vsh[threadIdx.x] || (ov == vsh[threadIdx.x] && oi < ish[threadIdx.x])) {
        vsh[threadIdx.x] = ov; ish[threadIdx.x] = oi;
      }
    }
    __syncthreads();
  }
  if (threadIdx.x == 0) jout[b] = ish[0];
}

__global__ __launch_bounds__(256) void vq_gather_loss(const float* __restrict__ Z,
    const float* __restrict__ cb, const int* __restrict__ jidx,
    ushort* __restrict__ Zq, float* __restrict__ lossAcc) {
  int b = blockIdx.x;
  int k = jidx[b];
  const float* w = cb + ((long)k << 10);
  const float* zp = Z + ((long)b << 10);
  float part = 0.f;
  for (int d = threadIdx.x; d < 1024; d += 256) {
    float wv = w[d];
    float diff = zp[d] - wv;
    part = fmaf(diff, diff, part);
    Zq[(b << 10) + d] = f2bf(wv);
  }
#pragma unroll
  for (int o = 32; o > 0; o >>= 1) part += __shfl_down(part, o);
  __shared__ float sh[4];
  if ((threadIdx.x & 63) == 0) sh[threadIdx.x >> 6] = part;
  __syncthreads();
  if (threadIdx.x == 0) atomicAdd(lossAcc, sh[0] + sh[1] + sh[2] + sh[3]);
}

__global__ void write_losses(const float* __restrict__ lossAcc, float* __restrict__ out2) {
  float v = lossAcc[0] * (1.0f / 512.0f);
  out2[0] = v;
  out2[1] = v;
}

// ===================== launch ==========
extern "C" void kernel_launch(void* const* d_in, const int* in_sizes, int n_in,
                              void* d_out, int out_size, void* d_ws, size_t ws_size,
                              hipStream_t stream) {
  const float* x      = (const float*)d_in[0];
  const float* ce1_w  = (const float*)d_in[1];  const float* ce1_b = (const float*)d_in[2];
  const float* ce2_w  = (const float*)d_in[3];  const float* ce2_b = (const float*)d_in[4];
  const float* ce3_w  = (const float*)d_in[5];  const float* ce3_b = (const float*)d_in[6];
  const float* ce4_w  = (const float*)d_in[7];  const float* ce4_b = (const float*)d_in[8];
  const float* ce5_w  = (const float*)d_in[9];  const float* ce5_b = (const float*)d_in[10];
  const float* cd0_w  = (const float*)d_in[11]; const float* cd0_b = (const float*)d_in[12];
  const float* cd1_w  = (const float*)d_in[13]; const float* cd1_b = (const float*)d_in[14];
  const float* cd2_w  = (const float*)d_in[15]; const float* cd2_b = (const float*)d_in[16];
  const float* cd3_w  = (const float*)d_in[17]; const float* cd3_b = (const float*)d_in[18];
  const float* cd4_w  = (const float*)d_in[19]; const float* cd4_b = (const float*)d_in[20];
  const float* bn_e1_g = (const float*)d_in[21]; const float* bn_e1_b = (const float*)d_in[22];
  const float* bn_e2_g = (const float*)d_in[23]; const float* bn_e2_b = (const float*)d_in[24];
  const float* bn_e3_g = (const float*)d_in[25]; const float* bn_e3_b = (const float*)d_in[26];
  const float* bn_e4_g = (const float*)d_in[27]; const float* bn_e4_b = (const float*)d_in[28];
  const float* bn_e5_g = (const float*)d_in[29]; const float* bn_e5_b = (const float*)d_in[30];
  const float* bn_d0_g = (const float*)d_in[31]; const float* bn_d0_b = (const float*)d_in[32];
  const float* bn_d1_g = (const float*)d_in[33]; const float* bn_d1_b = (const float*)d_in[34];
  const float* bn_d2_g = (const float*)d_in[35]; const float* bn_d2_b = (const float*)d_in[36];
  const float* bn_d3_g = (const float*)d_in[37]; const float* bn_d3_b = (const float*)d_in[38];
  const float* codebook = (const float*)d_in[39];

  float* out = (float*)d_out;

  // ---- workspace carve ----
  char* p = (char*)d_ws;
  auto alloc = [&](size_t bytes) { void* r = p; p += (bytes + 255) & ~(size_t)255; return r; };
  uint*   r1   = (uint*)alloc((size_t)512 * 1024 * 32 * 4);   // 67.1 MB (split pairs, NHWC)
  uint*   r2   = (uint*)alloc((size_t)512 * 256 * 64 * 4);    // 33.6 MB
  uint*   r3   = (uint*)alloc((size_t)512 * 64 * 128 * 4);    // 16.8 MB
  uint*   r4   = (uint*)alloc((size_t)512 * 16 * 256 * 4);    // 8.4 MB
  uint*   r5   = (uint*)alloc((size_t)512 * 16 * 64 * 4);     // 2.1 MB
  ushort* Zq   = (ushort*)alloc((size_t)524288 * 2);
  float*  Z    = (float*)alloc((size_t)524288 * 4);
  uint*   wce2 = (uint*)alloc((size_t)16 * 64 * 32 * 4);
  uint*   wce3 = (uint*)alloc((size_t)16 * 128 * 64 * 4);
  uint*   wce4 = (uint*)alloc((size_t)16 * 256 * 128 * 4);
  uint*   wce5 = (uint*)alloc((size_t)64 * 256 * 4);
  ushort* wcd0 = (ushort*)alloc((size_t)256 * 64 * 2);
  ushort* wcd1 = (ushort*)alloc((size_t)16 * 128 * 256 * 2);
  ushort* wcd2 = (ushort*)alloc((size_t)16 * 64 * 128 * 2);
  ushort* wcd3 = (ushort*)alloc((size_t)16 * 32 * 64 * 2);
  ushort* wcd4 = (ushort*)alloc((size_t)16 * 3 * 32 * 2);
  float*  stats = (float*)alloc((size_t)4096 * 4);
  float*  coef  = (float*)alloc((size_t)512 * 4);
  float*  lossAcc = (float*)alloc(4);
  int*    jbuf = (int*)alloc((size_t)512 * 4);
  // decoder activations (bf16 NHWC) alias r1 (dead after ce2)
  ushort* d0 = (ushort*)r1;                                    // 8192*256
  ushort* d1 = (ushort*)((char*)r1 + 4194304);                 // 32768*128
  ushort* d2 = (ushort*)((char*)r1 + 4194304 + 8388608);       // 131072*64
  ushort* d3 = (ushort*)((char*)r1 + 4194304 + 8388608 + 16777216); // 524288*32

  auto bnstage_sp = [&](const uint* buf, int C, long nPix, const float* g, const float* b) {
    hipMemsetAsync(stats, 0, 4096 * sizeof(float), stream);
    bn_stats_sp<<<512, 256, 0, stream>>>(buf, stats, C, nPix * C);
    bn_finalize<<<1, C, 0, stream>>>(stats, g, b, coef, C, 1.0f / (float)nPix);
  };
  auto bnstage_bf = [&](const ushort* buf, int C, long nPix, const float* g, const float* b) {
    hipMemsetAsync(stats, 0, 4096 * sizeof(float), stream);
    bn_stats<<<512, 256, 0, stream>>>(buf, stats, C, nPix * (C >> 1));
    bn_finalize<<<1, C, 0, stream>>>(stats, g, b, coef, C, 1.0f / (float)nPix);
  };

  // ---- weight transforms ----
  enc_wt_sp<<<128, 256, 0, stream>>>(ce2_w, wce2, 64, 32, 16);
  enc_wt_sp<<<512, 256, 0, stream>>>(ce3_w, wce3, 128, 64, 16);
  enc_wt_sp<<<2048, 256, 0, stream>>>(ce4_w, wce4, 256, 128, 16);
  enc_wt_sp<<<64, 256, 0, stream>>>(ce5_w, wce5, 64, 256, 1);
  {
    // cd0 1x1: plain bf16 [Co][Ci]
    // reuse dec-style simple cast via enc path is split; do a tiny dedicated pass with dec_wt? no:
  }
  // cd0: cast fp32 [256][64] -> bf16 (tap-major T=1 layout == same flat)
  // (use enc_wt_sp's indexing but bf16 out -> small inline kernel below)
  {
    struct L { static __global__ void k(const float* w, ushort* o, int n) {
      int i = blockIdx.x * 256 + threadIdx.x; if (i < n) o[i] = f2bf(w[i]); } };
    L::k<<<64, 256, 0, stream>>>(cd0_w, wcd0, 16384);
  }
  dec_wt<<<2048, 256, 0, stream>>>(cd1_w, wcd1, 128, 256);
  dec_wt<<<512, 256, 0, stream>>>(cd2_w, wcd2, 64, 128);
  dec_wt<<<128, 256, 0, stream>>>(cd3_w, wcd3, 32, 64);
  dec_wt<<<6, 256, 0, stream>>>(cd4_w, wcd4, 3, 32);

  // ---- encoder ----
  ce1_conv<<<2048, 256, 0, stream>>>(x, ce1_w, ce1_b, r1);
  bnstage_sp(r1, 32, 524288, bn_e1_g, bn_e1_b);
  conv_mfma<1, 32, 64, 32, 64, 128, true, true><<<dim3(1024, 1, 1), 256, 0, stream>>>(r1, wce2, ce2_b, coef, r2);
  bnstage_sp(r2, 64, 131072, bn_e2_g, bn_e2_b);
  conv_mfma<1, 64, 128, 16, 64, 128, true, true><<<dim3(256, 2, 1), 256, 0, stream>>>(r2, wce3, ce3_b, coef, r3);
  bnstage_sp(r3, 128, 32768, bn_e3_g, bn_e3_b);
  conv_mfma<1, 128, 256, 8, 64, 128, true, true><<<dim3(64, 4, 1), 256, 0, stream>>>(r3, wce4, ce4_b, coef, r4);
  bnstage_sp(r4, 256, 8192, bn_e4_g, bn_e4_b);
  conv_mfma<0, 256, 64, 4, 64, 128, true, true><<<dim3(64, 1, 1), 256, 0, stream>>>(r4, wce5, ce5_b, coef, r5);
  bnstage_sp(r5, 64, 8192, bn_e5_g, bn_e5_b);

  // ---- VQ ----
  make_Z<<<2048, 256, 0, stream>>>(r5, coef, Z);
  vq_argmin<<<512, 256, 0, stream>>>(Z, codebook, jbuf);
  hipMemsetAsync(lossAcc, 0, sizeof(float), stream);
  vq_gather_loss<<<512, 256, 0, stream>>>(Z, codebook, jbuf, Zq, lossAcc);
  write_losses<<<1, 1, 0, stream>>>(lossAcc, out + 6291456);

  // ---- decoder ----
  conv_mfma<0, 64, 256, 4, 64, 128, false, false><<<dim3(64, 4, 1), 256, 0, stream>>>(Zq, wcd0, cd0_b, coef, d0);
  bnstage_bf(d0, 256, 8192, bn_d0_g, bn_d0_b);
  conv_mfma<2, 256, 128, 4, 64, 128, true, false><<<dim3(64, 2, 4), 256, 0, stream>>>(d0, wcd1, cd1_b, coef, d1);
  bnstage_bf(d1, 128, 32768, bn_d1_g, bn_d1_b);
  conv_mfma<2, 128, 64, 8, 64, 128, true, false><<<dim3(256, 1, 4), 256, 0, stream>>>(d1, wcd2, cd2_b, coef, d2);
  bnstage_bf(d2, 64, 131072, bn_d2_g, bn_d2_b);
  conv_mfma<2, 64, 32, 16, 32, 128, true, false><<<dim3(1024, 1, 4), 256, 0, stream>>>(d2, wcd3, cd3_b, coef, d3);
  bnstage_bf(d3, 32, 524288, bn_d3_g, bn_d3_b);
  cd4_conv<<<8192, 256, 0, stream>>>(d3, wcd4, cd4_b, coef, out);
}

// Round 4
// 885.327 us; speedup vs baseline: 19.1477x; 1.3748x over previous
//
#include <hip/hip_runtime.h>
#include <hip/hip_bf16.h>
#include <math.h>

typedef __attribute__((ext_vector_type(8))) short bf16x8;
typedef __attribute__((ext_vector_type(4))) float f32x4;

__device__ __forceinline__ float bf2f(ushort u) {
  union { uint i; float f; } t; t.i = ((uint)u) << 16; return t.f;
}
__device__ __forceinline__ ushort f2bf(float f) {
  __hip_bfloat16 h = __float2bfloat16(f);
  return *reinterpret_cast<ushort*>(&h);
}
__device__ __forceinline__ uint pk(float a, float b) {
  return (uint)f2bf(a) | ((uint)f2bf(b) << 16);
}
constexpr int ilog2c(int v) { int r = 0; while (v > 1) { v >>= 1; ++r; } return r; }

// =====================================================================
// Tiled MFMA conv. MODE 1: k4s2p1 encoder. MODE 2: up2+3x3 decoder via
// 4 parity classes x 2x2 pre-combined taps (wave = parity).
// Activations bf16 NHWC (post-BN). Input tile staged to LDS once per
// 32-ci chunk, reused across all taps. Weight A-frags direct from global
// (layout [tap][Co][Ci], bf16). Pixel pitch 40 ushorts (16B-aligned frags).
// =====================================================================
template<int MODE, int Ci, int Co, int HIN, int TR, int WM, int WN>
__global__ __launch_bounds__(256) void tconv(const ushort* __restrict__ in,
    const ushort* __restrict__ wt, const float* __restrict__ bias,
    ushort* __restrict__ out) {
  constexpr int W    = (MODE == 1) ? HIN / 2 : HIN;   // output-grid width
  constexpr int LW   = ilog2c(W);
  constexpr int R_IN = (MODE == 1) ? 2 * TR + 2 : TR + 2;
  constexpr int W2   = HIN + 2;
  constexpr int MT   = TR * W / 16;
  constexpr int NG   = Co / 16;
  constexpr int TAPS = (MODE == 1) ? 16 : 4;
  constexpr int RB   = W / TR;
  static_assert(TR * W % 16 == 0, "mtile");
  static_assert(MODE == 2 ? (WM == MT && WN == NG)
                          : ((MT % WM == 0) && (NG % WN == 0) && (MT / WM) * (NG / WN) == 4),
                "wave map");

  __shared__ ushort lt[R_IN * W2 * 40];

  const int tid  = threadIdx.x;
  const int wave = tid >> 6;
  const int ln15 = tid & 15;
  const int quad = (tid & 63) >> 4;
  const int rb = blockIdx.x % RB;
  const int n  = blockIdx.x / RB;
  const int h0 = rb * TR;
  int mt0, cg0, ph, pw, pb;
  if (MODE == 2) { mt0 = 0; cg0 = 0; ph = wave >> 1; pw = wave & 1; pb = wave * 4; }
  else {
    constexpr int MW = (MT / WM > 0) ? MT / WM : 1;
    mt0 = (wave % MW) * WM; cg0 = (wave / MW) * WN; ph = 0; pw = 0; pb = 0;
  }

  f32x4 acc[WM][WN];
#pragma unroll
  for (int j = 0; j < WN; ++j) {
    f32x4 b4 = *(const f32x4*)&bias[(cg0 + j) * 16 + quad * 4];
#pragma unroll
    for (int i = 0; i < WM; ++i) acc[i][j] = b4;
  }

  const uint* src = (const uint*)in;
  const int gr0 = (MODE == 1) ? 2 * h0 - 1 : h0 - 1;

#pragma unroll 1
  for (int c0 = 0; c0 < Ci; c0 += 32) {
    __syncthreads();
    constexpr int SN = R_IN * W2 * 16;
    for (int i = tid; i < SN; i += 256) {
      int ciu = i & 15; int t2 = i >> 4; int c = t2 % W2; int r = t2 / W2;
      int gr = gr0 + r, gc = c - 1;
      uint v = 0;
      if ((unsigned)gr < (unsigned)HIN && (unsigned)gc < (unsigned)HIN)
        v = src[((size_t)(n * HIN + gr) * HIN + gc) * (Ci / 2) + (c0 >> 1) + ciu];
      ((uint*)lt)[(r * W2 + c) * 20 + ciu] = v;
    }
    __syncthreads();

#pragma unroll
    for (int t = 0; t < TAPS; ++t) {
      const int kh = (MODE == 1) ? (t >> 2) : (t >> 1);
      const int kw = (MODE == 1) ? (t & 3) : (t & 1);
      bf16x8 af[WN];
      const ushort* wb = wt + (size_t)(pb + t) * Co * Ci;
#pragma unroll
      for (int j = 0; j < WN; ++j)
        af[j] = *(const bf16x8*)&wb[(size_t)((cg0 + j) * 16 + ln15) * Ci + c0 + quad * 8];
      bf16x8 bfr[WM];
#pragma unroll
      for (int i = 0; i < WM; ++i) {
        int m = (mt0 + i) * 16 + ln15;
        int hr = m >> LW, wr = m & (W - 1);
        int row, col;
        if (MODE == 1) { row = 2 * hr + kh; col = 2 * wr + kw; }
        else           { row = hr + kh + ph; col = wr + kw + pw; }
        bfr[i] = *(const bf16x8*)&lt[(row * W2 + col) * 40 + quad * 8];
      }
#pragma unroll
      for (int i = 0; i < WM; ++i)
#pragma unroll
        for (int j = 0; j < WN; ++j)
          acc[i][j] = __builtin_amdgcn_mfma_f32_16x16x32_bf16(af[j], bfr[i], acc[i][j], 0, 0, 0);
    }
  }

  // epilogue: bf16 NHWC
#pragma unroll
  for (int i = 0; i < WM; ++i) {
    int m = (mt0 + i) * 16 + ln15;
    int hr = m >> LW, wr = m & (W - 1);
    size_t sp;
    if (MODE == 2) {
      int oh = 2 * (h0 + hr) + ph, ow = 2 * wr + pw;
      sp = ((size_t)n * (2 * HIN) + oh) * (2 * HIN) + ow;
    } else {
      sp = ((size_t)n * W + h0 + hr) * W + wr;
    }
#pragma unroll
    for (int j = 0; j < WN; ++j) {
      f32x4 a = acc[i][j];
      uint2 st; st.x = pk(a[0], a[1]); st.y = pk(a[2], a[3]);
      *(uint2*)&out[sp * Co + (cg0 + j) * 16 + quad * 4] = st;
    }
  }
}

// ===================== 1x1 conv GEMM (ce5 / cd0) =====================
template<int Ci, int Co, int COT>
__global__ __launch_bounds__(256) void g1x1(const ushort* __restrict__ in,
    const ushort* __restrict__ wt, const float* __restrict__ bias,
    ushort* __restrict__ out) {
  constexpr int NG = COT / 16;
  __shared__ ushort lb[64 * 40];
  const int tid = threadIdx.x, wave = tid >> 6, ln15 = tid & 15, quad = (tid & 63) >> 4;
  const int pixBase = blockIdx.x * 64;
  const int co0 = blockIdx.y * COT;
  f32x4 acc[NG];
#pragma unroll
  for (int j = 0; j < NG; ++j) acc[j] = *(const f32x4*)&bias[co0 + j * 16 + quad * 4];
  const uint* src = (const uint*)in;
#pragma unroll 1
  for (int c0 = 0; c0 < Ci; c0 += 32) {
    __syncthreads();
    for (int i = tid; i < 1024; i += 256) {
      int ciu = i & 15, pl = i >> 4;
      ((uint*)lb)[pl * 20 + ciu] = src[(size_t)(pixBase + pl) * (Ci / 2) + (c0 >> 1) + ciu];
    }
    __syncthreads();
    bf16x8 bfr = *(const bf16x8*)&lb[(wave * 16 + ln15) * 40 + quad * 8];
#pragma unroll
    for (int j = 0; j < NG; ++j) {
      bf16x8 af = *(const bf16x8*)&wt[(size_t)(co0 + j * 16 + ln15) * Ci + c0 + quad * 8];
      acc[j] = __builtin_amdgcn_mfma_f32_16x16x32_bf16(af, bfr, acc[j], 0, 0, 0);
    }
  }
  int pix = pixBase + wave * 16 + ln15;
#pragma unroll
  for (int j = 0; j < NG; ++j) {
    uint2 st; st.x = pk(acc[j][0], acc[j][1]); st.y = pk(acc[j][2], acc[j][3]);
    *(uint2*)&out[(size_t)pix * Co + co0 + j * 16 + quad * 4] = st;
  }
}

// ===================== ce1: k4s2p1, Ci=3, fp32 NCHW in -> bf16 NHWC ==========
__global__ __launch_bounds__(256) void ce1_conv(const float* __restrict__ x,
    const float* __restrict__ w, const float* __restrict__ bias, uint* __restrict__ out) {
  __shared__ float lw[1536];
  __shared__ float lb[32];
  int tid = threadIdx.x;
#pragma unroll
  for (int k = 0; k < 6; ++k) lw[tid + k * 256] = w[tid + k * 256];
  if (tid < 32) lb[tid] = bias[tid];
  __syncthreads();
  int pix = blockIdx.x * 256 + tid;     // 512*32*32
  int w_ = pix & 31, h_ = (pix >> 5) & 31, n = pix >> 10;
  float v[48];
#pragma unroll
  for (int ci = 0; ci < 3; ++ci) {
    const float* xp = x + (((size_t)n * 3 + ci) << 12);
#pragma unroll
    for (int kh = 0; kh < 4; ++kh) {
      int ih = 2 * h_ - 1 + kh;
#pragma unroll
      for (int kw = 0; kw < 4; ++kw) {
        int iw = 2 * w_ - 1 + kw;
        bool okk = ((unsigned)ih < 64u) && ((unsigned)iw < 64u);
        v[ci * 16 + kh * 4 + kw] = okk ? xp[(ih << 6) + iw] : 0.f;
      }
    }
  }
  uint ub[16];
#pragma unroll
  for (int cp = 0; cp < 16; ++cp) {
    float a[2];
#pragma unroll
    for (int s = 0; s < 2; ++s) {
      int co = 2 * cp + s;
      float ac = lb[co];
#pragma unroll
      for (int q = 0; q < 12; ++q) {
        float4 wv = *(const float4*)&lw[co * 48 + q * 4];
        ac = fmaf(v[q * 4 + 0], wv.x, ac);
        ac = fmaf(v[q * 4 + 1], wv.y, ac);
        ac = fmaf(v[q * 4 + 2], wv.z, ac);
        ac = fmaf(v[q * 4 + 3], wv.w, ac);
      }
      a[s] = ac;
    }
    ub[cp] = pk(a[0], a[1]);
  }
  uint4* op = (uint4*)&out[(size_t)pix * 16];
#pragma unroll
  for (int q = 0; q < 4; ++q)
    op[q] = make_uint4(ub[4 * q], ub[4 * q + 1], ub[4 * q + 2], ub[4 * q + 3]);
}

// ===================== cd4: parity 2x2 + sigmoid, bf16 NHWC -> fp32 NCHW ==========
__global__ __launch_bounds__(256) void cd4_conv(const ushort* __restrict__ in,
    const ushort* __restrict__ wt, const float* __restrict__ bias,
    float* __restrict__ out) {
  __shared__ ushort lw[1536];
  __shared__ float lb[3];
  int tid = threadIdx.x;
#pragma unroll
  for (int k = 0; k < 6; ++k) lw[tid + k * 256] = wt[tid + k * 256];
  if (tid < 3) lb[tid] = bias[tid];
  __syncthreads();
  int pix = blockIdx.x * 256 + tid;    // 512*64*64
  int ow = pix & 63, oh = (pix >> 6) & 63, n = pix >> 12;
  int pw_ = ow & 1, ph_ = oh & 1, w_ = ow >> 1, h_ = oh >> 1;
  int p = ph_ * 2 + pw_;
  float a0 = lb[0], a1 = lb[1], a2 = lb[2];
#pragma unroll
  for (int t = 0; t < 4; ++t) {
    int r = t >> 1, c = t & 1;
    int ih = h_ + r - 1 + ph_;
    int iw = w_ + c - 1 + pw_;
    if ((unsigned)ih < 32u && (unsigned)iw < 32u) {
      const uint* ip = (const uint*)&in[(size_t)((n * 32 + ih) * 32 + iw) * 32];
      const uint* w0 = (const uint*)&lw[((p * 4 + t) * 3 + 0) * 32];
      const uint* w1 = (const uint*)&lw[((p * 4 + t) * 3 + 1) * 32];
      const uint* w2 = (const uint*)&lw[((p * 4 + t) * 3 + 2) * 32];
#pragma unroll
      for (int cp2 = 0; cp2 < 16; ++cp2) {
        uint vv = ip[cp2];
        float f0 = bf2f((ushort)(vv & 0xffffu));
        float f1 = bf2f((ushort)(vv >> 16));
        uint u0 = w0[cp2], u1 = w1[cp2], u2 = w2[cp2];
        a0 = fmaf(f0, bf2f((ushort)(u0 & 0xffffu)), a0);
        a0 = fmaf(f1, bf2f((ushort)(u0 >> 16)), a0);
        a1 = fmaf(f0, bf2f((ushort)(u1 & 0xffffu)), a1);
        a1 = fmaf(f1, bf2f((ushort)(u1 >> 16)), a1);
        a2 = fmaf(f0, bf2f((ushort)(u2 & 0xffffu)), a2);
        a2 = fmaf(f1, bf2f((ushort)(u2 >> 16)), a2);
      }
    }
  }
  a0 = 1.f / (1.f + __expf(-a0));
  a1 = 1.f / (1.f + __expf(-a1));
  a2 = 1.f / (1.f + __expf(-a2));
  size_t ob = ((size_t)n * 3) << 12;
  int sp = (oh << 6) | ow;
  out[ob + sp] = a0;
  out[ob + 4096 + sp] = a1;
  out[ob + 8192 + sp] = a2;
}

// ===================== weight transforms ==========
__global__ void enc_wt(const float* __restrict__ w, ushort* __restrict__ o, int Co, int Ci) {
  int idx = blockIdx.x * 256 + threadIdx.x;
  if (idx >= 16 * Co * Ci) return;
  int ci = idx % Ci; int r = idx / Ci; int co = r % Co; int t = r / Co;
  o[idx] = f2bf(w[(co * Ci + ci) * 16 + t]);
}

__global__ void dec_wt(const float* __restrict__ w, ushort* __restrict__ o, int Co, int Ci) {
  int idx = blockIdx.x * 256 + threadIdx.x;
  if (idx >= 16 * Co * Ci) return;
  int ci = idx % Ci; int r = idx / Ci; int co = r % Co; int pt = r / Co;
  int p = pt >> 2, t = pt & 3;
  int ph = p >> 1, pw = p & 1, rr = t >> 1, cc = t & 1;
  int rs = (rr == 0) ? 0 : (ph == 0 ? 1 : 2);
  int re = (rr == 0) ? (ph == 0 ? 1 : 2) : 3;
  int cs = (cc == 0) ? 0 : (pw == 0 ? 1 : 2);
  int ce = (cc == 0) ? (pw == 0 ? 1 : 2) : 3;
  float s = 0.f;
  for (int kh = rs; kh < re; ++kh)
    for (int kw = cs; kw < ce; ++kw)
      s += w[((co * Ci + ci) * 3 + kh) * 3 + kw];
  o[idx] = f2bf(s);
}

__global__ void bf16cast(const float* __restrict__ w, ushort* __restrict__ o, int n) {
  int i = blockIdx.x * 256 + threadIdx.x;
  if (i < n) o[i] = f2bf(w[i]);
}

// ===================== BatchNorm ==========
__global__ __launch_bounds__(256) void bn_stats(const ushort* __restrict__ x,
    float* __restrict__ st, int C, long npairs) {
  int tid = threadIdx.x;
  int cpw = C >> 1;
  float s0 = 0.f, s1 = 0.f, q0 = 0.f, q1 = 0.f;
  const uint* xp = (const uint*)x;
  for (long i = (long)blockIdx.x * 256 + tid; i < npairs; i += (long)gridDim.x * 256) {
    uint v = xp[i];
    float f0 = bf2f((ushort)(v & 0xffffu));
    float f1 = bf2f((ushort)(v >> 16));
    s0 += f0; q0 = fmaf(f0, f0, q0);
    s1 += f1; q1 = fmaf(f1, f1, q1);
  }
  __shared__ float A0[256], A1[256], Q0[256], Q1[256];
  A0[tid] = s0; A1[tid] = s1; Q0[tid] = q0; Q1[tid] = q1;
  __syncthreads();
  for (int off = 128; off >= cpw; off >>= 1) {
    if (tid < off) {
      A0[tid] += A0[tid + off]; A1[tid] += A1[tid + off];
      Q0[tid] += Q0[tid + off]; Q1[tid] += Q1[tid + off];
    }
    __syncthreads();
  }
  if (tid < cpw) {
    float* d = st + (size_t)(blockIdx.x & 7) * 2 * C;
    atomicAdd(&d[2 * tid], A0[tid]);
    atomicAdd(&d[2 * tid + 1], A1[tid]);
    atomicAdd(&d[C + 2 * tid], Q0[tid]);
    atomicAdd(&d[C + 2 * tid + 1], Q1[tid]);
  }
}

__global__ void bn_finalize(const float* __restrict__ st, const float* __restrict__ g,
    const float* __restrict__ b, float* __restrict__ coef, int C, float inv_cnt) {
  int c = threadIdx.x;
  if (c >= C) return;
  float s = 0.f, q = 0.f;
  for (int sl = 0; sl < 8; ++sl) {
    s += st[(size_t)sl * 2 * C + c];
    q += st[(size_t)sl * 2 * C + C + c];
  }
  float m = s * inv_cnt;
  float var = fmaf(q, inv_cnt, -m * m);
  float sc = g[c] * rsqrtf(var + 1e-5f);
  coef[c] = sc;
  coef[C + c] = fmaf(-m, sc, b[c]);
}

__global__ __launch_bounds__(256) void bn_apply(uint* __restrict__ x,
    const float* __restrict__ coef, int C, long nU) {
  long i = (long)blockIdx.x * 256 + threadIdx.x;
  if (i >= nU) return;
  int cp = (int)(i & (long)(C / 2 - 1));
  int c = 2 * cp;
  uint v = x[i];
  float f0 = fmaf(bf2f((ushort)(v & 0xffffu)), coef[c], coef[C + c]);
  float f1 = fmaf(bf2f((ushort)(v >> 16)), coef[c + 1], coef[C + c + 1]);
  f0 = f0 > 0.f ? f0 : 0.01f * f0;
  f1 = f1 > 0.f ? f1 : 0.01f * f1;
  x[i] = pk(f0, f1);
}

// ===================== VQ ==========
__global__ void make_Z(const ushort* __restrict__ r5, float* __restrict__ Z) {
  int i = blockIdx.x * 256 + threadIdx.x;   // 524288
  Z[i] = bf2f(r5[i]);
}

__global__ void cb_tr(const float* __restrict__ cb, float* __restrict__ cbT) {
  int idx = blockIdx.x * 256 + threadIdx.x;  // 524288
  int d = idx & 1023, k = idx >> 10;
  cbT[d * 512 + k] = cb[idx];
}

__global__ __launch_bounds__(256) void cb_wsq(const float* __restrict__ cb,
                                              float* __restrict__ wsq) {
  int k = blockIdx.x;
  float s = 0.f;
  for (int d = threadIdx.x; d < 1024; d += 256) {
    float v = cb[k * 1024 + d];
    s = fmaf(v, v, s);
  }
#pragma unroll
  for (int o = 32; o > 0; o >>= 1) s += __shfl_down(s, o);
  __shared__ float sh[4];
  if ((threadIdx.x & 63) == 0) sh[threadIdx.x >> 6] = s;
  __syncthreads();
  if (threadIdx.x == 0) wsq[k] = sh[0] + sh[1] + sh[2] + sh[3];
}

// 8 images per block; coalesced codebook reads via cbT [d][k].
__global__ __launch_bounds__(256) void vq_argmin8(const float* __restrict__ Z,
    const float* __restrict__ cbT, const float* __restrict__ wsq,
    int* __restrict__ jout) {
  __shared__ float zsh[8192];
  __shared__ float vsh[256];
  __shared__ int ish[256];
  int tid = threadIdx.x;
  int bb0 = blockIdx.x * 8;
  for (int i = tid; i < 8192; i += 256) zsh[i] = Z[(size_t)bb0 * 1024 + i];
  __syncthreads();
  int k1 = tid, k2 = tid + 256;
  float dA[8], dB[8];
#pragma unroll
  for (int b = 0; b < 8; ++b) { dA[b] = 0.f; dB[b] = 0.f; }
  for (int d = 0; d < 1024; ++d) {
    float w1 = cbT[d * 512 + k1];
    float w2 = cbT[d * 512 + k2];
#pragma unroll
    for (int b = 0; b < 8; ++b) {
      float z = zsh[b * 1024 + d];
      dA[b] = fmaf(z, w1, dA[b]);
      dB[b] = fmaf(z, w2, dB[b]);
    }
  }
  float q1 = wsq[k1], q2 = wsq[k2];
  for (int b = 0; b < 8; ++b) {
    float f1 = fmaf(-2.f, dA[b], q1);
    float f2 = fmaf(-2.f, dB[b], q2);
    float bv = (f2 < f1) ? f2 : f1;    // tie -> k1 (smaller)
    int bk = (f2 < f1) ? k2 : k1;
    vsh[tid] = bv; ish[tid] = bk;
    __syncthreads();
    for (int s = 128; s > 0; s >>= 1) {
      if (tid < s) {
        float ov = vsh[tid + s]; int oi = ish[tid + s];
        if (ov < vsh[tid] || (ov == vsh[tid] && oi < ish[tid])) { vsh[tid] = ov; ish[tid] = oi; }
      }
      __syncthreads();
    }
    if (tid == 0) jout[bb0 + b] = ish[0];
    __syncthreads();
  }
}

__global__ __launch_bounds__(256) void vq_gather_loss(const float* __restrict__ Z,
    const float* __restrict__ cb, const int* __restrict__ jidx,
    ushort* __restrict__ Zq, float* __restrict__ lossAcc) {
  int b = blockIdx.x;
  int k = jidx[b];
  const float* w = cb + ((long)k << 10);
  const float* zp = Z + ((long)b << 10);
  float part = 0.f;
  for (int d = threadIdx.x; d < 1024; d += 256) {
    float wv = w[d];
    float diff = zp[d] - wv;
    part = fmaf(diff, diff, part);
    Zq[(b << 10) + d] = f2bf(wv);
  }
#pragma unroll
  for (int o = 32; o > 0; o >>= 1) part += __shfl_down(part, o);
  __shared__ float sh[4];
  if ((threadIdx.x & 63) == 0) sh[threadIdx.x >> 6] = part;
  __syncthreads();
  if (threadIdx.x == 0) atomicAdd(lossAcc, sh[0] + sh[1] + sh[2] + sh[3]);
}

__global__ void write_losses(const float* __restrict__ lossAcc, float* __restrict__ out2) {
  float v = lossAcc[0] * (1.0f / 512.0f);
  out2[0] = v;
  out2[1] = v;
}

// ===================== launch ==========
extern "C" void kernel_launch(void* const* d_in, const int* in_sizes, int n_in,
                              void* d_out, int out_size, void* d_ws, size_t ws_size,
                              hipStream_t stream) {
  const float* x      = (const float*)d_in[0];
  const float* ce1_w  = (const float*)d_in[1];  const float* ce1_b = (const float*)d_in[2];
  const float* ce2_w  = (const float*)d_in[3];  const float* ce2_b = (const float*)d_in[4];
  const float* ce3_w  = (const float*)d_in[5];  const float* ce3_b = (const float*)d_in[6];
  const float* ce4_w  = (const float*)d_in[7];  const float* ce4_b = (const float*)d_in[8];
  const float* ce5_w  = (const float*)d_in[9];  const float* ce5_b = (const float*)d_in[10];
  const float* cd0_w  = (const float*)d_in[11]; const float* cd0_b = (const float*)d_in[12];
  const float* cd1_w  = (const float*)d_in[13]; const float* cd1_b = (const float*)d_in[14];
  const float* cd2_w  = (const float*)d_in[15]; const float* cd2_b = (const float*)d_in[16];
  const float* cd3_w  = (const float*)d_in[17]; const float* cd3_b = (const float*)d_in[18];
  const float* cd4_w  = (const float*)d_in[19]; const float* cd4_b = (const float*)d_in[20];
  const float* bn_e1_g = (const float*)d_in[21]; const float* bn_e1_b = (const float*)d_in[22];
  const float* bn_e2_g = (const float*)d_in[23]; const float* bn_e2_b = (const float*)d_in[24];
  const float* bn_e3_g = (const float*)d_in[25]; const float* bn_e3_b = (const float*)d_in[26];
  const float* bn_e4_g = (const float*)d_in[27]; const float* bn_e4_b = (const float*)d_in[28];
  const float* bn_e5_g = (const float*)d_in[29]; const float* bn_e5_b = (const float*)d_in[30];
  const float* bn_d0_g = (const float*)d_in[31]; const float* bn_d0_b = (const float*)d_in[32];
  const float* bn_d1_g = (const float*)d_in[33]; const float* bn_d1_b = (const float*)d_in[34];
  const float* bn_d2_g = (const float*)d_in[35]; const float* bn_d2_b = (const float*)d_in[36];
  const float* bn_d3_g = (const float*)d_in[37]; const float* bn_d3_b = (const float*)d_in[38];
  const float* codebook = (const float*)d_in[39];

  float* out = (float*)d_out;

  // ---- workspace carve (all bf16 NHWC activations) ----
  char* p = (char*)d_ws;
  auto alloc = [&](size_t bytes) { void* r = p; p += (bytes + 255) & ~(size_t)255; return r; };
  ushort* r1 = (ushort*)alloc((size_t)524288 * 32 * 2);   // 33.6 MB
  ushort* r2 = (ushort*)alloc((size_t)131072 * 64 * 2);   // 16.8 MB
  ushort* r3 = (ushort*)alloc((size_t)32768 * 128 * 2);   // 8.4 MB
  ushort* r4 = (ushort*)alloc((size_t)8192 * 256 * 2);    // 4.2 MB
  ushort* r5 = (ushort*)alloc((size_t)8192 * 64 * 2);     // 1.05 MB
  ushort* d0 = (ushort*)alloc((size_t)8192 * 256 * 2);
  ushort* d1 = (ushort*)alloc((size_t)32768 * 128 * 2);
  ushort* d2 = (ushort*)alloc((size_t)131072 * 64 * 2);
  ushort* d3 = (ushort*)alloc((size_t)524288 * 32 * 2);
  float*  Z    = (float*)alloc((size_t)524288 * 4);
  ushort* Zq   = (ushort*)alloc((size_t)524288 * 2);
  float*  cbT  = (float*)alloc((size_t)524288 * 4);
  float*  wsq  = (float*)alloc((size_t)512 * 4);
  ushort* wce2 = (ushort*)alloc((size_t)16 * 64 * 32 * 2);
  ushort* wce3 = (ushort*)alloc((size_t)16 * 128 * 64 * 2);
  ushort* wce4 = (ushort*)alloc((size_t)16 * 256 * 128 * 2);
  ushort* wce5 = (ushort*)alloc((size_t)64 * 256 * 2);
  ushort* wcd0 = (ushort*)alloc((size_t)256 * 64 * 2);
  ushort* wcd1 = (ushort*)alloc((size_t)16 * 128 * 256 * 2);
  ushort* wcd2 = (ushort*)alloc((size_t)16 * 64 * 128 * 2);
  ushort* wcd3 = (ushort*)alloc((size_t)16 * 32 * 64 * 2);
  ushort* wcd4 = (ushort*)alloc((size_t)16 * 3 * 32 * 2);
  float*  stats   = (float*)alloc((size_t)4096 * 4);
  float*  coef    = (float*)alloc((size_t)512 * 4);
  float*  lossAcc = (float*)alloc(256);
  int*    jbuf    = (int*)alloc((size_t)512 * 4);

  auto bnstage = [&](ushort* buf, int C, long nPix, const float* g, const float* b) {
    long nU = nPix * (C >> 1);
    hipMemsetAsync(stats, 0, 4096 * sizeof(float), stream);
    bn_stats<<<512, 256, 0, stream>>>(buf, stats, C, nU);
    bn_finalize<<<1, C, 0, stream>>>(stats, g, b, coef, C, 1.0f / (float)nPix);
    bn_apply<<<(int)((nU + 255) / 256), 256, 0, stream>>>((uint*)buf, coef, C, nU);
  };

  // ---- weight transforms + codebook prep ----
  enc_wt<<<128, 256, 0, stream>>>(ce2_w, wce2, 64, 32);
  enc_wt<<<512, 256, 0, stream>>>(ce3_w, wce3, 128, 64);
  enc_wt<<<2048, 256, 0, stream>>>(ce4_w, wce4, 256, 128);
  bf16cast<<<64, 256, 0, stream>>>(ce5_w, wce5, 16384);
  bf16cast<<<64, 256, 0, stream>>>(cd0_w, wcd0, 16384);
  dec_wt<<<2048, 256, 0, stream>>>(cd1_w, wcd1, 128, 256);
  dec_wt<<<512, 256, 0, stream>>>(cd2_w, wcd2, 64, 128);
  dec_wt<<<128, 256, 0, stream>>>(cd3_w, wcd3, 32, 64);
  dec_wt<<<6, 256, 0, stream>>>(cd4_w, wcd4, 3, 32);
  cb_tr<<<2048, 256, 0, stream>>>(codebook, cbT);
  cb_wsq<<<512, 256, 0, stream>>>(codebook, wsq);

  // ---- encoder ----
  ce1_conv<<<2048, 256, 0, stream>>>(x, ce1_w, ce1_b, (uint*)r1);
  bnstage(r1, 32, 524288, bn_e1_g, bn_e1_b);
  tconv<1, 32, 64, 32, 4, 2, 2><<<2048, 256, 0, stream>>>(r1, wce2, ce2_b, r2);
  bnstage(r2, 64, 131072, bn_e2_g, bn_e2_b);
  tconv<1, 64, 128, 16, 4, 1, 4><<<1024, 256, 0, stream>>>(r2, wce3, ce3_b, r3);
  bnstage(r3, 128, 32768, bn_e3_g, bn_e3_b);
  tconv<1, 128, 256, 8, 4, 1, 4><<<512, 256, 0, stream>>>(r3, wce4, ce4_b, r4);
  bnstage(r4, 256, 8192, bn_e4_g, bn_e4_b);
  g1x1<256, 64, 64><<<dim3(128, 1), 256, 0, stream>>>(r4, wce5, ce5_b, r5);
  bnstage(r5, 64, 8192, bn_e5_g, bn_e5_b);

  // ---- VQ ----
  make_Z<<<2048, 256, 0, stream>>>(r5, Z);
  vq_argmin8<<<64, 256, 0, stream>>>(Z, cbT, wsq, jbuf);
  hipMemsetAsync(lossAcc, 0, sizeof(float), stream);
  vq_gather_loss<<<512, 256, 0, stream>>>(Z, codebook, jbuf, Zq, lossAcc);
  write_losses<<<1, 1, 0, stream>>>(lossAcc, out + 6291456);

  // ---- decoder ----
  g1x1<64, 256, 64><<<dim3(128, 4), 256, 0, stream>>>(Zq, wcd0, cd0_b, d0);
  bnstage(d0, 256, 8192, bn_d0_g, bn_d0_b);
  tconv<2, 256, 128, 4, 4, 1, 8><<<512, 256, 0, stream>>>(d0, wcd1, cd1_b, d1);
  bnstage(d1, 128, 32768, bn_d1_g, bn_d1_b);
  tconv<2, 128, 64, 8, 8, 4, 4><<<512, 256, 0, stream>>>(d1, wcd2, cd2_b, d2);
  bnstage(d2, 64, 131072, bn_d2_g, bn_d2_b);
  tconv<2, 64, 32, 16, 8, 8, 2><<<1024, 256, 0, stream>>>(d2, wcd3, cd3_b, d3);
  bnstage(d3, 32, 524288, bn_d3_g, bn_d3_b);
  cd4_conv<<<8192, 256, 0, stream>>>(d3, wcd4, cd4_b, out);
}

// Round 5
// 776.500 us; speedup vs baseline: 21.8312x; 1.1401x over previous
//
#include <hip/hip_runtime.h>
#include <hip/hip_bf16.h>
#include <math.h>

typedef __attribute__((ext_vector_type(8))) short bf16x8;
typedef __attribute__((ext_vector_type(4))) float f32x4;

__device__ __forceinline__ float bf2f(ushort u) {
  union { uint i; float f; } t; t.i = ((uint)u) << 16; return t.f;
}
__device__ __forceinline__ ushort f2bf(float f) {
  __hip_bfloat16 h = __float2bfloat16(f);
  return *reinterpret_cast<ushort*>(&h);
}
__device__ __forceinline__ uint pk(float a, float b) {
  return (uint)f2bf(a) | ((uint)f2bf(b) << 16);
}
constexpr int ilog2c(int v) { int r = 0; while (v > 1) { v >>= 1; ++r; } return r; }

// =====================================================================
// Tiled MFMA conv with fused input-BN+LReLU.
// MODE 1: k4s2p1 encoder. MODE 2: up2+3x3 decoder (4 parity classes,
// 2x2 pre-combined taps, wave = parity).
// Input: RAW bf16 NHWC. BN coef computed per-block from stats[8][2][Ci]
// (+g,b), applied during LDS staging (in-bounds only). Weights
// [tap][Co][Ci] bf16 direct from global. Pixel pitch 40 ushorts.
// =====================================================================
template<int MODE, int Ci, int Co, int HIN, int TR, int WM, int WN, bool BN>
__global__ __launch_bounds__(256) void tconv(const ushort* __restrict__ in,
    const ushort* __restrict__ wt, const float* __restrict__ bias,
    const float* __restrict__ st, const float* __restrict__ g,
    const float* __restrict__ bb, ushort* __restrict__ out) {
  constexpr int W    = (MODE == 1) ? HIN / 2 : HIN;
  constexpr int LW   = ilog2c(W);
  constexpr int R_IN = (MODE == 1) ? 2 * TR + 2 : TR + 2;
  constexpr int W2   = HIN + 2;
  constexpr int MT   = TR * W / 16;
  constexpr int NG   = Co / 16;
  constexpr int TAPS = (MODE == 1) ? 16 : 4;
  constexpr int RB   = W / TR;
  constexpr int CB   = BN ? Ci : 1;
  static_assert(TR * W % 16 == 0, "mtile");
  static_assert(MODE == 2 ? (WM == MT && WN == NG)
                          : ((MT % WM == 0) && (NG % WN == 0) && (MT / WM) * (NG / WN) == 4),
                "wave map");

  __shared__ ushort lt[R_IN * W2 * 40];
  __shared__ float lsc[CB], lsh[CB];

  const int tid  = threadIdx.x;
  const int wave = tid >> 6;
  const int ln15 = tid & 15;
  const int quad = (tid & 63) >> 4;
  const int rb = blockIdx.x % RB;
  const int n  = blockIdx.x / RB;
  const int h0 = rb * TR;

  if (BN) {
    constexpr float inv_cnt = 1.0f / (float)(512 * HIN * HIN);
    for (int c = tid; c < Ci; c += 256) {
      float s = 0.f, q = 0.f;
#pragma unroll
      for (int sl = 0; sl < 8; ++sl) {
        s += st[sl * 2 * Ci + c];
        q += st[sl * 2 * Ci + Ci + c];
      }
      float m = s * inv_cnt;
      float var = fmaf(q, inv_cnt, -m * m);
      float sc = g[c] * rsqrtf(var + 1e-5f);
      lsc[c] = sc;
      lsh[c] = fmaf(-m, sc, bb[c]);
    }
  }

  int mt0, cg0, ph, pw, pb;
  if (MODE == 2) { mt0 = 0; cg0 = 0; ph = wave >> 1; pw = wave & 1; pb = wave * 4; }
  else {
    constexpr int MW = (MT / WM > 0) ? MT / WM : 1;
    mt0 = (wave % MW) * WM; cg0 = (wave / MW) * WN; ph = 0; pw = 0; pb = 0;
  }

  f32x4 acc[WM][WN];
#pragma unroll
  for (int j = 0; j < WN; ++j) {
    f32x4 b4 = *(const f32x4*)&bias[(cg0 + j) * 16 + quad * 4];
#pragma unroll
    for (int i = 0; i < WM; ++i) acc[i][j] = b4;
  }

  const uint* src = (const uint*)in;
  const int gr0 = (MODE == 1) ? 2 * h0 - 1 : h0 - 1;

#pragma unroll 1
  for (int c0 = 0; c0 < Ci; c0 += 32) {
    __syncthreads();
    constexpr int SN = R_IN * W2 * 16;
    for (int i = tid; i < SN; i += 256) {
      int ciu = i & 15; int t2 = i >> 4; int c = t2 % W2; int r = t2 / W2;
      int gr = gr0 + r, gc = c - 1;
      uint v = 0;
      if ((unsigned)gr < (unsigned)HIN && (unsigned)gc < (unsigned)HIN) {
        v = src[((size_t)(n * HIN + gr) * HIN + gc) * (Ci / 2) + (c0 >> 1) + ciu];
        if (BN) {
          int cc = c0 + 2 * ciu;
          float f0 = fmaf(bf2f((ushort)(v & 0xffffu)), lsc[cc], lsh[cc]);
          float f1 = fmaf(bf2f((ushort)(v >> 16)), lsc[cc + 1], lsh[cc + 1]);
          f0 = f0 > 0.f ? f0 : 0.01f * f0;
          f1 = f1 > 0.f ? f1 : 0.01f * f1;
          v = pk(f0, f1);
        }
      }
      ((uint*)lt)[(r * W2 + c) * 20 + ciu] = v;
    }
    __syncthreads();

#pragma unroll
    for (int t = 0; t < TAPS; ++t) {
      const int kh = (MODE == 1) ? (t >> 2) : (t >> 1);
      const int kw = (MODE == 1) ? (t & 3) : (t & 1);
      bf16x8 af[WN];
      const ushort* wb = wt + (size_t)(pb + t) * Co * Ci;
#pragma unroll
      for (int j = 0; j < WN; ++j)
        af[j] = *(const bf16x8*)&wb[(size_t)((cg0 + j) * 16 + ln15) * Ci + c0 + quad * 8];
      bf16x8 bfr[WM];
#pragma unroll
      for (int i = 0; i < WM; ++i) {
        int m = (mt0 + i) * 16 + ln15;
        int hr = m >> LW, wr = m & (W - 1);
        int row, col;
        if (MODE == 1) { row = 2 * hr + kh; col = 2 * wr + kw; }
        else           { row = hr + kh + ph; col = wr + kw + pw; }
        bfr[i] = *(const bf16x8*)&lt[(row * W2 + col) * 40 + quad * 8];
      }
#pragma unroll
      for (int i = 0; i < WM; ++i)
#pragma unroll
        for (int j = 0; j < WN; ++j)
          acc[i][j] = __builtin_amdgcn_mfma_f32_16x16x32_bf16(af[j], bfr[i], acc[i][j], 0, 0, 0);
    }
  }

#pragma unroll
  for (int i = 0; i < WM; ++i) {
    int m = (mt0 + i) * 16 + ln15;
    int hr = m >> LW, wr = m & (W - 1);
    size_t sp;
    if (MODE == 2) {
      int oh = 2 * (h0 + hr) + ph, ow = 2 * wr + pw;
      sp = ((size_t)n * (2 * HIN) + oh) * (2 * HIN) + ow;
    } else {
      sp = ((size_t)n * W + h0 + hr) * W + wr;
    }
#pragma unroll
    for (int j = 0; j < WN; ++j) {
      f32x4 a = acc[i][j];
      uint2 stv; stv.x = pk(a[0], a[1]); stv.y = pk(a[2], a[3]);
      *(uint2*)&out[sp * Co + (cg0 + j) * 16 + quad * 4] = stv;
    }
  }
}

// ===================== 1x1 conv GEMM (ce5 / cd0), fused input-BN =====================
template<int Ci, int Co, int COT, bool BN, int NPIX>
__global__ __launch_bounds__(256) void g1x1(const ushort* __restrict__ in,
    const ushort* __restrict__ wt, const float* __restrict__ bias,
    const float* __restrict__ st, const float* __restrict__ g,
    const float* __restrict__ bb, ushort* __restrict__ out) {
  constexpr int NG = COT / 16;
  constexpr int CB = BN ? Ci : 1;
  __shared__ ushort lb[64 * 40];
  __shared__ float lsc[CB], lsh[CB];
  const int tid = threadIdx.x, wave = tid >> 6, ln15 = tid & 15, quad = (tid & 63) >> 4;
  const int pixBase = blockIdx.x * 64;
  const int co0 = blockIdx.y * COT;
  if (BN) {
    constexpr float inv_cnt = 1.0f / (float)NPIX;
    for (int c = tid; c < Ci; c += 256) {
      float s = 0.f, q = 0.f;
#pragma unroll
      for (int sl = 0; sl < 8; ++sl) {
        s += st[sl * 2 * Ci + c];
        q += st[sl * 2 * Ci + Ci + c];
      }
      float m = s * inv_cnt;
      float var = fmaf(q, inv_cnt, -m * m);
      float sc = g[c] * rsqrtf(var + 1e-5f);
      lsc[c] = sc;
      lsh[c] = fmaf(-m, sc, bb[c]);
    }
  }
  f32x4 acc[NG];
#pragma unroll
  for (int j = 0; j < NG; ++j) acc[j] = *(const f32x4*)&bias[co0 + j * 16 + quad * 4];
  const uint* src = (const uint*)in;
#pragma unroll 1
  for (int c0 = 0; c0 < Ci; c0 += 32) {
    __syncthreads();
    for (int i = tid; i < 1024; i += 256) {
      int ciu = i & 15, pl = i >> 4;
      uint v = src[(size_t)(pixBase + pl) * (Ci / 2) + (c0 >> 1) + ciu];
      if (BN) {
        int cc = c0 + 2 * ciu;
        float f0 = fmaf(bf2f((ushort)(v & 0xffffu)), lsc[cc], lsh[cc]);
        float f1 = fmaf(bf2f((ushort)(v >> 16)), lsc[cc + 1], lsh[cc + 1]);
        f0 = f0 > 0.f ? f0 : 0.01f * f0;
        f1 = f1 > 0.f ? f1 : 0.01f * f1;
        v = pk(f0, f1);
      }
      ((uint*)lb)[pl * 20 + ciu] = v;
    }
    __syncthreads();
    bf16x8 bfr = *(const bf16x8*)&lb[(wave * 16 + ln15) * 40 + quad * 8];
#pragma unroll
    for (int j = 0; j < NG; ++j) {
      bf16x8 af = *(const bf16x8*)&wt[(size_t)(co0 + j * 16 + ln15) * Ci + c0 + quad * 8];
      acc[j] = __builtin_amdgcn_mfma_f32_16x16x32_bf16(af, bfr, acc[j], 0, 0, 0);
    }
  }
  int pix = pixBase + wave * 16 + ln15;
#pragma unroll
  for (int j = 0; j < NG; ++j) {
    uint2 stv; stv.x = pk(acc[j][0], acc[j][1]); stv.y = pk(acc[j][2], acc[j][3]);
    *(uint2*)&out[(size_t)pix * Co + co0 + j * 16 + quad * 4] = stv;
  }
}

// ===================== ce1: k4s2p1, Ci=3, fp32 NCHW in -> raw bf16 NHWC ==========
__global__ __launch_bounds__(256) void ce1_conv(const float* __restrict__ x,
    const float* __restrict__ w, const float* __restrict__ bias, uint* __restrict__ out) {
  __shared__ float lw[1536];
  __shared__ float lb[32];
  int tid = threadIdx.x;
#pragma unroll
  for (int k = 0; k < 6; ++k) lw[tid + k * 256] = w[tid + k * 256];
  if (tid < 32) lb[tid] = bias[tid];
  __syncthreads();
  int pix = blockIdx.x * 256 + tid;     // 512*32*32
  int w_ = pix & 31, h_ = (pix >> 5) & 31, n = pix >> 10;
  float v[48];
#pragma unroll
  for (int ci = 0; ci < 3; ++ci) {
    const float* xp = x + (((size_t)n * 3 + ci) << 12);
#pragma unroll
    for (int kh = 0; kh < 4; ++kh) {
      int ih = 2 * h_ - 1 + kh;
#pragma unroll
      for (int kw = 0; kw < 4; ++kw) {
        int iw = 2 * w_ - 1 + kw;
        bool okk = ((unsigned)ih < 64u) && ((unsigned)iw < 64u);
        v[ci * 16 + kh * 4 + kw] = okk ? xp[(ih << 6) + iw] : 0.f;
      }
    }
  }
  uint ub[16];
#pragma unroll
  for (int cp = 0; cp < 16; ++cp) {
    float a[2];
#pragma unroll
    for (int s = 0; s < 2; ++s) {
      int co = 2 * cp + s;
      float ac = lb[co];
#pragma unroll
      for (int q = 0; q < 12; ++q) {
        float4 wv = *(const float4*)&lw[co * 48 + q * 4];
        ac = fmaf(v[q * 4 + 0], wv.x, ac);
        ac = fmaf(v[q * 4 + 1], wv.y, ac);
        ac = fmaf(v[q * 4 + 2], wv.z, ac);
        ac = fmaf(v[q * 4 + 3], wv.w, ac);
      }
      a[s] = ac;
    }
    ub[cp] = pk(a[0], a[1]);
  }
  uint4* op = (uint4*)&out[(size_t)pix * 16];
#pragma unroll
  for (int q = 0; q < 4; ++q)
    op[q] = make_uint4(ub[4 * q], ub[4 * q + 1], ub[4 * q + 2], ub[4 * q + 3]);
}

// ===================== cd4: fused input-BN + parity 2x2 + sigmoid -> fp32 NCHW ======
__global__ __launch_bounds__(256) void cd4_conv(const ushort* __restrict__ in,
    const ushort* __restrict__ wt, const float* __restrict__ bias,
    const float* __restrict__ st, const float* __restrict__ g,
    const float* __restrict__ bb, float* __restrict__ out) {
  __shared__ ushort lw[1536];
  __shared__ float lb[3];
  __shared__ float lsc[32], lsh[32];
  int tid = threadIdx.x;
#pragma unroll
  for (int k = 0; k < 6; ++k) lw[tid + k * 256] = wt[tid + k * 256];
  if (tid < 3) lb[tid] = bias[tid];
  if (tid < 32) {
    float s = 0.f, q = 0.f;
#pragma unroll
    for (int sl = 0; sl < 8; ++sl) { s += st[sl * 64 + tid]; q += st[sl * 64 + 32 + tid]; }
    float m = s * (1.0f / 2097152.f);
    float var = fmaf(q, 1.0f / 2097152.f, -m * m);
    float sc = g[tid] * rsqrtf(var + 1e-5f);
    lsc[tid] = sc;
    lsh[tid] = fmaf(-m, sc, bb[tid]);
  }
  __syncthreads();
  int pix = blockIdx.x * 256 + tid;    // 512*64*64
  int ow = pix & 63, oh = (pix >> 6) & 63, n = pix >> 12;
  int pw_ = ow & 1, ph_ = oh & 1, w_ = ow >> 1, h_ = oh >> 1;
  int p = ph_ * 2 + pw_;
  float a0 = lb[0], a1 = lb[1], a2 = lb[2];
#pragma unroll
  for (int t = 0; t < 4; ++t) {
    int r = t >> 1, c = t & 1;
    int ih = h_ + r - 1 + ph_;
    int iw = w_ + c - 1 + pw_;
    if ((unsigned)ih < 32u && (unsigned)iw < 32u) {
      const uint* ip = (const uint*)&in[(size_t)((n * 32 + ih) * 32 + iw) * 32];
      const uint* w0 = (const uint*)&lw[((p * 4 + t) * 3 + 0) * 32];
      const uint* w1 = (const uint*)&lw[((p * 4 + t) * 3 + 1) * 32];
      const uint* w2 = (const uint*)&lw[((p * 4 + t) * 3 + 2) * 32];
#pragma unroll
      for (int cp2 = 0; cp2 < 16; ++cp2) {
        uint vv = ip[cp2];
        float f0 = fmaf(bf2f((ushort)(vv & 0xffffu)), lsc[2 * cp2], lsh[2 * cp2]);
        float f1 = fmaf(bf2f((ushort)(vv >> 16)), lsc[2 * cp2 + 1], lsh[2 * cp2 + 1]);
        f0 = f0 > 0.f ? f0 : 0.01f * f0;
        f1 = f1 > 0.f ? f1 : 0.01f * f1;
        uint u0 = w0[cp2], u1 = w1[cp2], u2 = w2[cp2];
        a0 = fmaf(f0, bf2f((ushort)(u0 & 0xffffu)), a0);
        a0 = fmaf(f1, bf2f((ushort)(u0 >> 16)), a0);
        a1 = fmaf(f0, bf2f((ushort)(u1 & 0xffffu)), a1);
        a1 = fmaf(f1, bf2f((ushort)(u1 >> 16)), a1);
        a2 = fmaf(f0, bf2f((ushort)(u2 & 0xffffu)), a2);
        a2 = fmaf(f1, bf2f((ushort)(u2 >> 16)), a2);
      }
    }
  }
  a0 = 1.f / (1.f + __expf(-a0));
  a1 = 1.f / (1.f + __expf(-a1));
  a2 = 1.f / (1.f + __expf(-a2));
  size_t ob = ((size_t)n * 3) << 12;
  int sp = (oh << 6) | ow;
  out[ob + sp] = a0;
  out[ob + 4096 + sp] = a1;
  out[ob + 8192 + sp] = a2;
}

// ===================== weight transforms ==========
__global__ void enc_wt(const float* __restrict__ w, ushort* __restrict__ o, int Co, int Ci) {
  int idx = blockIdx.x * 256 + threadIdx.x;
  if (idx >= 16 * Co * Ci) return;
  int ci = idx % Ci; int r = idx / Ci; int co = r % Co; int t = r / Co;
  o[idx] = f2bf(w[(co * Ci + ci) * 16 + t]);
}

__global__ void dec_wt(const float* __restrict__ w, ushort* __restrict__ o, int Co, int Ci) {
  int idx = blockIdx.x * 256 + threadIdx.x;
  if (idx >= 16 * Co * Ci) return;
  int ci = idx % Ci; int r = idx / Ci; int co = r % Co; int pt = r / Co;
  int p = pt >> 2, t = pt & 3;
  int ph = p >> 1, pw = p & 1, rr = t >> 1, cc = t & 1;
  int rs = (rr == 0) ? 0 : (ph == 0 ? 1 : 2);
  int re = (rr == 0) ? (ph == 0 ? 1 : 2) : 3;
  int cs = (cc == 0) ? 0 : (pw == 0 ? 1 : 2);
  int ce = (cc == 0) ? (pw == 0 ? 1 : 2) : 3;
  float s = 0.f;
  for (int kh = rs; kh < re; ++kh)
    for (int kw = cs; kw < ce; ++kw)
      s += w[((co * Ci + ci) * 3 + kh) * 3 + kw];
  o[idx] = f2bf(s);
}

__global__ void bf16cast(const float* __restrict__ w, ushort* __restrict__ o, int n) {
  int i = blockIdx.x * 256 + threadIdx.x;
  if (i < n) o[i] = f2bf(w[i]);
}

// ===================== BatchNorm stats (raw tensor -> [8][2][C] partials) ==========
__global__ __launch_bounds__(256) void bn_stats(const ushort* __restrict__ x,
    float* __restrict__ st, int C, long npairs) {
  int tid = threadIdx.x;
  int cpw = C >> 1;
  float s0 = 0.f, s1 = 0.f, q0 = 0.f, q1 = 0.f;
  const uint* xp = (const uint*)x;
  for (long i = (long)blockIdx.x * 256 + tid; i < npairs; i += (long)gridDim.x * 256) {
    uint v = xp[i];
    float f0 = bf2f((ushort)(v & 0xffffu));
    float f1 = bf2f((ushort)(v >> 16));
    s0 += f0; q0 = fmaf(f0, f0, q0);
    s1 += f1; q1 = fmaf(f1, f1, q1);
  }
  __shared__ float A0[256], A1[256], Q0[256], Q1[256];
  A0[tid] = s0; A1[tid] = s1; Q0[tid] = q0; Q1[tid] = q1;
  __syncthreads();
  for (int off = 128; off >= cpw; off >>= 1) {
    if (tid < off) {
      A0[tid] += A0[tid + off]; A1[tid] += A1[tid + off];
      Q0[tid] += Q0[tid + off]; Q1[tid] += Q1[tid + off];
    }
    __syncthreads();
  }
  if (tid < cpw) {
    float* d = st + (size_t)(blockIdx.x & 7) * 2 * C;
    atomicAdd(&d[2 * tid], A0[tid]);
    atomicAdd(&d[2 * tid + 1], A1[tid]);
    atomicAdd(&d[C + 2 * tid], Q0[tid]);
    atomicAdd(&d[C + 2 * tid + 1], Q1[tid]);
  }
}

// ===================== VQ ==========
// zprep: raw r5 + e5 stats -> fp32 Z (post-BN+LReLU) and bf16 Zbf
__global__ __launch_bounds__(256) void zprep(const ushort* __restrict__ r5,
    const float* __restrict__ st, const float* __restrict__ g,
    const float* __restrict__ bb, float* __restrict__ Z, ushort* __restrict__ Zbf) {
  __shared__ float lsc[64], lsh[64];
  int tid = threadIdx.x;
  if (tid < 64) {
    float s = 0.f, q = 0.f;
#pragma unroll
    for (int sl = 0; sl < 8; ++sl) { s += st[sl * 128 + tid]; q += st[sl * 128 + 64 + tid]; }
    float m = s * (1.0f / 8192.f);
    float var = fmaf(q, 1.0f / 8192.f, -m * m);
    float sc = g[tid] * rsqrtf(var + 1e-5f);
    lsc[tid] = sc;
    lsh[tid] = fmaf(-m, sc, bb[tid]);
  }
  __syncthreads();
  int i = blockIdx.x * 256 + tid;   // 524288
  int c = i & 63;
  float f = fmaf(bf2f(r5[i]), lsc[c], lsh[c]);
  f = f > 0.f ? f : 0.01f * f;
  Z[i] = f;
  Zbf[i] = f2bf(f);
}

__global__ __launch_bounds__(256) void cb_wsq(const float* __restrict__ cb,
                                              float* __restrict__ wsq) {
  int k = blockIdx.x;
  float s = 0.f;
  for (int d = threadIdx.x; d < 1024; d += 256) {
    float v = cb[k * 1024 + d];
    s = fmaf(v, v, s);
  }
#pragma unroll
  for (int o = 32; o > 0; o >>= 1) s += __shfl_down(s, o);
  __shared__ float sh[4];
  if ((threadIdx.x & 63) == 0) sh[threadIdx.x >> 6] = s;
  __syncthreads();
  if (threadIdx.x == 0) wsq[k] = sh[0] + sh[1] + sh[2] + sh[3];
}

// S[b][k] = Z_b . W_k  (bf16 MFMA GEMM, 64x64 tiles)
__global__ __launch_bounds__(256) void vq_gemm(const ushort* __restrict__ Zbf,
    const ushort* __restrict__ cbbf, float* __restrict__ S) {
  __shared__ ushort lZ[64 * 40], lW[64 * 40];
  const int tid = threadIdx.x, wave = tid >> 6, ln15 = tid & 15, quad = (tid & 63) >> 4;
  const int b0 = blockIdx.x * 64, k0 = blockIdx.y * 64;
  f32x4 acc[4];
#pragma unroll
  for (int j = 0; j < 4; ++j) acc[j] = (f32x4)(0.f);
  const uint* zs = (const uint*)Zbf;
  const uint* ws = (const uint*)cbbf;
#pragma unroll 1
  for (int c0 = 0; c0 < 1024; c0 += 32) {
    __syncthreads();
    for (int i = tid; i < 1024; i += 256) {
      int ciu = i & 15, rl = i >> 4;
      ((uint*)lZ)[rl * 20 + ciu] = zs[(size_t)(b0 + rl) * 512 + (c0 >> 1) + ciu];
      ((uint*)lW)[rl * 20 + ciu] = ws[(size_t)(k0 + rl) * 512 + (c0 >> 1) + ciu];
    }
    __syncthreads();
    bf16x8 bfr = *(const bf16x8*)&lZ[(wave * 16 + ln15) * 40 + quad * 8];
#pragma unroll
    for (int j = 0; j < 4; ++j) {
      bf16x8 af = *(const bf16x8*)&lW[(j * 16 + ln15) * 40 + quad * 8];
      acc[j] = __builtin_amdgcn_mfma_f32_16x16x32_bf16(af, bfr, acc[j], 0, 0, 0);
    }
  }
  int b = b0 + wave * 16 + ln15;
#pragma unroll
  for (int j = 0; j < 4; ++j)
    *(f32x4*)&S[(size_t)b * 512 + k0 + j * 16 + quad * 4] = acc[j];
}

// per-image argmin over k of wsq[k] - 2*S[b][k], first-index tie-break
__global__ __launch_bounds__(256) void vq_scan(const float* __restrict__ S,
    const float* __restrict__ wsq, int* __restrict__ jout) {
  int b = blockIdx.x, tid = threadIdx.x;
  float d1 = fmaf(-2.f, S[(size_t)b * 512 + tid], wsq[tid]);
  float d2 = fmaf(-2.f, S[(size_t)b * 512 + tid + 256], wsq[tid + 256]);
  float bv = d1; int bk = tid;
  if (d2 < bv) { bv = d2; bk = tid + 256; }
  __shared__ float vsh[256]; __shared__ int ish[256];
  vsh[tid] = bv; ish[tid] = bk;
  __syncthreads();
  for (int s = 128; s > 0; s >>= 1) {
    if (tid < s) {
      float ov = vsh[tid + s]; int oi = ish[tid + s];
      if (ov < vsh[tid] || (ov == vsh[tid] && oi < ish[tid])) { vsh[tid] = ov; ish[tid] = oi; }
    }
    __syncthreads();
  }
  if (tid == 0) jout[b] = ish[0];
}

__global__ __launch_bounds__(256) void vq_gather_loss(const float* __restrict__ Z,
    const float* __restrict__ cb, const int* __restrict__ jidx,
    ushort* __restrict__ Zq, float* __restrict__ lossAcc) {
  int b = blockIdx.x;
  int k = jidx[b];
  const float* w = cb + ((long)k << 10);
  const float* zp = Z + ((long)b << 10);
  float part = 0.f;
  for (int d = threadIdx.x; d < 1024; d += 256) {
    float wv = w[d];
    float diff = zp[d] - wv;
    part = fmaf(diff, diff, part);
    Zq[(b << 10) + d] = f2bf(wv);
  }
#pragma unroll
  for (int o = 32; o > 0; o >>= 1) part += __shfl_down(part, o);
  __shared__ float sh[4];
  if ((threadIdx.x & 63) == 0) sh[threadIdx.x >> 6] = part;
  __syncthreads();
  if (threadIdx.x == 0) atomicAdd(lossAcc, sh[0] + sh[1] + sh[2] + sh[3]);
}

__global__ void write_losses(const float* __restrict__ lossAcc, float* __restrict__ out2) {
  float v = lossAcc[0] * (1.0f / 512.0f);
  out2[0] = v;
  out2[1] = v;
}

// ===================== launch ==========
extern "C" void kernel_launch(void* const* d_in, const int* in_sizes, int n_in,
                              void* d_out, int out_size, void* d_ws, size_t ws_size,
                              hipStream_t stream) {
  const float* x      = (const float*)d_in[0];
  const float* ce1_w  = (const float*)d_in[1];  const float* ce1_b = (const float*)d_in[2];
  const float* ce2_w  = (const float*)d_in[3];  const float* ce2_b = (const float*)d_in[4];
  const float* ce3_w  = (const float*)d_in[5];  const float* ce3_b = (const float*)d_in[6];
  const float* ce4_w  = (const float*)d_in[7];  const float* ce4_b = (const float*)d_in[8];
  const float* ce5_w  = (const float*)d_in[9];  const float* ce5_b = (const float*)d_in[10];
  const float* cd0_w  = (const float*)d_in[11]; const float* cd0_b = (const float*)d_in[12];
  const float* cd1_w  = (const float*)d_in[13]; const float* cd1_b = (const float*)d_in[14];
  const float* cd2_w  = (const float*)d_in[15]; const float* cd2_b = (const float*)d_in[16];
  const float* cd3_w  = (const float*)d_in[17]; const float* cd3_b = (const float*)d_in[18];
  const float* cd4_w  = (const float*)d_in[19]; const float* cd4_b = (const float*)d_in[20];
  const float* bn_e1_g = (const float*)d_in[21]; const float* bn_e1_b = (const float*)d_in[22];
  const float* bn_e2_g = (const float*)d_in[23]; const float* bn_e2_b = (const float*)d_in[24];
  const float* bn_e3_g = (const float*)d_in[25]; const float* bn_e3_b = (const float*)d_in[26];
  const float* bn_e4_g = (const float*)d_in[27]; const float* bn_e4_b = (const float*)d_in[28];
  const float* bn_e5_g = (const float*)d_in[29]; const float* bn_e5_b = (const float*)d_in[30];
  const float* bn_d0_g = (const float*)d_in[31]; const float* bn_d0_b = (const float*)d_in[32];
  const float* bn_d1_g = (const float*)d_in[33]; const float* bn_d1_b = (const float*)d_in[34];
  const float* bn_d2_g = (const float*)d_in[35]; const float* bn_d2_b = (const float*)d_in[36];
  const float* bn_d3_g = (const float*)d_in[37]; const float* bn_d3_b = (const float*)d_in[38];
  const float* codebook = (const float*)d_in[39];

  float* out = (float*)d_out;

  // ---- workspace carve (raw bf16 NHWC activations) ----
  char* p = (char*)d_ws;
  auto alloc = [&](size_t bytes) { void* r = p; p += (bytes + 255) & ~(size_t)255; return r; };
  ushort* r1 = (ushort*)alloc((size_t)524288 * 32 * 2);
  ushort* r2 = (ushort*)alloc((size_t)131072 * 64 * 2);
  ushort* r3 = (ushort*)alloc((size_t)32768 * 128 * 2);
  ushort* r4 = (ushort*)alloc((size_t)8192 * 256 * 2);
  ushort* r5 = (ushort*)alloc((size_t)8192 * 64 * 2);
  ushort* d0 = (ushort*)alloc((size_t)8192 * 256 * 2);
  ushort* d1 = (ushort*)alloc((size_t)32768 * 128 * 2);
  ushort* d2 = (ushort*)alloc((size_t)131072 * 64 * 2);
  ushort* d3 = (ushort*)alloc((size_t)524288 * 32 * 2);
  float*  Z    = (float*)alloc((size_t)524288 * 4);
  ushort* Zbf  = (ushort*)alloc((size_t)524288 * 2);
  ushort* cbbf = (ushort*)alloc((size_t)524288 * 2);
  float*  S    = (float*)alloc((size_t)512 * 512 * 4);
  ushort* Zq   = (ushort*)alloc((size_t)524288 * 2);
  float*  wsq  = (float*)alloc((size_t)512 * 4);
  ushort* wce2 = (ushort*)alloc((size_t)16 * 64 * 32 * 2);
  ushort* wce3 = (ushort*)alloc((size_t)16 * 128 * 64 * 2);
  ushort* wce4 = (ushort*)alloc((size_t)16 * 256 * 128 * 2);
  ushort* wce5 = (ushort*)alloc((size_t)64 * 256 * 2);
  ushort* wcd0 = (ushort*)alloc((size_t)256 * 64 * 2);
  ushort* wcd1 = (ushort*)alloc((size_t)16 * 128 * 256 * 2);
  ushort* wcd2 = (ushort*)alloc((size_t)16 * 64 * 128 * 2);
  ushort* wcd3 = (ushort*)alloc((size_t)16 * 32 * 64 * 2);
  ushort* wcd4 = (ushort*)alloc((size_t)16 * 3 * 32 * 2);
  float*  stats   = (float*)alloc((size_t)4096 * 4);
  float*  lossAcc = (float*)alloc(256);
  int*    jbuf    = (int*)alloc((size_t)512 * 4);

  auto runstats = [&](ushort* buf, int C, long nPix) {
    long nU = nPix * (C >> 1);
    hipMemsetAsync(stats, 0, 4096 * sizeof(float), stream);
    bn_stats<<<512, 256, 0, stream>>>(buf, stats, C, nU);
  };

  // ---- weight transforms + codebook prep ----
  enc_wt<<<128, 256, 0, stream>>>(ce2_w, wce2, 64, 32);
  enc_wt<<<512, 256, 0, stream>>>(ce3_w, wce3, 128, 64);
  enc_wt<<<2048, 256, 0, stream>>>(ce4_w, wce4, 256, 128);
  bf16cast<<<64, 256, 0, stream>>>(ce5_w, wce5, 16384);
  bf16cast<<<64, 256, 0, stream>>>(cd0_w, wcd0, 16384);
  dec_wt<<<2048, 256, 0, stream>>>(cd1_w, wcd1, 128, 256);
  dec_wt<<<512, 256, 0, stream>>>(cd2_w, wcd2, 64, 128);
  dec_wt<<<128, 256, 0, stream>>>(cd3_w, wcd3, 32, 64);
  dec_wt<<<6, 256, 0, stream>>>(cd4_w, wcd4, 3, 32);
  bf16cast<<<2048, 256, 0, stream>>>(codebook, cbbf, 524288);
  cb_wsq<<<512, 256, 0, stream>>>(codebook, wsq);

  // ---- encoder (convs consume RAW input + stats, applying BN in staging) ----
  ce1_conv<<<2048, 256, 0, stream>>>(x, ce1_w, ce1_b, (uint*)r1);
  runstats(r1, 32, 524288);
  tconv<1, 32, 64, 32, 4, 2, 2, true><<<2048, 256, 0, stream>>>(r1, wce2, ce2_b, stats, bn_e1_g, bn_e1_b, r2);
  runstats(r2, 64, 131072);
  tconv<1, 64, 128, 16, 4, 1, 4, true><<<1024, 256, 0, stream>>>(r2, wce3, ce3_b, stats, bn_e2_g, bn_e2_b, r3);
  runstats(r3, 128, 32768);
  tconv<1, 128, 256, 8, 4, 1, 4, true><<<512, 256, 0, stream>>>(r3, wce4, ce4_b, stats, bn_e3_g, bn_e3_b, r4);
  runstats(r4, 256, 8192);
  g1x1<256, 64, 64, true, 8192><<<dim3(128, 1), 256, 0, stream>>>(r4, wce5, ce5_b, stats, bn_e4_g, bn_e4_b, r5);
  runstats(r5, 64, 8192);

  // ---- VQ ----
  zprep<<<2048, 256, 0, stream>>>(r5, stats, bn_e5_g, bn_e5_b, Z, Zbf);
  vq_gemm<<<dim3(8, 8), 256, 0, stream>>>(Zbf, cbbf, S);
  vq_scan<<<512, 256, 0, stream>>>(S, wsq, jbuf);
  hipMemsetAsync(lossAcc, 0, sizeof(float), stream);
  vq_gather_loss<<<512, 256, 0, stream>>>(Z, codebook, jbuf, Zq, lossAcc);
  write_losses<<<1, 1, 0, stream>>>(lossAcc, out + 6291456);

  // ---- decoder ----
  g1x1<64, 256, 64, false, 1><<<dim3(128, 4), 256, 0, stream>>>(Zq, wcd0, cd0_b, nullptr, nullptr, nullptr, d0);
  runstats(d0, 256, 8192);
  tconv<2, 256, 128, 4, 4, 1, 8, true><<<512, 256, 0, stream>>>(d0, wcd1, cd1_b, stats, bn_d0_g, bn_d0_b, d1);
  runstats(d1, 128, 32768);
  tconv<2, 128, 64, 8, 8, 4, 4, true><<<512, 256, 0, stream>>>(d1, wcd2, cd2_b, stats, bn_d1_g, bn_d1_b, d2);
  runstats(d2, 64, 131072);
  tconv<2, 64, 32, 16, 8, 8, 2, true><<<1024, 256, 0, stream>>>(d2, wcd3, cd3_b, stats, bn_d2_g, bn_d2_b, d3);
  runstats(d3, 32, 524288);
  cd4_conv<<<8192, 256, 0, stream>>>(d3, wcd4, cd4_b, stats, bn_d3_g, bn_d3_b, out);
}

// Round 6
// 661.671 us; speedup vs baseline: 25.6199x; 1.1735x over previous
//
#include <hip/hip_runtime.h>
#include <hip/hip_bf16.h>
#include <math.h>

typedef __attribute__((ext_vector_type(8))) short bf16x8;
typedef __attribute__((ext_vector_type(4))) float f32x4;

__device__ __forceinline__ float bf2f(ushort u) {
  union { uint i; float f; } t; t.i = ((uint)u) << 16; return t.f;
}
__device__ __forceinline__ ushort f2bf(float f) {
  __hip_bfloat16 h = __float2bfloat16(f);
  return *reinterpret_cast<ushort*>(&h);
}
__device__ __forceinline__ uint pk(float a, float b) {
  return (uint)f2bf(a) | ((uint)f2bf(b) << 16);
}
constexpr int ilog2c(int v) { int r = 0; while (v > 1) { v >>= 1; ++r; } return r; }

// =====================================================================
// Tiled MFMA conv, fused input-BN+LReLU and fused OUTPUT batch-stats.
// MODE 1: k4s2p1 encoder. MODE 2: up2+3x3 decoder (4 parity classes,
// 2x2 pre-combined taps, wave = parity).
// SIG: fp32 NCHW sigmoid output (cd4, Co padded to 16, real 3).
// stOut: [8][2][Co] partial sums (slice = blockIdx&7).
// =====================================================================
template<int MODE, int Ci, int Co, int HIN, int TR, int WM, int WN,
         bool BN, bool OSTAT, bool SIG>
__global__ __launch_bounds__(256) void tconv(const ushort* __restrict__ in,
    const ushort* __restrict__ wt, const float* __restrict__ bias,
    const float* __restrict__ st, const float* __restrict__ g,
    const float* __restrict__ bb, void* __restrict__ out_,
    float* __restrict__ stOut) {
  constexpr int W    = (MODE == 1) ? HIN / 2 : HIN;
  constexpr int LW   = ilog2c(W);
  constexpr int R_IN = (MODE == 1) ? 2 * TR + 2 : TR + 2;
  constexpr int W2   = HIN + 2;
  constexpr int MT   = TR * W / 16;
  constexpr int NG   = Co / 16;
  constexpr int TAPS = (MODE == 1) ? 16 : 4;
  constexpr int RB   = W / TR;
  constexpr int CB   = BN ? Ci : 1;
  constexpr int SB   = OSTAT ? Co : 1;
  static_assert(TR * W % 16 == 0, "mtile");
  static_assert(MODE == 2 ? (WM == MT && WN == NG)
                          : ((MT % WM == 0) && (NG % WN == 0) && (MT / WM) * (NG / WN) == 4),
                "wave map");

  __shared__ ushort lt[R_IN * W2 * 40];
  __shared__ float lsc[CB], lsh[CB];
  __shared__ float sst[SB], ssq[SB];

  const int tid  = threadIdx.x;
  const int wave = tid >> 6;
  const int ln15 = tid & 15;
  const int quad = (tid & 63) >> 4;
  const int rb = blockIdx.x % RB;
  const int n  = blockIdx.x / RB;
  const int h0 = rb * TR;

  if (BN) {
    constexpr float inv_cnt = 1.0f / (float)(512 * HIN * HIN);
    for (int c = tid; c < Ci; c += 256) {
      float s = 0.f, q = 0.f;
#pragma unroll
      for (int sl = 0; sl < 8; ++sl) {
        s += st[sl * 2 * Ci + c];
        q += st[sl * 2 * Ci + Ci + c];
      }
      float m = s * inv_cnt;
      float var = fmaf(q, inv_cnt, -m * m);
      float sc = g[c] * rsqrtf(var + 1e-5f);
      lsc[c] = sc;
      lsh[c] = fmaf(-m, sc, bb[c]);
    }
  }

  int mt0, cg0, ph, pw, pb;
  if (MODE == 2) { mt0 = 0; cg0 = 0; ph = wave >> 1; pw = wave & 1; pb = wave * 4; }
  else {
    constexpr int MW = (MT / WM > 0) ? MT / WM : 1;
    mt0 = (wave % MW) * WM; cg0 = (wave / MW) * WN; ph = 0; pw = 0; pb = 0;
  }

  f32x4 acc[WM][WN];
#pragma unroll
  for (int j = 0; j < WN; ++j) {
    f32x4 b4 = *(const f32x4*)&bias[(cg0 + j) * 16 + quad * 4];
#pragma unroll
    for (int i = 0; i < WM; ++i) acc[i][j] = b4;
  }

  const uint* src = (const uint*)in;
  const int gr0 = (MODE == 1) ? 2 * h0 - 1 : h0 - 1;

#pragma unroll 1
  for (int c0 = 0; c0 < Ci; c0 += 32) {
    __syncthreads();
    constexpr int SN = R_IN * W2 * 16;
    for (int i = tid; i < SN; i += 256) {
      int ciu = i & 15; int t2 = i >> 4; int c = t2 % W2; int r = t2 / W2;
      int gr = gr0 + r, gc = c - 1;
      uint v = 0;
      if ((unsigned)gr < (unsigned)HIN && (unsigned)gc < (unsigned)HIN) {
        v = src[((size_t)(n * HIN + gr) * HIN + gc) * (Ci / 2) + (c0 >> 1) + ciu];
        if (BN) {
          int cc = c0 + 2 * ciu;
          float f0 = fmaf(bf2f((ushort)(v & 0xffffu)), lsc[cc], lsh[cc]);
          float f1 = fmaf(bf2f((ushort)(v >> 16)), lsc[cc + 1], lsh[cc + 1]);
          f0 = f0 > 0.f ? f0 : 0.01f * f0;
          f1 = f1 > 0.f ? f1 : 0.01f * f1;
          v = pk(f0, f1);
        }
      }
      ((uint*)lt)[(r * W2 + c) * 20 + ciu] = v;
    }
    __syncthreads();

#pragma unroll
    for (int t = 0; t < TAPS; ++t) {
      const int kh = (MODE == 1) ? (t >> 2) : (t >> 1);
      const int kw = (MODE == 1) ? (t & 3) : (t & 1);
      bf16x8 af[WN];
      const ushort* wb = wt + (size_t)(pb + t) * Co * Ci;
#pragma unroll
      for (int j = 0; j < WN; ++j)
        af[j] = *(const bf16x8*)&wb[(size_t)((cg0 + j) * 16 + ln15) * Ci + c0 + quad * 8];
      bf16x8 bfr[WM];
#pragma unroll
      for (int i = 0; i < WM; ++i) {
        int m = (mt0 + i) * 16 + ln15;
        int hr = m >> LW, wr = m & (W - 1);
        int row, col;
        if (MODE == 1) { row = 2 * hr + kh; col = 2 * wr + kw; }
        else           { row = hr + kh + ph; col = wr + kw + pw; }
        bfr[i] = *(const bf16x8*)&lt[(row * W2 + col) * 40 + quad * 8];
      }
#pragma unroll
      for (int i = 0; i < WM; ++i)
#pragma unroll
        for (int j = 0; j < WN; ++j)
          acc[i][j] = __builtin_amdgcn_mfma_f32_16x16x32_bf16(af[j], bfr[i], acc[i][j], 0, 0, 0);
    }
  }

  if (OSTAT) {
    __syncthreads();
    for (int c = tid; c < Co; c += 256) { sst[c] = 0.f; ssq[c] = 0.f; }
    __syncthreads();
  }

  if (SIG) {
    // fp32 NCHW + sigmoid, real Co = 3 (rows 0..2)
    constexpr int HO2 = 2 * HIN;
    float* outF = (float*)out_;
#pragma unroll
    for (int i = 0; i < WM; ++i) {
      int m = (mt0 + i) * 16 + ln15;
      int hr = m >> LW, wr = m & (W - 1);
      int oh = 2 * (h0 + hr) + ph, ow = 2 * wr + pw;
      size_t base = (size_t)n * 3 * HO2 * HO2 + (size_t)oh * HO2 + ow;
#pragma unroll
      for (int r = 0; r < 4; ++r) {
        int co = quad * 4 + r;
        if (co < 3)
          outF[base + (size_t)co * HO2 * HO2] = 1.f / (1.f + __expf(-acc[i][0][r]));
      }
    }
  } else {
    ushort* out = (ushort*)out_;
#pragma unroll
    for (int i = 0; i < WM; ++i) {
      int m = (mt0 + i) * 16 + ln15;
      int hr = m >> LW, wr = m & (W - 1);
      size_t sp;
      if (MODE == 2) {
        int oh = 2 * (h0 + hr) + ph, ow = 2 * wr + pw;
        sp = ((size_t)n * (2 * HIN) + oh) * (2 * HIN) + ow;
      } else {
        sp = ((size_t)n * W + h0 + hr) * W + wr;
      }
#pragma unroll
      for (int j = 0; j < WN; ++j) {
        f32x4 a = acc[i][j];
        uint2 stv; stv.x = pk(a[0], a[1]); stv.y = pk(a[2], a[3]);
        *(uint2*)&out[sp * Co + (cg0 + j) * 16 + quad * 4] = stv;
      }
    }
  }

  if (OSTAT) {
#pragma unroll
    for (int j = 0; j < WN; ++j)
#pragma unroll
      for (int r = 0; r < 4; ++r) {
        float s = 0.f, q = 0.f;
#pragma unroll
        for (int i = 0; i < WM; ++i) {
          float v = acc[i][j][r];
          s += v; q = fmaf(v, v, q);
        }
#pragma unroll
        for (int mk = 1; mk < 16; mk <<= 1) {
          s += __shfl_xor(s, mk);
          q += __shfl_xor(q, mk);
        }
        if (ln15 == 0) {
          int co = (cg0 + j) * 16 + quad * 4 + r;
          atomicAdd(&sst[co], s);
          atomicAdd(&ssq[co], q);
        }
      }
    __syncthreads();
    float* d = stOut + (size_t)(blockIdx.x & 7) * 2 * Co;
    for (int c = tid; c < Co; c += 256) {
      atomicAdd(&d[c], sst[c]);
      atomicAdd(&d[Co + c], ssq[c]);
    }
  }
}

// ===================== 1x1 conv GEMM, fused input-BN + output stats ==========
template<int Ci, int Co, int COT, bool BN, int NPIX, bool OSTAT>
__global__ __launch_bounds__(256) void g1x1(const ushort* __restrict__ in,
    const ushort* __restrict__ wt, const float* __restrict__ bias,
    const float* __restrict__ st, const float* __restrict__ g,
    const float* __restrict__ bb, ushort* __restrict__ out,
    float* __restrict__ stOut) {
  constexpr int NG = COT / 16;
  constexpr int CB = BN ? Ci : 1;
  constexpr int SB = OSTAT ? COT : 1;
  __shared__ ushort lb[64 * 40];
  __shared__ float lsc[CB], lsh[CB];
  __shared__ float sst[SB], ssq[SB];
  const int tid = threadIdx.x, wave = tid >> 6, ln15 = tid & 15, quad = (tid & 63) >> 4;
  const int pixBase = blockIdx.x * 64;
  const int co0 = blockIdx.y * COT;
  if (BN) {
    constexpr float inv_cnt = 1.0f / (float)NPIX;
    for (int c = tid; c < Ci; c += 256) {
      float s = 0.f, q = 0.f;
#pragma unroll
      for (int sl = 0; sl < 8; ++sl) {
        s += st[sl * 2 * Ci + c];
        q += st[sl * 2 * Ci + Ci + c];
      }
      float m = s * inv_cnt;
      float var = fmaf(q, inv_cnt, -m * m);
      float sc = g[c] * rsqrtf(var + 1e-5f);
      lsc[c] = sc;
      lsh[c] = fmaf(-m, sc, bb[c]);
    }
  }
  f32x4 acc[NG];
#pragma unroll
  for (int j = 0; j < NG; ++j) acc[j] = *(const f32x4*)&bias[co0 + j * 16 + quad * 4];
  const uint* src = (const uint*)in;
#pragma unroll 1
  for (int c0 = 0; c0 < Ci; c0 += 32) {
    __syncthreads();
    for (int i = tid; i < 1024; i += 256) {
      int ciu = i & 15, pl = i >> 4;
      uint v = src[(size_t)(pixBase + pl) * (Ci / 2) + (c0 >> 1) + ciu];
      if (BN) {
        int cc = c0 + 2 * ciu;
        float f0 = fmaf(bf2f((ushort)(v & 0xffffu)), lsc[cc], lsh[cc]);
        float f1 = fmaf(bf2f((ushort)(v >> 16)), lsc[cc + 1], lsh[cc + 1]);
        f0 = f0 > 0.f ? f0 : 0.01f * f0;
        f1 = f1 > 0.f ? f1 : 0.01f * f1;
        v = pk(f0, f1);
      }
      ((uint*)lb)[pl * 20 + ciu] = v;
    }
    __syncthreads();
    bf16x8 bfr = *(const bf16x8*)&lb[(wave * 16 + ln15) * 40 + quad * 8];
#pragma unroll
    for (int j = 0; j < NG; ++j) {
      bf16x8 af = *(const bf16x8*)&wt[(size_t)(co0 + j * 16 + ln15) * Ci + c0 + quad * 8];
      acc[j] = __builtin_amdgcn_mfma_f32_16x16x32_bf16(af, bfr, acc[j], 0, 0, 0);
    }
  }
  if (OSTAT) {
    __syncthreads();
    for (int c = tid; c < COT; c += 256) { sst[c] = 0.f; ssq[c] = 0.f; }
    __syncthreads();
  }
  int pix = pixBase + wave * 16 + ln15;
#pragma unroll
  for (int j = 0; j < NG; ++j) {
    uint2 stv; stv.x = pk(acc[j][0], acc[j][1]); stv.y = pk(acc[j][2], acc[j][3]);
    *(uint2*)&out[(size_t)pix * Co + co0 + j * 16 + quad * 4] = stv;
  }
  if (OSTAT) {
#pragma unroll
    for (int j = 0; j < NG; ++j)
#pragma unroll
      for (int r = 0; r < 4; ++r) {
        float s = acc[j][r];
        float q = s * s;
#pragma unroll
        for (int mk = 1; mk < 16; mk <<= 1) {
          s += __shfl_xor(s, mk);
          q += __shfl_xor(q, mk);
        }
        if (ln15 == 0) {
          int cl = j * 16 + quad * 4 + r;
          atomicAdd(&sst[cl], s);
          atomicAdd(&ssq[cl], q);
        }
      }
    __syncthreads();
    float* d = stOut + (size_t)(blockIdx.x & 7) * 2 * Co;
    for (int c = tid; c < COT; c += 256) {
      atomicAdd(&d[co0 + c], sst[c]);
      atomicAdd(&d[Co + co0 + c], ssq[c]);
    }
  }
}

// ===================== ce1: k4s2p1, Ci=3, fp32 NCHW in -> raw bf16 NHWC ==========
__global__ __launch_bounds__(256) void ce1_conv(const float* __restrict__ x,
    const float* __restrict__ w, const float* __restrict__ bias, uint* __restrict__ out) {
  __shared__ float lw[1536];
  __shared__ float lb[32];
  int tid = threadIdx.x;
#pragma unroll
  for (int k = 0; k < 6; ++k) lw[tid + k * 256] = w[tid + k * 256];
  if (tid < 32) lb[tid] = bias[tid];
  __syncthreads();
  int pix = blockIdx.x * 256 + tid;     // 512*32*32
  int w_ = pix & 31, h_ = (pix >> 5) & 31, n = pix >> 10;
  float v[48];
#pragma unroll
  for (int ci = 0; ci < 3; ++ci) {
    const float* xp = x + (((size_t)n * 3 + ci) << 12);
#pragma unroll
    for (int kh = 0; kh < 4; ++kh) {
      int ih = 2 * h_ - 1 + kh;
#pragma unroll
      for (int kw = 0; kw < 4; ++kw) {
        int iw = 2 * w_ - 1 + kw;
        bool okk = ((unsigned)ih < 64u) && ((unsigned)iw < 64u);
        v[ci * 16 + kh * 4 + kw] = okk ? xp[(ih << 6) + iw] : 0.f;
      }
    }
  }
  uint ub[16];
#pragma unroll
  for (int cp = 0; cp < 16; ++cp) {
    float a[2];
#pragma unroll
    for (int s = 0; s < 2; ++s) {
      int co = 2 * cp + s;
      float ac = lb[co];
#pragma unroll
      for (int q = 0; q < 12; ++q) {
        float4 wv = *(const float4*)&lw[co * 48 + q * 4];
        ac = fmaf(v[q * 4 + 0], wv.x, ac);
        ac = fmaf(v[q * 4 + 1], wv.y, ac);
        ac = fmaf(v[q * 4 + 2], wv.z, ac);
        ac = fmaf(v[q * 4 + 3], wv.w, ac);
      }
      a[s] = ac;
    }
    ub[cp] = pk(a[0], a[1]);
  }
  uint4* op = (uint4*)&out[(size_t)pix * 16];
#pragma unroll
  for (int q = 0; q < 4; ++q)
    op[q] = make_uint4(ub[4 * q], ub[4 * q + 1], ub[4 * q + 2], ub[4 * q + 3]);
}

// ===================== BN stats for r1 only ==========
__global__ __launch_bounds__(256) void bn_stats(const ushort* __restrict__ x,
    float* __restrict__ st, int C, long npairs) {
  int tid = threadIdx.x;
  int cpw = C >> 1;
  float s0 = 0.f, s1 = 0.f, q0 = 0.f, q1 = 0.f;
  const uint* xp = (const uint*)x;
  for (long i = (long)blockIdx.x * 256 + tid; i < npairs; i += (long)gridDim.x * 256) {
    uint v = xp[i];
    float f0 = bf2f((ushort)(v & 0xffffu));
    float f1 = bf2f((ushort)(v >> 16));
    s0 += f0; q0 = fmaf(f0, f0, q0);
    s1 += f1; q1 = fmaf(f1, f1, q1);
  }
  __shared__ float A0[256], A1[256], Q0[256], Q1[256];
  A0[tid] = s0; A1[tid] = s1; Q0[tid] = q0; Q1[tid] = q1;
  __syncthreads();
  for (int off = 128; off >= cpw; off >>= 1) {
    if (tid < off) {
      A0[tid] += A0[tid + off]; A1[tid] += A1[tid + off];
      Q0[tid] += Q0[tid + off]; Q1[tid] += Q1[tid + off];
    }
    __syncthreads();
  }
  if (tid < cpw) {
    float* d = st + (size_t)(blockIdx.x & 7) * 2 * C;
    atomicAdd(&d[2 * tid], A0[tid]);
    atomicAdd(&d[2 * tid + 1], A1[tid]);
    atomicAdd(&d[C + 2 * tid], Q0[tid]);
    atomicAdd(&d[C + 2 * tid + 1], Q1[tid]);
  }
}

// ===================== prep: ALL weight transforms + codebook, one dispatch ======
__device__ __forceinline__ void enc_tr(const float* __restrict__ w,
    ushort* __restrict__ o, int Co, int Ci, int idx) {
  int ci = idx % Ci; int r = idx / Ci; int co = r % Co; int t = r / Co;
  o[idx] = f2bf(w[(co * Ci + ci) * 16 + t]);
}
__device__ __forceinline__ float dec_comb(const float* __restrict__ w,
    int Ci, int co, int ci, int pt) {
  int p = pt >> 2, t = pt & 3;
  int ph = p >> 1, pw = p & 1, rr = t >> 1, cc = t & 1;
  int rs = (rr == 0) ? 0 : (ph == 0 ? 1 : 2);
  int re = (rr == 0) ? (ph == 0 ? 1 : 2) : 3;
  int cs = (cc == 0) ? 0 : (pw == 0 ? 1 : 2);
  int ce = (cc == 0) ? (pw == 0 ? 1 : 2) : 3;
  float s = 0.f;
  for (int kh = rs; kh < re; ++kh)
    for (int kw = cs; kw < ce; ++kw)
      s += w[((co * Ci + ci) * 3 + kh) * 3 + kw];
  return s;
}
__device__ __forceinline__ void dec_tr(const float* __restrict__ w,
    ushort* __restrict__ o, int Co, int Ci, int idx) {
  int ci = idx % Ci; int r = idx / Ci; int co = r % Co; int pt = r / Co;
  o[idx] = f2bf(dec_comb(w, Ci, co, ci, pt));
}

__global__ __launch_bounds__(256) void prep_all(
    const float* __restrict__ ce2_w, const float* __restrict__ ce3_w,
    const float* __restrict__ ce4_w, const float* __restrict__ ce5_w,
    const float* __restrict__ cd0_w, const float* __restrict__ cd1_w,
    const float* __restrict__ cd2_w, const float* __restrict__ cd3_w,
    const float* __restrict__ cd4_w, const float* __restrict__ cd4_b,
    const float* __restrict__ codebook,
    ushort* __restrict__ wce2, ushort* __restrict__ wce3, ushort* __restrict__ wce4,
    ushort* __restrict__ wce5, ushort* __restrict__ wcd0, ushort* __restrict__ wcd1,
    ushort* __restrict__ wcd2, ushort* __restrict__ wcd3, ushort* __restrict__ wcd4,
    float* __restrict__ cd4bp, ushort* __restrict__ cbbf, float* __restrict__ wsq) {
  __shared__ float sh[4];
  int bx = blockIdx.x, tid = threadIdx.x;
  if (bx < 2048) { int i = bx * 256 + tid; cbbf[i] = f2bf(codebook[i]); return; }
  bx -= 2048;
  if (bx < 512) {               // wsq: one k per block
    int k = bx;
    float s = 0.f;
    for (int d = tid; d < 1024; d += 256) {
      float v = codebook[k * 1024 + d];
      s = fmaf(v, v, s);
    }
#pragma unroll
    for (int o = 32; o > 0; o >>= 1) s += __shfl_down(s, o);
    if ((tid & 63) == 0) sh[tid >> 6] = s;
    __syncthreads();
    if (tid == 0) wsq[k] = sh[0] + sh[1] + sh[2] + sh[3];
    return;
  }
  bx -= 512;
  if (bx < 2048) { enc_tr(ce4_w, wce4, 256, 128, bx * 256 + tid); return; }
  bx -= 2048;
  if (bx < 2048) { dec_tr(cd1_w, wcd1, 128, 256, bx * 256 + tid); return; }
  bx -= 2048;
  if (bx < 512)  { enc_tr(ce3_w, wce3, 128, 64, bx * 256 + tid); return; }
  bx -= 512;
  if (bx < 512)  { dec_tr(cd2_w, wcd2, 64, 128, bx * 256 + tid); return; }
  bx -= 512;
  if (bx < 128)  { enc_tr(ce2_w, wce2, 64, 32, bx * 256 + tid); return; }
  bx -= 128;
  if (bx < 128)  { dec_tr(cd3_w, wcd3, 32, 64, bx * 256 + tid); return; }
  bx -= 128;
  if (bx < 64)   { int i = bx * 256 + tid; wce5[i] = f2bf(ce5_w[i]); return; }
  bx -= 64;
  if (bx < 64)   { int i = bx * 256 + tid; wcd0[i] = f2bf(cd0_w[i]); return; }
  bx -= 64;
  {                             // cd4 padded: [16 taps][16 co][32 ci]
    int idx = bx * 256 + tid;   // 32 blocks -> 8192
    int ci = idx & 31; int r = idx >> 5; int co = r & 15; int pt = r >> 4;
    wcd4[idx] = (co < 3) ? f2bf(dec_comb(cd4_w, 32, co, ci, pt)) : (ushort)0;
    if (bx == 0 && tid < 16) cd4bp[tid] = (tid < 3) ? cd4_b[tid] : 0.f;
  }
}

// ===================== VQ ==========
__global__ __launch_bounds__(256) void zprep(const ushort* __restrict__ r5,
    const float* __restrict__ st, const float* __restrict__ g,
    const float* __restrict__ bb, float* __restrict__ Z, ushort* __restrict__ Zbf) {
  __shared__ float lsc[64], lsh[64];
  int tid = threadIdx.x;
  if (tid < 64) {
    float s = 0.f, q = 0.f;
#pragma unroll
    for (int sl = 0; sl < 8; ++sl) { s += st[sl * 128 + tid]; q += st[sl * 128 + 64 + tid]; }
    float m = s * (1.0f / 8192.f);
    float var = fmaf(q, 1.0f / 8192.f, -m * m);
    float sc = g[tid] * rsqrtf(var + 1e-5f);
    lsc[tid] = sc;
    lsh[tid] = fmaf(-m, sc, bb[tid]);
  }
  __syncthreads();
  int i = blockIdx.x * 256 + tid;   // 524288
  int c = i & 63;
  float f = fmaf(bf2f(r5[i]), lsc[c], lsh[c]);
  f = f > 0.f ? f : 0.01f * f;
  Z[i] = f;
  Zbf[i] = f2bf(f);
}

__global__ __launch_bounds__(256) void vq_gemm(const ushort* __restrict__ Zbf,
    const ushort* __restrict__ cbbf, float* __restrict__ S) {
  __shared__ ushort lZ[64 * 40], lW[64 * 40];
  const int tid = threadIdx.x, wave = tid >> 6, ln15 = tid & 15, quad = (tid & 63) >> 4;
  const int b0 = blockIdx.x * 64, k0 = blockIdx.y * 64;
  f32x4 acc[4];
#pragma unroll
  for (int j = 0; j < 4; ++j) acc[j] = (f32x4)(0.f);
  const uint* zs = (const uint*)Zbf;
  const uint* ws = (const uint*)cbbf;
#pragma unroll 1
  for (int c0 = 0; c0 < 1024; c0 += 32) {
    __syncthreads();
    for (int i = tid; i < 1024; i += 256) {
      int ciu = i & 15, rl = i >> 4;
      ((uint*)lZ)[rl * 20 + ciu] = zs[(size_t)(b0 + rl) * 512 + (c0 >> 1) + ciu];
      ((uint*)lW)[rl * 20 + ciu] = ws[(size_t)(k0 + rl) * 512 + (c0 >> 1) + ciu];
    }
    __syncthreads();
    bf16x8 bfr = *(const bf16x8*)&lZ[(wave * 16 + ln15) * 40 + quad * 8];
#pragma unroll
    for (int j = 0; j < 4; ++j) {
      bf16x8 af = *(const bf16x8*)&lW[(j * 16 + ln15) * 40 + quad * 8];
      acc[j] = __builtin_amdgcn_mfma_f32_16x16x32_bf16(af, bfr, acc[j], 0, 0, 0);
    }
  }
  int b = b0 + wave * 16 + ln15;
#pragma unroll
  for (int j = 0; j < 4; ++j)
    *(f32x4*)&S[(size_t)b * 512 + k0 + j * 16 + quad * 4] = acc[j];
}

__global__ __launch_bounds__(256) void vq_scan(const float* __restrict__ S,
    const float* __restrict__ wsq, int* __restrict__ jout) {
  int b = blockIdx.x, tid = threadIdx.x;
  float d1 = fmaf(-2.f, S[(size_t)b * 512 + tid], wsq[tid]);
  float d2 = fmaf(-2.f, S[(size_t)b * 512 + tid + 256], wsq[tid + 256]);
  float bv = d1; int bk = tid;
  if (d2 < bv) { bv = d2; bk = tid + 256; }
  __shared__ float vsh[256]; __shared__ int ish[256];
  vsh[tid] = bv; ish[tid] = bk;
  __syncthreads();
  for (int s = 128; s > 0; s >>= 1) {
    if (tid < s) {
      float ov = vsh[tid + s]; int oi = ish[tid + s];
      if (ov < vsh[tid] || (ov == vsh[tid] && oi < ish[tid])) { vsh[tid] = ov; ish[tid] = oi; }
    }
    __syncthreads();
  }
  if (tid == 0) jout[b] = ish[0];
}

__global__ __launch_bounds__(256) void vq_gather_loss(const float* __restrict__ Z,
    const float* __restrict__ cb, const int* __restrict__ jidx,
    ushort* __restrict__ Zq, float* __restrict__ lossAcc) {
  int b = blockIdx.x;
  int k = jidx[b];
  const float* w = cb + ((long)k << 10);
  const float* zp = Z + ((long)b << 10);
  float part = 0.f;
  for (int d = threadIdx.x; d < 1024; d += 256) {
    float wv = w[d];
    float diff = zp[d] - wv;
    part = fmaf(diff, diff, part);
    Zq[(b << 10) + d] = f2bf(wv);
  }
#pragma unroll
  for (int o = 32; o > 0; o >>= 1) part += __shfl_down(part, o);
  __shared__ float sh[4];
  if ((threadIdx.x & 63) == 0) sh[threadIdx.x >> 6] = part;
  __syncthreads();
  if (threadIdx.x == 0) atomicAdd(lossAcc, sh[0] + sh[1] + sh[2] + sh[3]);
}

__global__ void write_losses(const float* __restrict__ lossAcc, float* __restrict__ out2) {
  float v = lossAcc[0] * (1.0f / 512.0f);
  out2[0] = v;
  out2[1] = v;
}

// ===================== launch ==========
extern "C" void kernel_launch(void* const* d_in, const int* in_sizes, int n_in,
                              void* d_out, int out_size, void* d_ws, size_t ws_size,
                              hipStream_t stream) {
  const float* x      = (const float*)d_in[0];
  const float* ce1_w  = (const float*)d_in[1];  const float* ce1_b = (const float*)d_in[2];
  const float* ce2_w  = (const float*)d_in[3];  const float* ce2_b = (const float*)d_in[4];
  const float* ce3_w  = (const float*)d_in[5];  const float* ce3_b = (const float*)d_in[6];
  const float* ce4_w  = (const float*)d_in[7];  const float* ce4_b = (const float*)d_in[8];
  const float* ce5_w  = (const float*)d_in[9];  const float* ce5_b = (const float*)d_in[10];
  const float* cd0_w  = (const float*)d_in[11]; const float* cd0_b = (const float*)d_in[12];
  const float* cd1_w  = (const float*)d_in[13]; const float* cd1_b = (const float*)d_in[14];
  const float* cd2_w  = (const float*)d_in[15]; const float* cd2_b = (const float*)d_in[16];
  const float* cd3_w  = (const float*)d_in[17]; const float* cd3_b = (const float*)d_in[18];
  const float* cd4_w  = (const float*)d_in[19]; const float* cd4_b = (const float*)d_in[20];
  const float* bn_e1_g = (const float*)d_in[21]; const float* bn_e1_b = (const float*)d_in[22];
  const float* bn_e2_g = (const float*)d_in[23]; const float* bn_e2_b = (const float*)d_in[24];
  const float* bn_e3_g = (const float*)d_in[25]; const float* bn_e3_b = (const float*)d_in[26];
  const float* bn_e4_g = (const float*)d_in[27]; const float* bn_e4_b = (const float*)d_in[28];
  const float* bn_e5_g = (const float*)d_in[29]; const float* bn_e5_b = (const float*)d_in[30];
  const float* bn_d0_g = (const float*)d_in[31]; const float* bn_d0_b = (const float*)d_in[32];
  const float* bn_d1_g = (const float*)d_in[33]; const float* bn_d1_b = (const float*)d_in[34];
  const float* bn_d2_g = (const float*)d_in[35]; const float* bn_d2_b = (const float*)d_in[36];
  const float* bn_d3_g = (const float*)d_in[37]; const float* bn_d3_b = (const float*)d_in[38];
  const float* codebook = (const float*)d_in[39];

  float* out = (float*)d_out;

  // ---- workspace carve ----
  char* p = (char*)d_ws;
  auto alloc = [&](size_t bytes) { void* r = p; p += (bytes + 255) & ~(size_t)255; return r; };
  ushort* r1 = (ushort*)alloc((size_t)524288 * 32 * 2);
  ushort* r2 = (ushort*)alloc((size_t)131072 * 64 * 2);
  ushort* r3 = (ushort*)alloc((size_t)32768 * 128 * 2);
  ushort* r4 = (ushort*)alloc((size_t)8192 * 256 * 2);
  ushort* r5 = (ushort*)alloc((size_t)8192 * 64 * 2);
  ushort* d0 = (ushort*)alloc((size_t)8192 * 256 * 2);
  ushort* d1 = (ushort*)alloc((size_t)32768 * 128 * 2);
  ushort* d2 = (ushort*)alloc((size_t)131072 * 64 * 2);
  ushort* d3 = (ushort*)alloc((size_t)524288 * 32 * 2);
  float*  Z    = (float*)alloc((size_t)524288 * 4);
  ushort* Zbf  = (ushort*)alloc((size_t)524288 * 2);
  ushort* cbbf = (ushort*)alloc((size_t)524288 * 2);
  float*  S    = (float*)alloc((size_t)512 * 512 * 4);
  ushort* Zq   = (ushort*)alloc((size_t)524288 * 2);
  float*  wsq  = (float*)alloc((size_t)512 * 4);
  ushort* wce2 = (ushort*)alloc((size_t)16 * 64 * 32 * 2);
  ushort* wce3 = (ushort*)alloc((size_t)16 * 128 * 64 * 2);
  ushort* wce4 = (ushort*)alloc((size_t)16 * 256 * 128 * 2);
  ushort* wce5 = (ushort*)alloc((size_t)64 * 256 * 2);
  ushort* wcd0 = (ushort*)alloc((size_t)256 * 64 * 2);
  ushort* wcd1 = (ushort*)alloc((size_t)16 * 128 * 256 * 2);
  ushort* wcd2 = (ushort*)alloc((size_t)16 * 64 * 128 * 2);
  ushort* wcd3 = (ushort*)alloc((size_t)16 * 32 * 64 * 2);
  ushort* wcd4 = (ushort*)alloc((size_t)16 * 16 * 32 * 2);
  float*  cd4bp = (float*)alloc(64);
  float*  statsAll = (float*)alloc((size_t)(9 * 4096 + 64) * 4);
  int*    jbuf = (int*)alloc((size_t)512 * 4);

  float* st_e1 = statsAll + 0 * 4096;
  float* st_e2 = statsAll + 1 * 4096;
  float* st_e3 = statsAll + 2 * 4096;
  float* st_e4 = statsAll + 3 * 4096;
  float* st_e5 = statsAll + 4 * 4096;
  float* st_d0 = statsAll + 5 * 4096;
  float* st_d1 = statsAll + 6 * 4096;
  float* st_d2 = statsAll + 7 * 4096;
  float* st_d3 = statsAll + 8 * 4096;
  float* lossAcc = statsAll + 9 * 4096;

  // ---- single memset for all stats + lossAcc ----
  hipMemsetAsync(statsAll, 0, (size_t)(9 * 4096 + 64) * 4, stream);

  // ---- one-dispatch prep ----
  prep_all<<<8096, 256, 0, stream>>>(ce2_w, ce3_w, ce4_w, ce5_w, cd0_w, cd1_w,
      cd2_w, cd3_w, cd4_w, cd4_b, codebook,
      wce2, wce3, wce4, wce5, wcd0, wcd1, wcd2, wcd3, wcd4, cd4bp, cbbf, wsq);

  // ---- encoder ----
  ce1_conv<<<2048, 256, 0, stream>>>(x, ce1_w, ce1_b, (uint*)r1);
  bn_stats<<<512, 256, 0, stream>>>(r1, st_e1, 32, (long)524288 * 16);
  tconv<1, 32, 64, 32, 4, 2, 2, true, true, false><<<2048, 256, 0, stream>>>(
      r1, wce2, ce2_b, st_e1, bn_e1_g, bn_e1_b, r2, st_e2);
  tconv<1, 64, 128, 16, 4, 1, 4, true, true, false><<<1024, 256, 0, stream>>>(
      r2, wce3, ce3_b, st_e2, bn_e2_g, bn_e2_b, r3, st_e3);
  tconv<1, 128, 256, 8, 4, 1, 4, true, true, false><<<512, 256, 0, stream>>>(
      r3, wce4, ce4_b, st_e3, bn_e3_g, bn_e3_b, r4, st_e4);
  g1x1<256, 64, 64, true, 8192, true><<<dim3(128, 1), 256, 0, stream>>>(
      r4, wce5, ce5_b, st_e4, bn_e4_g, bn_e4_b, r5, st_e5);

  // ---- VQ ----
  zprep<<<2048, 256, 0, stream>>>(r5, st_e5, bn_e5_g, bn_e5_b, Z, Zbf);
  vq_gemm<<<dim3(8, 8), 256, 0, stream>>>(Zbf, cbbf, S);
  vq_scan<<<512, 256, 0, stream>>>(S, wsq, jbuf);
  vq_gather_loss<<<512, 256, 0, stream>>>(Z, codebook, jbuf, Zq, lossAcc);
  write_losses<<<1, 1, 0, stream>>>(lossAcc, out + 6291456);

  // ---- decoder ----
  g1x1<64, 256, 64, false, 1, true><<<dim3(128, 4), 256, 0, stream>>>(
      Zq, wcd0, cd0_b, nullptr, nullptr, nullptr, d0, st_d0);
  tconv<2, 256, 128, 4, 4, 1, 8, true, true, false><<<512, 256, 0, stream>>>(
      d0, wcd1, cd1_b, st_d0, bn_d0_g, bn_d0_b, d1, st_d1);
  tconv<2, 128, 64, 8, 8, 4, 4, true, true, false><<<512, 256, 0, stream>>>(
      d1, wcd2, cd2_b, st_d1, bn_d1_g, bn_d1_b, d2, st_d2);
  tconv<2, 64, 32, 16, 8, 8, 2, true, true, false><<<1024, 256, 0, stream>>>(
      d2, wcd3, cd3_b, st_d2, bn_d2_g, bn_d2_b, d3, st_d3);
  tconv<2, 32, 16, 32, 4, 8, 1, true, false, true><<<4096, 256, 0, stream>>>(
      d3, wcd4, cd4bp, st_d3, bn_d3_g, bn_d3_b, out, nullptr);
}

// Round 7
// 603.318 us; speedup vs baseline: 28.0979x; 1.0967x over previous
//
#include <hip/hip_runtime.h>
#include <hip/hip_bf16.h>
#include <math.h>

typedef __attribute__((ext_vector_type(8))) short bf16x8;
typedef __attribute__((ext_vector_type(4))) float f32x4;

__device__ __forceinline__ float bf2f(ushort u) {
  union { uint i; float f; } t; t.i = ((uint)u) << 16; return t.f;
}
__device__ __forceinline__ ushort f2bf(float f) {
  __hip_bfloat16 h = __float2bfloat16(f);
  return *reinterpret_cast<ushort*>(&h);
}
__device__ __forceinline__ uint pk(float a, float b) {
  return (uint)f2bf(a) | ((uint)f2bf(b) << 16);
}
constexpr int ilog2c(int v) { int r = 0; while (v > 1) { v >>= 1; ++r; } return r; }

// =====================================================================
// Tiled MFMA conv, fused input-BN+LReLU, fused output batch-stats,
// co-split across blockIdx.y (CS) for occupancy.
// MODE 1: k4s2p1 encoder. MODE 2: up2+3x3 decoder (wave = parity class).
// SIG: fp32 NCHW sigmoid output (cd4, Co padded to 16, real 3).
// =====================================================================
template<int MODE, int Ci, int Co, int HIN, int TR, int WM, int WN, int CS,
         bool BN, bool OSTAT, bool SIG>
__global__ __launch_bounds__(256) void tconv(const ushort* __restrict__ in,
    const ushort* __restrict__ wt, const float* __restrict__ bias,
    const float* __restrict__ st, const float* __restrict__ g,
    const float* __restrict__ bb, void* __restrict__ out_,
    float* __restrict__ stOut) {
  constexpr int W    = (MODE == 1) ? HIN / 2 : HIN;
  constexpr int LW   = ilog2c(W);
  constexpr int R_IN = (MODE == 1) ? 2 * TR + 2 : TR + 2;
  constexpr int W2   = HIN + 2;
  constexpr int MT   = TR * W / 16;
  constexpr int NG   = Co / 16;
  constexpr int NGB  = NG / CS;            // co groups per block
  constexpr int COB  = NGB * 16;           // channels per block
  constexpr int TAPS = (MODE == 1) ? 16 : 4;
  constexpr int RB   = W / TR;
  constexpr int CB   = BN ? Ci : 1;
  constexpr int SB   = OSTAT ? COB : 1;
  static_assert(TR * W % 16 == 0, "mtile");
  static_assert(MODE == 2 ? (WM == MT && WN == NGB)
                          : ((MT % WM == 0) && (NGB % WN == 0) &&
                             (MT / WM) * (NGB / WN) == 4),
                "wave map");

  __shared__ __align__(16) ushort lt[R_IN * W2 * 40];
  __shared__ float lsc[CB], lsh[CB];
  __shared__ float sst[SB], ssq[SB];

  const int tid  = threadIdx.x;
  const int wave = tid >> 6;
  const int ln15 = tid & 15;
  const int quad = (tid & 63) >> 4;
  const int rb = blockIdx.x % RB;
  const int n  = blockIdx.x / RB;
  const int h0 = rb * TR;
  const int cbase = blockIdx.y * NGB;      // co-group base for this block

  if (BN) {
    constexpr float inv_cnt = 1.0f / (float)(512 * HIN * HIN);
    for (int c = tid; c < Ci; c += 256) {
      float s = 0.f, q = 0.f;
#pragma unroll
      for (int sl = 0; sl < 8; ++sl) {
        s += st[sl * 2 * Ci + c];
        q += st[sl * 2 * Ci + Ci + c];
      }
      float m = s * inv_cnt;
      float var = fmaf(q, inv_cnt, -m * m);
      float sc = g[c] * rsqrtf(var + 1e-5f);
      lsc[c] = sc;
      lsh[c] = fmaf(-m, sc, bb[c]);
    }
  }

  int mt0, cg0, ph, pw, pb;
  if (MODE == 2) { mt0 = 0; cg0 = cbase; ph = wave >> 1; pw = wave & 1; pb = wave * 4; }
  else {
    constexpr int MW = MT / WM;
    mt0 = (wave % MW) * WM; cg0 = cbase + (wave / MW) * WN; ph = 0; pw = 0; pb = 0;
  }

  f32x4 acc[WM][WN];
#pragma unroll
  for (int j = 0; j < WN; ++j) {
    f32x4 b4 = *(const f32x4*)&bias[(cg0 + j) * 16 + quad * 4];
#pragma unroll
    for (int i = 0; i < WM; ++i) acc[i][j] = b4;
  }

  const uint4* src4 = (const uint4*)in;
  const int gr0 = (MODE == 1) ? 2 * h0 - 1 : h0 - 1;

#pragma unroll 1
  for (int c0 = 0; c0 < Ci; c0 += 32) {
    __syncthreads();
    constexpr int SN4 = R_IN * W2 * 4;     // 16B units (4 uint4 per pixel-chunk)
    for (int i = tid; i < SN4; i += 256) {
      int ciu4 = i & 3; int t2 = i >> 2; int c = t2 % W2; int r = t2 / W2;
      int gr = gr0 + r, gc = c - 1;
      uint4 v4 = make_uint4(0u, 0u, 0u, 0u);
      if ((unsigned)gr < (unsigned)HIN && (unsigned)gc < (unsigned)HIN) {
        v4 = src4[((size_t)(n * HIN + gr) * HIN + gc) * (Ci / 8) + (c0 >> 3) + ciu4];
        if (BN) {
          uint* pu = (uint*)&v4;
#pragma unroll
          for (int k2 = 0; k2 < 4; ++k2) {
            int cc = c0 + ciu4 * 8 + k2 * 2;
            float f0 = fmaf(bf2f((ushort)(pu[k2] & 0xffffu)), lsc[cc], lsh[cc]);
            float f1 = fmaf(bf2f((ushort)(pu[k2] >> 16)), lsc[cc + 1], lsh[cc + 1]);
            f0 = f0 > 0.f ? f0 : 0.01f * f0;
            f1 = f1 > 0.f ? f1 : 0.01f * f1;
            pu[k2] = pk(f0, f1);
          }
        }
      }
      *(uint4*)&((uint*)lt)[(r * W2 + c) * 20 + ciu4 * 4] = v4;
    }
    __syncthreads();

#pragma unroll
    for (int t = 0; t < TAPS; ++t) {
      const int kh = (MODE == 1) ? (t >> 2) : (t >> 1);
      const int kw = (MODE == 1) ? (t & 3) : (t & 1);
      bf16x8 af[WN];
      const ushort* wb = wt + (size_t)(pb + t) * Co * Ci;
#pragma unroll
      for (int j = 0; j < WN; ++j)
        af[j] = *(const bf16x8*)&wb[(size_t)((cg0 + j) * 16 + ln15) * Ci + c0 + quad * 8];
      bf16x8 bfr[WM];
#pragma unroll
      for (int i = 0; i < WM; ++i) {
        int m = (mt0 + i) * 16 + ln15;
        int hr = m >> LW, wr = m & (W - 1);
        int row, col;
        if (MODE == 1) { row = 2 * hr + kh; col = 2 * wr + kw; }
        else           { row = hr + kh + ph; col = wr + kw + pw; }
        bfr[i] = *(const bf16x8*)&lt[(row * W2 + col) * 40 + quad * 8];
      }
#pragma unroll
      for (int i = 0; i < WM; ++i)
#pragma unroll
        for (int j = 0; j < WN; ++j)
          acc[i][j] = __builtin_amdgcn_mfma_f32_16x16x32_bf16(af[j], bfr[i], acc[i][j], 0, 0, 0);
    }
  }

  if (OSTAT) {
    for (int c = tid; c < COB; c += 256) { sst[c] = 0.f; ssq[c] = 0.f; }
    __syncthreads();
  }

  if (SIG) {
    constexpr int HO2 = 2 * HIN;
    float* outF = (float*)out_;
#pragma unroll
    for (int i = 0; i < WM; ++i) {
      int m = (mt0 + i) * 16 + ln15;
      int hr = m >> LW, wr = m & (W - 1);
      int oh = 2 * (h0 + hr) + ph, ow = 2 * wr + pw;
      size_t base = (size_t)n * 3 * HO2 * HO2 + (size_t)oh * HO2 + ow;
#pragma unroll
      for (int r = 0; r < 4; ++r) {
        int co = quad * 4 + r;
        if (co < 3)
          outF[base + (size_t)co * HO2 * HO2] = 1.f / (1.f + __expf(-acc[i][0][r]));
      }
    }
  } else {
    ushort* out = (ushort*)out_;
#pragma unroll
    for (int i = 0; i < WM; ++i) {
      int m = (mt0 + i) * 16 + ln15;
      int hr = m >> LW, wr = m & (W - 1);
      size_t sp;
      if (MODE == 2) {
        int oh = 2 * (h0 + hr) + ph, ow = 2 * wr + pw;
        sp = ((size_t)n * (2 * HIN) + oh) * (2 * HIN) + ow;
      } else {
        sp = ((size_t)n * W + h0 + hr) * W + wr;
      }
#pragma unroll
      for (int j = 0; j < WN; ++j) {
        f32x4 a = acc[i][j];
        uint2 stv; stv.x = pk(a[0], a[1]); stv.y = pk(a[2], a[3]);
        *(uint2*)&out[sp * Co + (cg0 + j) * 16 + quad * 4] = stv;
      }
    }
  }

  if (OSTAT) {
#pragma unroll
    for (int j = 0; j < WN; ++j)
#pragma unroll
      for (int r = 0; r < 4; ++r) {
        float s = 0.f, q = 0.f;
#pragma unroll
        for (int i = 0; i < WM; ++i) {
          float v = acc[i][j][r];
          s += v; q = fmaf(v, v, q);
        }
#pragma unroll
        for (int mk = 1; mk < 16; mk <<= 1) {
          s += __shfl_xor(s, mk);
          q += __shfl_xor(q, mk);
        }
        if (ln15 == 0) {
          int lc = (cg0 + j) * 16 + quad * 4 + r - cbase * 16;
          atomicAdd(&sst[lc], s);
          atomicAdd(&ssq[lc], q);
        }
      }
    __syncthreads();
    float* d = stOut + (size_t)(blockIdx.x & 7) * 2 * Co;
    for (int c = tid; c < COB; c += 256) {
      atomicAdd(&d[cbase * 16 + c], sst[c]);
      atomicAdd(&d[Co + cbase * 16 + c], ssq[c]);
    }
  }
}

// ===================== 1x1 conv GEMM, fused input-BN + output stats ==========
template<int Ci, int Co, int COT, bool BN, int NPIX, bool OSTAT>
__global__ __launch_bounds__(256) void g1x1(const ushort* __restrict__ in,
    const ushort* __restrict__ wt, const float* __restrict__ bias,
    const float* __restrict__ st, const float* __restrict__ g,
    const float* __restrict__ bb, ushort* __restrict__ out,
    float* __restrict__ stOut) {
  constexpr int NG = COT / 16;
  constexpr int CB = BN ? Ci : 1;
  constexpr int SB = OSTAT ? COT : 1;
  __shared__ __align__(16) ushort lb[64 * 40];
  __shared__ float lsc[CB], lsh[CB];
  __shared__ float sst[SB], ssq[SB];
  const int tid = threadIdx.x, wave = tid >> 6, ln15 = tid & 15, quad = (tid & 63) >> 4;
  const int pixBase = blockIdx.x * 64;
  const int co0 = blockIdx.y * COT;
  if (BN) {
    constexpr float inv_cnt = 1.0f / (float)NPIX;
    for (int c = tid; c < Ci; c += 256) {
      float s = 0.f, q = 0.f;
#pragma unroll
      for (int sl = 0; sl < 8; ++sl) {
        s += st[sl * 2 * Ci + c];
        q += st[sl * 2 * Ci + Ci + c];
      }
      float m = s * inv_cnt;
      float var = fmaf(q, inv_cnt, -m * m);
      float sc = g[c] * rsqrtf(var + 1e-5f);
      lsc[c] = sc;
      lsh[c] = fmaf(-m, sc, bb[c]);
    }
  }
  f32x4 acc[NG];
#pragma unroll
  for (int j = 0; j < NG; ++j) acc[j] = *(const f32x4*)&bias[co0 + j * 16 + quad * 4];
  const uint4* src4 = (const uint4*)in;
#pragma unroll 1
  for (int c0 = 0; c0 < Ci; c0 += 32) {
    __syncthreads();
    {
      int ciu4 = tid & 3, pl = tid >> 2;
      uint4 v4 = src4[(size_t)(pixBase + pl) * (Ci / 8) + (c0 >> 3) + ciu4];
      if (BN) {
        uint* pu = (uint*)&v4;
#pragma unroll
        for (int k2 = 0; k2 < 4; ++k2) {
          int cc = c0 + ciu4 * 8 + k2 * 2;
          float f0 = fmaf(bf2f((ushort)(pu[k2] & 0xffffu)), lsc[cc], lsh[cc]);
          float f1 = fmaf(bf2f((ushort)(pu[k2] >> 16)), lsc[cc + 1], lsh[cc + 1]);
          f0 = f0 > 0.f ? f0 : 0.01f * f0;
          f1 = f1 > 0.f ? f1 : 0.01f * f1;
          pu[k2] = pk(f0, f1);
        }
      }
      *(uint4*)&((uint*)lb)[pl * 20 + ciu4 * 4] = v4;
    }
    __syncthreads();
    bf16x8 bfr = *(const bf16x8*)&lb[(wave * 16 + ln15) * 40 + quad * 8];
#pragma unroll
    for (int j = 0; j < NG; ++j) {
      bf16x8 af = *(const bf16x8*)&wt[(size_t)(co0 + j * 16 + ln15) * Ci + c0 + quad * 8];
      acc[j] = __builtin_amdgcn_mfma_f32_16x16x32_bf16(af, bfr, acc[j], 0, 0, 0);
    }
  }
  if (OSTAT) {
    for (int c = tid; c < COT; c += 256) { sst[c] = 0.f; ssq[c] = 0.f; }
    __syncthreads();
  }
  int pix = pixBase + wave * 16 + ln15;
#pragma unroll
  for (int j = 0; j < NG; ++j) {
    uint2 stv; stv.x = pk(acc[j][0], acc[j][1]); stv.y = pk(acc[j][2], acc[j][3]);
    *(uint2*)&out[(size_t)pix * Co + co0 + j * 16 + quad * 4] = stv;
  }
  if (OSTAT) {
#pragma unroll
    for (int j = 0; j < NG; ++j)
#pragma unroll
      for (int r = 0; r < 4; ++r) {
        float s = acc[j][r];
        float q = s * s;
#pragma unroll
        for (int mk = 1; mk < 16; mk <<= 1) {
          s += __shfl_xor(s, mk);
          q += __shfl_xor(q, mk);
        }
        if (ln15 == 0) {
          int cl = j * 16 + quad * 4 + r;
          atomicAdd(&sst[cl], s);
          atomicAdd(&ssq[cl], q);
        }
      }
    __syncthreads();
    float* d = stOut + (size_t)(blockIdx.x & 7) * 2 * Co;
    for (int c = tid; c < COT; c += 256) {
      atomicAdd(&d[co0 + c], sst[c]);
      atomicAdd(&d[Co + co0 + c], ssq[c]);
    }
  }
}

// ===================== ce1: k4s2p1, Ci=3, fp32 NCHW in -> bf16 NHWC + fused stats ==
__global__ __launch_bounds__(256) void ce1_conv(const float* __restrict__ x,
    const float* __restrict__ w, const float* __restrict__ bias,
    uint* __restrict__ out, float* __restrict__ stOut) {
  __shared__ float lw[1536];
  __shared__ float lb[32];
  __shared__ float sst[32], ssq[32];
  int tid = threadIdx.x;
#pragma unroll
  for (int k = 0; k < 6; ++k) lw[tid + k * 256] = w[tid + k * 256];
  if (tid < 32) { lb[tid] = bias[tid]; sst[tid] = 0.f; ssq[tid] = 0.f; }
  __syncthreads();
  int pix = blockIdx.x * 256 + tid;     // 512*32*32
  int w_ = pix & 31, h_ = (pix >> 5) & 31, n = pix >> 10;
  float v[48];
#pragma unroll
  for (int ci = 0; ci < 3; ++ci) {
    const float* xp = x + (((size_t)n * 3 + ci) << 12);
#pragma unroll
    for (int kh = 0; kh < 4; ++kh) {
      int ih = 2 * h_ - 1 + kh;
#pragma unroll
      for (int kw = 0; kw < 4; ++kw) {
        int iw = 2 * w_ - 1 + kw;
        bool okk = ((unsigned)ih < 64u) && ((unsigned)iw < 64u);
        v[ci * 16 + kh * 4 + kw] = okk ? xp[(ih << 6) + iw] : 0.f;
      }
    }
  }
  float vs[32];
  uint ub[16];
#pragma unroll
  for (int cp = 0; cp < 16; ++cp) {
    float a[2];
#pragma unroll
    for (int s = 0; s < 2; ++s) {
      int co = 2 * cp + s;
      float ac = lb[co];
#pragma unroll
      for (int q = 0; q < 12; ++q) {
        float4 wv = *(const float4*)&lw[co * 48 + q * 4];
        ac = fmaf(v[q * 4 + 0], wv.x, ac);
        ac = fmaf(v[q * 4 + 1], wv.y, ac);
        ac = fmaf(v[q * 4 + 2], wv.z, ac);
        ac = fmaf(v[q * 4 + 3], wv.w, ac);
      }
      a[s] = ac;
      vs[co] = ac;
    }
    ub[cp] = pk(a[0], a[1]);
  }
  uint4* op = (uint4*)&out[(size_t)pix * 16];
#pragma unroll
  for (int q = 0; q < 4; ++q)
    op[q] = make_uint4(ub[4 * q], ub[4 * q + 1], ub[4 * q + 2], ub[4 * q + 3]);
  // fused batch stats: wave-reduce each channel, LDS combine, one global add
  int lane = tid & 63;
#pragma unroll
  for (int ch = 0; ch < 32; ++ch) {
    float s = vs[ch];
    float q = s * s;
#pragma unroll
    for (int mk = 1; mk < 64; mk <<= 1) {
      s += __shfl_xor(s, mk);
      q += __shfl_xor(q, mk);
    }
    if (lane == 0) { atomicAdd(&sst[ch], s); atomicAdd(&ssq[ch], q); }
  }
  __syncthreads();
  if (tid < 32) {
    float* d = stOut + (size_t)(blockIdx.x & 7) * 64;
    atomicAdd(&d[tid], sst[tid]);
    atomicAdd(&d[32 + tid], ssq[tid]);
  }
}

// ===================== prep: ALL weight transforms + codebook, one dispatch ======
__device__ __forceinline__ void enc_tr(const float* __restrict__ w,
    ushort* __restrict__ o, int Co, int Ci, int idx) {
  int ci = idx % Ci; int r = idx / Ci; int co = r % Co; int t = r / Co;
  o[idx] = f2bf(w[(co * Ci + ci) * 16 + t]);
}
__device__ __forceinline__ float dec_comb(const float* __restrict__ w,
    int Ci, int co, int ci, int pt) {
  int p = pt >> 2, t = pt & 3;
  int ph = p >> 1, pw = p & 1, rr = t >> 1, cc = t & 1;
  int rs = (rr == 0) ? 0 : (ph == 0 ? 1 : 2);
  int re = (rr == 0) ? (ph == 0 ? 1 : 2) : 3;
  int cs = (cc == 0) ? 0 : (pw == 0 ? 1 : 2);
  int ce = (cc == 0) ? (pw == 0 ? 1 : 2) : 3;
  float s = 0.f;
  for (int kh = rs; kh < re; ++kh)
    for (int kw = cs; kw < ce; ++kw)
      s += w[((co * Ci + ci) * 3 + kh) * 3 + kw];
  return s;
}
__device__ __forceinline__ void dec_tr(const float* __restrict__ w,
    ushort* __restrict__ o, int Co, int Ci, int idx) {
  int ci = idx % Ci; int r = idx / Ci; int co = r % Co; int pt = r / Co;
  o[idx] = f2bf(dec_comb(w, Ci, co, ci, pt));
}

__global__ __launch_bounds__(256) void prep_all(
    const float* __restrict__ ce2_w, const float* __restrict__ ce3_w,
    const float* __restrict__ ce4_w, const float* __restrict__ ce5_w,
    const float* __restrict__ cd0_w, const float* __restrict__ cd1_w,
    const float* __restrict__ cd2_w, const float* __restrict__ cd3_w,
    const float* __restrict__ cd4_w, const float* __restrict__ cd4_b,
    const float* __restrict__ codebook,
    ushort* __restrict__ wce2, ushort* __restrict__ wce3, ushort* __restrict__ wce4,
    ushort* __restrict__ wce5, ushort* __restrict__ wcd0, ushort* __restrict__ wcd1,
    ushort* __restrict__ wcd2, ushort* __restrict__ wcd3, ushort* __restrict__ wcd4,
    float* __restrict__ cd4bp, ushort* __restrict__ cbbf, float* __restrict__ wsq) {
  __shared__ float sh[4];
  int bx = blockIdx.x, tid = threadIdx.x;
  if (bx < 2048) { int i = bx * 256 + tid; cbbf[i] = f2bf(codebook[i]); return; }
  bx -= 2048;
  if (bx < 512) {
    int k = bx;
    float s = 0.f;
    for (int d = tid; d < 1024; d += 256) {
      float v = codebook[k * 1024 + d];
      s = fmaf(v, v, s);
    }
#pragma unroll
    for (int o = 32; o > 0; o >>= 1) s += __shfl_down(s, o);
    if ((tid & 63) == 0) sh[tid >> 6] = s;
    __syncthreads();
    if (tid == 0) wsq[k] = sh[0] + sh[1] + sh[2] + sh[3];
    return;
  }
  bx -= 512;
  if (bx < 2048) { enc_tr(ce4_w, wce4, 256, 128, bx * 256 + tid); return; }
  bx -= 2048;
  if (bx < 2048) { dec_tr(cd1_w, wcd1, 128, 256, bx * 256 + tid); return; }
  bx -= 2048;
  if (bx < 512)  { enc_tr(ce3_w, wce3, 128, 64, bx * 256 + tid); return; }
  bx -= 512;
  if (bx < 512)  { dec_tr(cd2_w, wcd2, 64, 128, bx * 256 + tid); return; }
  bx -= 512;
  if (bx < 128)  { enc_tr(ce2_w, wce2, 64, 32, bx * 256 + tid); return; }
  bx -= 128;
  if (bx < 128)  { dec_tr(cd3_w, wcd3, 32, 64, bx * 256 + tid); return; }
  bx -= 128;
  if (bx < 64)   { int i = bx * 256 + tid; wce5[i] = f2bf(ce5_w[i]); return; }
  bx -= 64;
  if (bx < 64)   { int i = bx * 256 + tid; wcd0[i] = f2bf(cd0_w[i]); return; }
  bx -= 64;
  {                             // cd4 padded: [16 taps][16 co][32 ci]
    int idx = bx * 256 + tid;   // 32 blocks
    int ci = idx & 31; int r = idx >> 5; int co = r & 15; int pt = r >> 4;
    wcd4[idx] = (co < 3) ? f2bf(dec_comb(cd4_w, 32, co, ci, pt)) : (ushort)0;
    if (bx == 0 && tid < 16) cd4bp[tid] = (tid < 3) ? cd4_b[tid] : 0.f;
  }
}

// ===================== VQ ==========
__global__ __launch_bounds__(256) void zprep(const ushort* __restrict__ r5,
    const float* __restrict__ st, const float* __restrict__ g,
    const float* __restrict__ bb, float* __restrict__ Z, ushort* __restrict__ Zbf) {
  __shared__ float lsc[64], lsh[64];
  int tid = threadIdx.x;
  if (tid < 64) {
    float s = 0.f, q = 0.f;
#pragma unroll
    for (int sl = 0; sl < 8; ++sl) { s += st[sl * 128 + tid]; q += st[sl * 128 + 64 + tid]; }
    float m = s * (1.0f / 8192.f);
    float var = fmaf(q, 1.0f / 8192.f, -m * m);
    float sc = g[tid] * rsqrtf(var + 1e-5f);
    lsc[tid] = sc;
    lsh[tid] = fmaf(-m, sc, bb[tid]);
  }
  __syncthreads();
  int i = blockIdx.x * 256 + tid;
  int c = i & 63;
  float f = fmaf(bf2f(r5[i]), lsc[c], lsh[c]);
  f = f > 0.f ? f : 0.01f * f;
  Z[i] = f;
  Zbf[i] = f2bf(f);
}

// S_ks[b][k] partial dot over K-slice ks (4 slices). Grid (8,8,4).
__global__ __launch_bounds__(256) void vq_gemm(const ushort* __restrict__ Zbf,
    const ushort* __restrict__ cbbf, float* __restrict__ S) {
  __shared__ __align__(16) ushort lZ[64 * 40], lW[64 * 40];
  const int tid = threadIdx.x, wave = tid >> 6, ln15 = tid & 15, quad = (tid & 63) >> 4;
  const int b0 = blockIdx.x * 64, k0 = blockIdx.y * 64, ks = blockIdx.z;
  f32x4 acc[4];
#pragma unroll
  for (int j = 0; j < 4; ++j) acc[j] = (f32x4)(0.f);
  const uint4* zs = (const uint4*)Zbf;
  const uint4* ws = (const uint4*)cbbf;
#pragma unroll 1
  for (int c0 = ks * 256; c0 < ks * 256 + 256; c0 += 32) {
    __syncthreads();
    for (int i = tid; i < 512; i += 256) {
      int ciu4 = i & 3; int rl = (i >> 2) & 63; bool isW = i >= 256;
      uint4 v = (isW ? ws : zs)[(size_t)((isW ? k0 : b0) + rl) * 128 + (c0 >> 3) + ciu4];
      *(uint4*)&((uint*)(isW ? lW : lZ))[rl * 20 + ciu4 * 4] = v;
    }
    __syncthreads();
    bf16x8 bfr = *(const bf16x8*)&lZ[(wave * 16 + ln15) * 40 + quad * 8];
#pragma unroll
    for (int j = 0; j < 4; ++j) {
      bf16x8 af = *(const bf16x8*)&lW[(j * 16 + ln15) * 40 + quad * 8];
      acc[j] = __builtin_amdgcn_mfma_f32_16x16x32_bf16(af, bfr, acc[j], 0, 0, 0);
    }
  }
  int b = b0 + wave * 16 + ln15;
  float* Sk = S + (size_t)ks * 262144;
#pragma unroll
  for (int j = 0; j < 4; ++j)
    *(f32x4*)&Sk[(size_t)b * 512 + k0 + j * 16 + quad * 4] = acc[j];
}

// fused: argmin scan + gather Zq + exact fp32 loss + last-block writes losses
__global__ __launch_bounds__(256) void vq_post(const float* __restrict__ S,
    const float* __restrict__ wsq, const float* __restrict__ Z,
    const float* __restrict__ cb, ushort* __restrict__ Zq,
    float* __restrict__ lossAcc, int* __restrict__ cnt, float* __restrict__ out2) {
  int b = blockIdx.x, tid = threadIdx.x;
  float s1 = 0.f, s2 = 0.f;
#pragma unroll
  for (int sl = 0; sl < 4; ++sl) {
    s1 += S[(size_t)sl * 262144 + (size_t)b * 512 + tid];
    s2 += S[(size_t)sl * 262144 + (size_t)b * 512 + tid + 256];
  }
  float d1 = fmaf(-2.f, s1, wsq[tid]);
  float d2 = fmaf(-2.f, s2, wsq[tid + 256]);
  float bv = d1; int bk = tid;
  if (d2 < bv) { bv = d2; bk = tid + 256; }
  __shared__ float vsh[256]; __shared__ int ish[256];
  vsh[tid] = bv; ish[tid] = bk;
  __syncthreads();
  for (int s = 128; s > 0; s >>= 1) {
    if (tid < s) {
      float ov = vsh[tid + s]; int oi = ish[tid + s];
      if (ov < vsh[tid] || (ov == vsh[tid] && oi < ish[tid])) { vsh[tid] = ov; ish[tid] = oi; }
    }
    __syncthreads();
  }
  int k = ish[0];
  const float* w = cb + ((long)k << 10);
  const float* zp = Z + ((long)b << 10);
  float part = 0.f;
  for (int d = tid; d < 1024; d += 256) {
    float wv = w[d];
    float diff = zp[d] - wv;
    part = fmaf(diff, diff, part);
    Zq[(b << 10) + d] = f2bf(wv);
  }
#pragma unroll
  for (int o = 32; o > 0; o >>= 1) part += __shfl_down(part, o);
  __shared__ float sh[4];
  if ((tid & 63) == 0) sh[tid >> 6] = part;
  __syncthreads();
  if (tid == 0) {
    atomicAdd(lossAcc, sh[0] + sh[1] + sh[2] + sh[3]);
    __threadfence();
    int old = atomicAdd(cnt, 1);
    if (old == 511) {
      float v = *(volatile float*)lossAcc * (1.0f / 512.0f);
      out2[0] = v;
      out2[1] = v;
    }
  }
}

// ===================== launch ==========
extern "C" void kernel_launch(void* const* d_in, const int* in_sizes, int n_in,
                              void* d_out, int out_size, void* d_ws, size_t ws_size,
                              hipStream_t stream) {
  const float* x      = (const float*)d_in[0];
  const float* ce1_w  = (const float*)d_in[1];  const float* ce1_b = (const float*)d_in[2];
  const float* ce2_w  = (const float*)d_in[3];  const float* ce2_b = (const float*)d_in[4];
  const float* ce3_w  = (const float*)d_in[5];  const float* ce3_b = (const float*)d_in[6];
  const float* ce4_w  = (const float*)d_in[7];  const float* ce4_b = (const float*)d_in[8];
  const float* ce5_w  = (const float*)d_in[9];  const float* ce5_b = (const float*)d_in[10];
  const float* cd0_w  = (const float*)d_in[11]; const float* cd0_b = (const float*)d_in[12];
  const float* cd1_w  = (const float*)d_in[13]; const float* cd1_b = (const float*)d_in[14];
  const float* cd2_w  = (const float*)d_in[15]; const float* cd2_b = (const float*)d_in[16];
  const float* cd3_w  = (const float*)d_in[17]; const float* cd3_b = (const float*)d_in[18];
  const float* cd4_w  = (const float*)d_in[19]; const float* cd4_b = (const float*)d_in[20];
  const float* bn_e1_g = (const float*)d_in[21]; const float* bn_e1_b = (const float*)d_in[22];
  const float* bn_e2_g = (const float*)d_in[23]; const float* bn_e2_b = (const float*)d_in[24];
  const float* bn_e3_g = (const float*)d_in[25]; const float* bn_e3_b = (const float*)d_in[26];
  const float* bn_e4_g = (const float*)d_in[27]; const float* bn_e4_b = (const float*)d_in[28];
  const float* bn_e5_g = (const float*)d_in[29]; const float* bn_e5_b = (const float*)d_in[30];
  const float* bn_d0_g = (const float*)d_in[31]; const float* bn_d0_b = (const float*)d_in[32];
  const float* bn_d1_g = (const float*)d_in[33]; const float* bn_d1_b = (const float*)d_in[34];
  const float* bn_d2_g = (const float*)d_in[35]; const float* bn_d2_b = (const float*)d_in[36];
  const float* bn_d3_g = (const float*)d_in[37]; const float* bn_d3_b = (const float*)d_in[38];
  const float* codebook = (const float*)d_in[39];

  float* out = (float*)d_out;

  // ---- workspace carve ----
  char* p = (char*)d_ws;
  auto alloc = [&](size_t bytes) { void* r = p; p += (bytes + 255) & ~(size_t)255; return r; };
  ushort* r1 = (ushort*)alloc((size_t)524288 * 32 * 2);
  ushort* r2 = (ushort*)alloc((size_t)131072 * 64 * 2);
  ushort* r3 = (ushort*)alloc((size_t)32768 * 128 * 2);
  ushort* r4 = (ushort*)alloc((size_t)8192 * 256 * 2);
  ushort* r5 = (ushort*)alloc((size_t)8192 * 64 * 2);
  ushort* d0 = (ushort*)alloc((size_t)8192 * 256 * 2);
  ushort* d1 = (ushort*)alloc((size_t)32768 * 128 * 2);
  ushort* d2 = (ushort*)alloc((size_t)131072 * 64 * 2);
  ushort* d3 = (ushort*)alloc((size_t)524288 * 32 * 2);
  float*  Z    = (float*)alloc((size_t)524288 * 4);
  ushort* Zbf  = (ushort*)alloc((size_t)524288 * 2);
  ushort* cbbf = (ushort*)alloc((size_t)524288 * 2);
  float*  S    = (float*)alloc((size_t)4 * 262144 * 4);   // 4 K-slices
  ushort* Zq   = (ushort*)alloc((size_t)524288 * 2);
  float*  wsq  = (float*)alloc((size_t)512 * 4);
  ushort* wce2 = (ushort*)alloc((size_t)16 * 64 * 32 * 2);
  ushort* wce3 = (ushort*)alloc((size_t)16 * 128 * 64 * 2);
  ushort* wce4 = (ushort*)alloc((size_t)16 * 256 * 128 * 2);
  ushort* wce5 = (ushort*)alloc((size_t)64 * 256 * 2);
  ushort* wcd0 = (ushort*)alloc((size_t)256 * 64 * 2);
  ushort* wcd1 = (ushort*)alloc((size_t)16 * 128 * 256 * 2);
  ushort* wcd2 = (ushort*)alloc((size_t)16 * 64 * 128 * 2);
  ushort* wcd3 = (ushort*)alloc((size_t)16 * 32 * 64 * 2);
  ushort* wcd4 = (ushort*)alloc((size_t)16 * 16 * 32 * 2);
  float*  cd4bp = (float*)alloc(64);
  float*  statsAll = (float*)alloc((size_t)(9 * 4096 + 64) * 4);
  int*    jbuf = (int*)alloc((size_t)512 * 4);

  float* st_e1 = statsAll + 0 * 4096;
  float* st_e2 = statsAll + 1 * 4096;
  float* st_e3 = statsAll + 2 * 4096;
  float* st_e4 = statsAll + 3 * 4096;
  float* st_e5 = statsAll + 4 * 4096;
  float* st_d0 = statsAll + 5 * 4096;
  float* st_d1 = statsAll + 6 * 4096;
  float* st_d2 = statsAll + 7 * 4096;
  float* st_d3 = statsAll + 8 * 4096;
  float* lossAcc = statsAll + 9 * 4096;
  int*   cnt = (int*)(lossAcc + 1);

  hipMemsetAsync(statsAll, 0, (size_t)(9 * 4096 + 64) * 4, stream);

  prep_all<<<8096, 256, 0, stream>>>(ce2_w, ce3_w, ce4_w, ce5_w, cd0_w, cd1_w,
      cd2_w, cd3_w, cd4_w, cd4_b, codebook,
      wce2, wce3, wce4, wce5, wcd0, wcd1, wcd2, wcd3, wcd4, cd4bp, cbbf, wsq);

  // ---- encoder ----
  ce1_conv<<<2048, 256, 0, stream>>>(x, ce1_w, ce1_b, (uint*)r1, st_e1);
  tconv<1, 32, 64, 32, 4, 2, 2, 1, true, true, false><<<dim3(2048, 1), 256, 0, stream>>>(
      r1, wce2, ce2_b, st_e1, bn_e1_g, bn_e1_b, r2, st_e2);
  tconv<1, 64, 128, 16, 4, 1, 2, 2, true, true, false><<<dim3(1024, 2), 256, 0, stream>>>(
      r2, wce3, ce3_b, st_e2, bn_e2_g, bn_e2_b, r3, st_e3);
  tconv<1, 128, 256, 8, 4, 1, 2, 2, true, true, false><<<dim3(512, 2), 256, 0, stream>>>(
      r3, wce4, ce4_b, st_e3, bn_e3_g, bn_e3_b, r4, st_e4);
  g1x1<256, 64, 16, true, 8192, true><<<dim3(128, 4), 256, 0, stream>>>(
      r4, wce5, ce5_b, st_e4, bn_e4_g, bn_e4_b, r5, st_e5);

  // ---- VQ ----
  zprep<<<2048, 256, 0, stream>>>(r5, st_e5, bn_e5_g, bn_e5_b, Z, Zbf);
  vq_gemm<<<dim3(8, 8, 4), 256, 0, stream>>>(Zbf, cbbf, S);
  vq_post<<<512, 256, 0, stream>>>(S, wsq, Z, codebook, Zq, lossAcc, cnt, out + 6291456);

  // ---- decoder ----
  g1x1<64, 256, 32, false, 1, true><<<dim3(128, 8), 256, 0, stream>>>(
      Zq, wcd0, cd0_b, nullptr, nullptr, nullptr, d0, st_d0);
  tconv<2, 256, 128, 4, 4, 1, 4, 2, true, true, false><<<dim3(512, 2), 256, 0, stream>>>(
      d0, wcd1, cd1_b, st_d0, bn_d0_g, bn_d0_b, d1, st_d1);
  tconv<2, 128, 64, 8, 8, 4, 2, 2, true, true, false><<<dim3(512, 2), 256, 0, stream>>>(
      d1, wcd2, cd2_b, st_d1, bn_d1_g, bn_d1_b, d2, st_d2);
  tconv<2, 64, 32, 16, 8, 8, 2, 1, true, true, false><<<dim3(1024, 1), 256, 0, stream>>>(
      d2, wcd3, cd3_b, st_d2, bn_d2_g, bn_d2_b, d3, st_d3);
  tconv<2, 32, 16, 32, 4, 8, 1, 1, true, false, true><<<dim3(4096, 1), 256, 0, stream>>>(
      d3, wcd4, cd4bp, st_d3, bn_d3_g, bn_d3_b, out, nullptr);
}